// Round 1
// baseline (1022.929 us; speedup 1.0000x reference)
//
#include <hip/hip_runtime.h>
#include <math.h>
#include <stdint.h>

typedef unsigned short u16;
typedef __attribute__((ext_vector_type(8))) short short8;   // 8 bf16 (4 VGPRs)
typedef __attribute__((ext_vector_type(4))) float floatx4;  // MFMA acc

__device__ __forceinline__ float b2f(u16 u){
  union{unsigned int i; float f;} v; v.i = ((unsigned int)u)<<16; return v.f;
}
__device__ __forceinline__ u16 f2b(float f){
  union{unsigned int i; float f;} v; v.f = f;
  unsigned int r = (v.i + 0x7FFFu + ((v.i>>16)&1u))>>16;
  return (u16)r;
}
// dual-dtype external loads: isb=1 -> bf16(u16), isb=0 -> float32
__device__ __forceinline__ float ldx(const void* p, size_t i, int isb){
  return isb ? b2f(((const u16*)p)[i]) : ((const float*)p)[i];
}
// async global->LDS, 16B per lane; LDS dest = wave-uniform base + lane*16
__device__ __forceinline__ void gll16(const u16* g, u16* l){
  __builtin_amdgcn_global_load_lds(
      (const __attribute__((address_space(1))) unsigned int*)(g),
      (__attribute__((address_space(3))) unsigned int*)(l), 16, 0, 0);
}

// dtype sniffer: bf16 N(0,1) data has exponent field in [110,139] for ~all
// even-indexed u16s; f32 low-mantissa halves are uniform (~12% in window).
__global__ void k_sniff(const void* __restrict__ X, int* __restrict__ flag)
{
  __shared__ int cnt;
  if (threadIdx.x==0) cnt = 0;
  __syncthreads();
  int c = 0;
  for (int t = threadIdx.x; t < 512; t += 256){
    unsigned int u = ((const u16*)X)[2*t];
    int e = (u >> 7) & 0xFF;
    if (e >= 110 && e <= 139) c++;
  }
  atomicAdd(&cnt, c);
  __syncthreads();
  if (threadIdx.x==0) *flag = (cnt > 300) ? 1 : 0;
}

__global__ __launch_bounds__(256) void k_zero(float* __restrict__ p, int n)
{
  int i = blockIdx.x*256 + threadIdx.x;
  if (i < n) p[i] = 0.f;
}
__global__ __launch_bounds__(256) void k_zero_int(int* __restrict__ p, int n)
{
  int i = blockIdx.x*256 + threadIdx.x;
  if (i < n) p[i] = 0;
}

// CSR build: histogram of dst, block-scan to rowptr (+fill copy), scatter.
__global__ __launch_bounds__(256) void k_hist(
    const int* __restrict__ ei, int* __restrict__ counts, int E)
{
  int e = blockIdx.x*256 + threadIdx.x;
  if (e < E) atomicAdd(&counts[ei[e]], 1);
}
__global__ __launch_bounds__(256) void k_scan(
    const int* __restrict__ counts, int* __restrict__ rowptr,
    int* __restrict__ fill, int N)
{
  __shared__ int sm[256];
  __shared__ int carry;
  int tid = threadIdx.x;
  if (tid == 0) carry = 0;
  __syncthreads();
  for (int base = 0; base < N; base += 256){
    int v = (base+tid < N) ? counts[base+tid] : 0;
    sm[tid] = v;
    __syncthreads();
    for (int off=1; off<256; off<<=1){
      int t = (tid >= off) ? sm[tid-off] : 0;
      __syncthreads();
      sm[tid] += t;
      __syncthreads();
    }
    int excl = carry + sm[tid] - v;
    if (base+tid < N){ rowptr[base+tid] = excl; fill[base+tid] = excl; }
    __syncthreads();
    if (tid == 0) carry += sm[255];
    __syncthreads();
  }
  if (tid == 0) rowptr[N] = carry;
}
__global__ __launch_bounds__(256) void k_scatter(
    const int* __restrict__ ei, int* __restrict__ fill,
    int* __restrict__ eorder, int E)
{
  int e = blockIdx.x*256 + threadIdx.x;
  if (e >= E) return;
  int d = ei[e];
  int pos = atomicAdd(&fill[d], 1);
  eorder[pos] = e;
}

// one-time weight conversion to bf16 workspace copies.
// layout in out: [0,49152) W1 | [49152,98304) W3 | [98304,106496) W2a |
// [106496,139264) W2b | [139264,237568) W2c with row permute r->(r&127)*3+(r>>7)
__global__ __launch_bounds__(256) void k_cvt_weights(
    const void* __restrict__ W1, const void* __restrict__ W3,
    const void* __restrict__ W2a, const void* __restrict__ W2b,
    const void* __restrict__ W2c, u16* __restrict__ out,
    const int* __restrict__ dflag)
{
  int isb = *dflag;
  int i = blockIdx.x*256 + threadIdx.x;
  if (i >= 237568) return;
  float v;
  if (i < 49152)        v = ldx(W1, i, isb);
  else if (i < 98304)   v = ldx(W3, i-49152, isb);
  else if (i < 106496)  v = ldx(W2a, i-98304, isb);
  else if (i < 139264)  v = ldx(W2b, i-106496, isb);
  else {
    int j = i - 139264;
    int r = j >> 8, c = j & 255;
    v = ldx(W2c, (size_t)((r & 127)*3 + (r >> 7))*256 + c, isb);
  }
  out[i] = f2b(v);
}
// biases -> f32: [0,128) b2a | [128,384) b2b | [384,768) b2c (col-permuted)
__global__ __launch_bounds__(256) void k_cvt_biases(
    const void* __restrict__ b2a, const void* __restrict__ b2b,
    const void* __restrict__ b2c, float* __restrict__ out,
    const int* __restrict__ dflag)
{
  int isb = *dflag;
  int i = blockIdx.x*256 + threadIdx.x;
  if (i < 128) out[i] = ldx(b2a, i, isb);
  else if (i < 384) out[i] = ldx(b2b, i-128, isb);
  else if (i < 768){ int c = i-384; out[i] = ldx(b2c, (c&127)*3 + (c>>7), isb); }
}
// eatt (E x 64) -> bf16 rows permuted into dst-sorted edge order (eorder).
// Removes the row-gather from gemm1 entirely.
__global__ __launch_bounds__(256) void k_perm_eatt(
    const void* __restrict__ eatt, const int* __restrict__ eorder,
    u16* __restrict__ dst, int E, const int* __restrict__ dflag)
{
  int isb = *dflag;
  int row = blockIdx.x*4 + (threadIdx.x >> 6);
  int c = threadIdx.x & 63;
  if (row >= E) return;
  int e = eorder[row];
  dst[(size_t)row*64 + c] = f2b(ldx(eatt, (size_t)e*64 + c, isb));
}

// normalize X, decompose into 10 independent components (bf16)
__global__ __launch_bounds__(256) void k_decompose(
    const void* __restrict__ X, u16* __restrict__ Di, u16* __restrict__ Da,
    u16* __restrict__ Ds, int NH, const int* __restrict__ dflag)
{
  int tid = blockIdx.x*256 + threadIdx.x;
  if (tid >= NH) return;
  int isb = *dflag;
  int n = tid >> 7, k = tid & 127;
  float x[9]; float nrm = 0.f;
#pragma unroll
  for (int i=0;i<9;i++){ x[i]=ldx(X,(size_t)tid*9+i,isb); nrm += x[i]*x[i]; }
  float inv = 1.0f/(nrm+1.0f);
#pragma unroll
  for (int i=0;i<9;i++) x[i]*=inv;
  float i0 = (x[0]+x[4]+x[8])*(1.0f/3.0f);
  Di[tid] = f2b(i0);
  size_t ab = ((size_t)n*3)*128 + k;
  Da[ab      ] = f2b(0.5f*(x[1]-x[3]));
  Da[ab + 128] = f2b(0.5f*(x[2]-x[6]));
  Da[ab + 256] = f2b(0.5f*(x[5]-x[7]));
  size_t sb = ((size_t)n*6)*128 + k;
  Ds[sb      ] = f2b(x[0]-i0);
  Ds[sb + 128] = f2b(0.5f*(x[1]+x[3]));
  Ds[sb + 256] = f2b(0.5f*(x[2]+x[6]));
  Ds[sb + 384] = f2b(x[4]-i0);
  Ds[sb + 512] = f2b(0.5f*(x[5]+x[7]));
  Ds[sb + 640] = f2b(x[8]-i0);
}

// ---------------------------------------------------------------------------
// MFMA GEMM (m97 structure): C[M,Ncol](bf16) = A[M,K](bf16) * B[Ncol,K]^T(bf16)
// 128x128 tile, 4 waves (2x2 of 64x64), BK=32, mfma_f32_16x16x32_bf16.
// global_load_lds width-16 staging (linear LDS dest), XOR-swizzled granules:
// LDS(row, g) holds global 16B-granule q = g ^ ((row>>1)&3)  -> conflict-free
// ds_read_b128 on the fragment reads (8 lanes per 4-bank group, uniform).
// bias f32, flags: 1=silu, 2=rowscale.  Requires Ncol%128==0, K%32==0.
// Rows >= M are clamped to M-1 on load (garbage compute, never stored).
// ---------------------------------------------------------------------------
__global__ __launch_bounds__(256) void k_mfma_gemm(
    const u16* __restrict__ A, const u16* __restrict__ B,
    const float* __restrict__ bias, const float* __restrict__ rowscale,
    u16* __restrict__ C, int M, int Ncol, int K, int flags)
{
  __shared__ u16 As[4096];   // 128 rows x 32 u16 (64B/row), linear
  __shared__ u16 Bs[4096];
  const int tid = threadIdx.x;
  const int lane = tid & 63, l15 = lane & 15, q = lane >> 4;
  const int wid = tid >> 6, wm = wid & 1, wn = wid >> 1;
  const int n0 = blockIdx.x * 128, m0 = blockIdx.y * 128;

  // staging geometry: wave wid stages rows [wid*32, wid*32+32), 2 instrs (j=0,1)
  // lane -> row = wid*32 + j*16 + (lane>>2), LDS granule g = lane&3,
  // global granule q = g ^ ((row>>1)&3) = (lane&3) ^ ((lane>>3)&3)
  const int srow = wid*32 + (lane >> 2);
  const int qsrc = (lane & 3) ^ ((lane >> 3) & 3);
  int ar0 = m0 + srow;      if (ar0 >= M) ar0 = M-1;
  int ar1 = m0 + srow + 16; if (ar1 >= M) ar1 = M-1;
  const u16* aSrc0 = A + (size_t)ar0*K + qsrc*8;
  const u16* aSrc1 = A + (size_t)ar1*K + qsrc*8;
  const u16* bSrc0 = B + (size_t)(n0 + srow)*K + qsrc*8;
  const u16* bSrc1 = B + (size_t)(n0 + srow + 16)*K + qsrc*8;
  u16* aDst0 = &As[wid*1024];  u16* aDst1 = &As[wid*1024 + 512];
  u16* bDst0 = &Bs[wid*1024];  u16* bDst1 = &Bs[wid*1024 + 512];

  floatx4 acc[4][4];
#pragma unroll
  for (int i=0;i<4;i++)
#pragma unroll
    for (int j=0;j<4;j++) acc[i][j] = (floatx4)0.f;

  // fragment read swizzle: row = {wm,wn}*64 + t*16 + l15 -> (row>>1)&3 == (l15>>1)&3
  const int qsw  = ((q ^ ((l15 >> 1) & 3)) << 3);
  const int aBase = (wm*64 + l15)*32 + qsw;
  const int bBase = (wn*64 + l15)*32 + qsw;

  for (int k0 = 0; k0 < K; k0 += 32){
    gll16(aSrc0 + k0, aDst0);
    gll16(aSrc1 + k0, aDst1);
    gll16(bSrc0 + k0, bDst0);
    gll16(bSrc1 + k0, bDst1);
    __syncthreads();   // compiler drains vmcnt before s_barrier -> LDS ready
    short8 av[4], bv[4];
#pragma unroll
    for (int mt=0; mt<4; mt++)
      av[mt] = *reinterpret_cast<const short8*>(&As[aBase + mt*512]);
#pragma unroll
    for (int nt=0; nt<4; nt++)
      bv[nt] = *reinterpret_cast<const short8*>(&Bs[bBase + nt*512]);
#pragma unroll
    for (int mt=0; mt<4; mt++)
#pragma unroll
      for (int nt=0; nt<4; nt++)
        acc[mt][nt] = __builtin_amdgcn_mfma_f32_16x16x32_bf16(av[mt], bv[nt], acc[mt][nt], 0, 0, 0);
    __syncthreads();   // protect LDS before next iteration's overwrite
  }

  float biasv[4];
#pragma unroll
  for (int nt=0; nt<4; nt++)
    biasv[nt] = bias ? bias[n0 + wn*64 + nt*16 + l15] : 0.f;
#pragma unroll
  for (int mt=0; mt<4; mt++){
#pragma unroll
    for (int reg=0; reg<4; reg++){
      int row = m0 + wm*64 + mt*16 + q*4 + reg;
      if (row >= M) continue;
      float rs = (flags & 2) ? rowscale[row] : 1.0f;
#pragma unroll
      for (int nt=0; nt<4; nt++){
        int col = n0 + wn*64 + nt*16 + l15;
        float t = acc[mt][nt][reg] + biasv[nt];
        if (flags & 1) t = t / (1.0f + expf(-t));
        C[(size_t)row*Ncol + col] = f2b(t*rs);
      }
    }
  }
}

// cutoff factor per sorted edge (row i of chunk = edge eorder[c0+i])
__global__ __launch_bounds__(256) void k_cutoff(
    const void* __restrict__ ew, const int* __restrict__ eorder, int c0,
    float* __restrict__ Cc, int ec, const int* __restrict__ dflag)
{
  int i = blockIdx.x*256 + threadIdx.x;
  if (i >= ec) return;
  int e = eorder[c0 + i];
  float w = ldx(ew, e, *dflag);
  float c = 0.0f;
  if (w < 4.5f) c = 0.5f*(cosf(w*0.6981317007977318f) + 1.0f);
  Cc[i] = c;
}

// ---------------------------------------------------------------------------
// Gather message passing: block per dst node, 128 threads = channels.
// Edges sorted by dst; chunk [c0,c1). ea chunk layout [ec][3][128] (permB).
// Non-atomic msg += (one block per node; chunks sequential on stream).
// msg layout [9][NH] f32 (coalesced).
// ---------------------------------------------------------------------------
__global__ __launch_bounds__(128) void k_gather(
    const int* __restrict__ rowptr, const int* __restrict__ eorder,
    const int* __restrict__ ei, int E, int c0, int c1,
    const u16* __restrict__ ea,
    const u16* __restrict__ Pi, const u16* __restrict__ Pa,
    const u16* __restrict__ Ps, const void* __restrict__ b1,
    float* __restrict__ msg, int NH, const int* __restrict__ dflag)
{
  int n = blockIdx.x;
  int lo = rowptr[n], hi = rowptr[n+1];
  if (lo < c0) lo = c0;
  if (hi > c1) hi = c1;
  if (lo >= hi) return;
  int isb = *dflag;
  int c = threadIdx.x;
  float b0 = ldx(b1,c,isb), b1f = ldx(b1,128+c,isb), b2v = ldx(b1,256+c,isb);
  float m[9];
#pragma unroll
  for (int i=0;i<9;i++) m[i]=0.f;
  for (int idx = lo; idx < hi; idx++){
    int e = eorder[idx];
    int src = ei[E + e];
    const u16* er = ea + (size_t)(idx - c0)*384;
    float e0f = b2f(er[c]), e1f = b2f(er[128+c]), e2f = b2f(er[256+c]);
    float i1 = b2f(Pi[(size_t)src*128 + c]);
    size_t ab = (size_t)src*384 + c;
    float a0 = b2f(Pa[ab]), a1 = b2f(Pa[ab+128]), a2 = b2f(Pa[ab+256]);
    size_t sb = (size_t)src*768 + c;
    float s0 = b2f(Ps[sb]),     s1 = b2f(Ps[sb+128]), s2 = b2f(Ps[sb+256]);
    float s3 = b2f(Ps[sb+384]), s4 = b2f(Ps[sb+512]), s5 = b2f(Ps[sb+640]);
    float bb = e0f*b0 + e1f*b1f + e2f*b2v;
    float t0 = e0f*i1;
    m[0] += t0 + e2f*s0 + bb;
    m[1] += e1f*a0 + e2f*s1 + bb;
    m[2] += e1f*a1 + e2f*s2 + bb;
    m[3] += -e1f*a0 + e2f*s1 + bb;
    m[4] += t0 + e2f*s3 + bb;
    m[5] += e1f*a2 + e2f*s4 + bb;
    m[6] += -e1f*a1 + e2f*s2 + bb;
    m[7] += -e1f*a2 + e2f*s4 + bb;
    m[8] += t0 + e2f*s5 + bb;
  }
  size_t o = (size_t)n*128 + c;
#pragma unroll
  for (int i=0;i<9;i++) msg[(size_t)i*NH + o] += m[i];
}

// Update: F = msg*Y + Y*msg, renormalize, decompose -> D2 (bf16)
__global__ __launch_bounds__(256) void k_update(
    const float* __restrict__ msg, const u16* __restrict__ Pi,
    const u16* __restrict__ Pa, const u16* __restrict__ Ps,
    const void* __restrict__ b1,
    u16* __restrict__ D2i, u16* __restrict__ D2a, u16* __restrict__ D2s,
    int NH, const int* __restrict__ dflag)
{
  int tid = blockIdx.x*256 + threadIdx.x;
  if (tid >= NH) return;
  int isb = *dflag;
  int n = tid >> 7, c = tid & 127;
  float Mx[9];
#pragma unroll
  for (int i=0;i<9;i++) Mx[i] = msg[(size_t)i*NH + tid];
  float i1 = b2f(Pi[tid]);
  size_t ab = ((size_t)n*3)*128 + c;
  float a0 = b2f(Pa[ab]), a1 = b2f(Pa[ab+128]), a2 = b2f(Pa[ab+256]);
  size_t sb = ((size_t)n*6)*128 + c;
  float s0 = b2f(Ps[sb]),     s1 = b2f(Ps[sb+128]), s2 = b2f(Ps[sb+256]);
  float s3 = b2f(Ps[sb+384]), s4 = b2f(Ps[sb+512]), s5 = b2f(Ps[sb+640]);
  float B = ldx(b1,c,isb) + ldx(b1,128+c,isb) + ldx(b1,256+c,isb);
  float Y[9];
  Y[0]= i1+s0+B; Y[1]= a0+s1+B; Y[2]= a1+s2+B;
  Y[3]=-a0+s1+B; Y[4]= i1+s3+B; Y[5]= a2+s4+B;
  Y[6]=-a1+s2+B; Y[7]=-a2+s4+B; Y[8]= i1+s5+B;
  float F[9];
#pragma unroll
  for (int i=0;i<3;i++)
#pragma unroll
    for (int j=0;j<3;j++){
      float acc = 0.f;
#pragma unroll
      for (int t=0;t<3;t++)
        acc += Mx[i*3+t]*Y[t*3+j] + Y[i*3+t]*Mx[t*3+j];
      F[i*3+j] = acc;
    }
  float nrm = 0.f;
#pragma unroll
  for (int i=0;i<9;i++) nrm += F[i]*F[i];
  float inv = 1.0f/(nrm+1.0f);
  float i2 = (F[0]+F[4]+F[8])*(1.0f/3.0f);
  D2i[tid] = f2b(i2*inv);
  D2a[ab      ] = f2b(0.5f*(F[1]-F[3])*inv);
  D2a[ab + 128] = f2b(0.5f*(F[2]-F[6])*inv);
  D2a[ab + 256] = f2b(0.5f*(F[5]-F[7])*inv);
  D2s[sb      ] = f2b((F[0]-i2)*inv);
  D2s[sb + 128] = f2b(0.5f*(F[1]+F[3])*inv);
  D2s[sb + 256] = f2b(0.5f*(F[2]+F[6])*inv);
  D2s[sb + 384] = f2b((F[4]-i2)*inv);
  D2s[sb + 512] = f2b(0.5f*(F[5]+F[7])*inv);
  D2s[sb + 640] = f2b((F[8]-i2)*inv);
}

// Final: dX from P2 + b3; out = Xn + dX + dX*dX (dual-dtype out)
__global__ __launch_bounds__(256) void k_final(
    const void* __restrict__ X, const u16* __restrict__ P2i,
    const u16* __restrict__ P2a, const u16* __restrict__ P2s,
    const void* __restrict__ b3, void* __restrict__ out, int NH,
    const int* __restrict__ dflag)
{
  int tid = blockIdx.x*256 + threadIdx.x;
  if (tid >= NH) return;
  int isb = *dflag;
  int n = tid >> 7, c = tid & 127;
  float i1 = b2f(P2i[tid]);
  size_t ab = ((size_t)n*3)*128 + c;
  float a0 = b2f(P2a[ab]), a1 = b2f(P2a[ab+128]), a2 = b2f(P2a[ab+256]);
  size_t sb = ((size_t)n*6)*128 + c;
  float s0 = b2f(P2s[sb]),     s1 = b2f(P2s[sb+128]), s2 = b2f(P2s[sb+256]);
  float s3 = b2f(P2s[sb+384]), s4 = b2f(P2s[sb+512]), s5 = b2f(P2s[sb+640]);
  float B = ldx(b3,c,isb) + ldx(b3,128+c,isb) + ldx(b3,256+c,isb);
  float dX[9];
  dX[0]= i1+s0+B; dX[1]= a0+s1+B; dX[2]= a1+s2+B;
  dX[3]=-a0+s1+B; dX[4]= i1+s3+B; dX[5]= a2+s4+B;
  dX[6]=-a1+s2+B; dX[7]=-a2+s4+B; dX[8]= i1+s5+B;

  float x[9]; float nrm = 0.f;
#pragma unroll
  for (int i=0;i<9;i++){ x[i]=ldx(X,(size_t)tid*9+i,isb); nrm += x[i]*x[i]; }
  float inv = 1.0f/(nrm+1.0f);

#pragma unroll
  for (int i=0;i<3;i++)
#pragma unroll
    for (int j=0;j<3;j++){
      float acc = 0.f;
#pragma unroll
      for (int t=0;t<3;t++) acc += dX[i*3+t]*dX[t*3+j];
      float v = x[i*3+j]*inv + dX[i*3+j] + acc;
      size_t oi = (size_t)tid*9 + i*3 + j;
      if (isb) ((u16*)out)[oi] = f2b(v);
      else     ((float*)out)[oi] = v;
    }
}

extern "C" void kernel_launch(void* const* d_in, const int* in_sizes, int n_in,
                              void* d_out, int out_size, void* d_ws, size_t ws_size,
                              hipStream_t stream)
{
  const void* X    = d_in[0];
  const int*  ei   = (const int*)d_in[1];
  const void* ew   = d_in[2];
  const void* eatt = d_in[3];
  const void* W1   = d_in[4];
  const void* b1   = d_in[5];
  const void* W2a  = d_in[6];
  const void* b2a  = d_in[7];
  const void* W2b  = d_in[8];
  const void* b2b  = d_in[9];
  const void* W2c  = d_in[10];
  const void* b2c  = d_in[11];
  const void* W3   = d_in[12];
  const void* b3   = d_in[13];

  const int NH = in_sizes[0]/9;   // 20001*128
  const int E  = in_sizes[2];     // 200000
  const int N  = NH/128;

  auto aln = [](size_t x){ return (x + 255) & ~(size_t)255; };
  char* ws = (char*)d_ws;
  size_t off = 0;
  size_t o_flag = off; off += 256;
  size_t o_msg  = off; off += aln((size_t)NH*9*4);
  size_t o_Di   = off; off += aln((size_t)NH*2);
  size_t o_Da   = off; off += aln((size_t)NH*6);
  size_t o_Ds   = off; off += aln((size_t)NH*12);
  size_t o_Pi   = off; off += aln((size_t)NH*2);
  size_t o_Pa   = off; off += aln((size_t)NH*6);
  size_t o_Ps   = off; off += aln((size_t)NH*12);
  size_t o_cnt  = off; off += aln((size_t)N*4);
  size_t o_rp   = off; off += aln((size_t)(N+1)*4);
  size_t o_fill = off; off += aln((size_t)N*4);
  size_t o_eord = off; off += aln((size_t)E*4);
  size_t o_eattb= off; off += aln((size_t)E*64*2);   // eorder-permuted bf16 eatt
  size_t o_wb   = off; off += aln((size_t)237568*2); // bf16 weight copies
  size_t o_bf   = off; off += aln((size_t)768*4);    // f32 bias copies
  size_t persistent = off;

  // Per-edge chunk footprint: h1(256B)+h2(512B)+ea(768B)+Cc(4B) = 1540B
  int EC;
  {
    size_t avail = (ws_size > persistent + 4096) ? (ws_size - persistent - 4096) : 0;
    size_t ecmax = avail / 1540;
    if (ecmax > (size_t)E) ecmax = (size_t)E;
    EC = (int)(ecmax & ~(size_t)1023);
    if (EC < 1024) EC = 1024;
  }
  size_t o_h1 = persistent;
  size_t o_h2 = o_h1 + aln((size_t)EC*256);
  size_t o_ea = o_h2 + aln((size_t)EC*512);
  size_t o_Cc = o_ea + aln((size_t)EC*768);
  (void)n_in; (void)out_size;

  int* dflag = (int*)(ws + o_flag);
  u16* Di = (u16*)(ws + o_Di);
  u16* Da = (u16*)(ws + o_Da);
  u16* Ds = (u16*)(ws + o_Ds);
  u16* Pi = (u16*)(ws + o_Pi);
  u16* Pa = (u16*)(ws + o_Pa);
  u16* Ps = (u16*)(ws + o_Ps);
  float* msg = (float*)(ws + o_msg);
  int* counts = (int*)(ws + o_cnt);
  int* rowptr = (int*)(ws + o_rp);
  int* fill   = (int*)(ws + o_fill);
  int* eorder = (int*)(ws + o_eord);
  u16* eattb  = (u16*)(ws + o_eattb);
  u16* wb     = (u16*)(ws + o_wb);
  float* bf   = (float*)(ws + o_bf);
  u16* h1 = (u16*)(ws + o_h1);
  u16* h2 = (u16*)(ws + o_h2);
  u16* ea = (u16*)(ws + o_ea);
  float* Cc = (float*)(ws + o_Cc);

  dim3 blk(256);
  auto gemm = [&](const u16* A, const u16* Bw, const float* bias, const float* rs,
                  u16* C, int M, int Ncol, int K, int flags){
    dim3 grid(Ncol/128, (M+127)/128);
    k_mfma_gemm<<<grid, blk, 0, stream>>>(A, Bw, bias, rs, C, M, Ncol, K, flags);
  };

  // 0. sniff dtype; one-time bf16/f32 conversions of weights+biases
  k_sniff<<<1, blk, 0, stream>>>(X, dflag);
  k_cvt_weights<<<(237568+255)/256, blk, 0, stream>>>(W1, W3, W2a, W2b, W2c, wb, dflag);
  k_cvt_biases<<<3, blk, 0, stream>>>(b2a, b2b, b2c, bf, dflag);
  // 1. decompose
  k_decompose<<<(NH+255)/256, blk, 0, stream>>>(X, Di, Da, Ds, NH, dflag);
  // 2. node linears (W1) -> P components
  gemm(Di, wb,       nullptr, nullptr, Pi, N,   128, 128, 0);
  gemm(Da, wb+16384, nullptr, nullptr, Pa, 3*N, 128, 128, 0);
  gemm(Ds, wb+32768, nullptr, nullptr, Ps, 6*N, 128, 128, 0);
  // 3. zero msg accumulator; build CSR (sort edges by dst); permute eatt
  k_zero<<<((NH*9)+255)/256, blk, 0, stream>>>(msg, NH*9);
  k_zero_int<<<(N+255)/256, blk, 0, stream>>>(counts, N);
  k_hist<<<(E+255)/256, blk, 0, stream>>>(ei, counts, E);
  k_scan<<<1, blk, 0, stream>>>(counts, rowptr, fill, N);
  k_scatter<<<(E+255)/256, blk, 0, stream>>>(ei, fill, eorder, E);
  k_perm_eatt<<<(E+3)/4, blk, 0, stream>>>(eatt, eorder, eattb, E, dflag);
  // 4. edge MLP (dst-sorted order) + gather message passing, chunked
  for (int c0 = 0; c0 < E; c0 += EC){
    int ec = E - c0; if (ec > EC) ec = EC;
    k_cutoff<<<(ec+255)/256, blk, 0, stream>>>(ew, eorder, c0, Cc, ec, dflag);
    gemm(eattb + (size_t)c0*64, wb+98304,  bf,     nullptr, h1, ec, 128, 64,  1);
    gemm(h1,                    wb+106496, bf+128, nullptr, h2, ec, 256, 128, 1);
    gemm(h2,                    wb+139264, bf+384, Cc,      ea, ec, 384, 256, 1|2);
    k_gather<<<N, dim3(128), 0, stream>>>(rowptr, eorder, ei, E, c0, c0+ec,
                                          ea, Pi, Pa, Ps, b1, msg, NH, dflag);
  }
  // 5. update (writes D2 into D buffers; D dead)
  k_update<<<(NH+255)/256, blk, 0, stream>>>(msg, Pi, Pa, Ps, b1, Di, Da, Ds, NH, dflag);
  // 6. node linears (W3) -> P2 (reuses P buffers)
  gemm(Di, wb+49152, nullptr, nullptr, Pi, N,   128, 128, 0);
  gemm(Da, wb+65536, nullptr, nullptr, Pa, 3*N, 128, 128, 0);
  gemm(Ds, wb+81920, nullptr, nullptr, Ps, 6*N, 128, 128, 0);
  // 7. final output
  k_final<<<(NH+255)/256, blk, 0, stream>>>(X, Pi, Pa, Ps, b3, d_out, NH, dflag);
}

// Round 2
// 978.813 us; speedup vs baseline: 1.0451x; 1.0451x over previous
//
#include <hip/hip_runtime.h>
#include <math.h>
#include <stdint.h>

typedef unsigned short u16;
typedef __attribute__((ext_vector_type(8))) short short8;   // 8 bf16 (4 VGPRs)
typedef __attribute__((ext_vector_type(4))) float floatx4;  // MFMA acc

__device__ __forceinline__ float b2f(u16 u){
  union{unsigned int i; float f;} v; v.i = ((unsigned int)u)<<16; return v.f;
}
__device__ __forceinline__ u16 f2b(float f){
  union{unsigned int i; float f;} v; v.f = f;
  unsigned int r = (v.i + 0x7FFFu + ((v.i>>16)&1u))>>16;
  return (u16)r;
}
// dual-dtype external loads: isb=1 -> bf16(u16), isb=0 -> float32
__device__ __forceinline__ float ldx(const void* p, size_t i, int isb){
  return isb ? b2f(((const u16*)p)[i]) : ((const float*)p)[i];
}
// async global->LDS, 16B per lane; LDS dest = wave-uniform base + lane*16
__device__ __forceinline__ void gll16(const u16* g, u16* l){
  __builtin_amdgcn_global_load_lds(
      (const __attribute__((address_space(1))) unsigned int*)(g),
      (__attribute__((address_space(3))) unsigned int*)(l), 16, 0, 0);
}

// dtype sniffer: bf16 N(0,1) data has exponent field in [110,139] for ~all
// even-indexed u16s; f32 low-mantissa halves are uniform (~12% in window).
__global__ void k_sniff(const void* __restrict__ X, int* __restrict__ flag)
{
  __shared__ int cnt;
  if (threadIdx.x==0) cnt = 0;
  __syncthreads();
  int c = 0;
  for (int t = threadIdx.x; t < 512; t += 256){
    unsigned int u = ((const u16*)X)[2*t];
    int e = (u >> 7) & 0xFF;
    if (e >= 110 && e <= 139) c++;
  }
  atomicAdd(&cnt, c);
  __syncthreads();
  if (threadIdx.x==0) *flag = (cnt > 300) ? 1 : 0;
}

__global__ __launch_bounds__(256) void k_zero(float* __restrict__ p, int n)
{
  int i = blockIdx.x*256 + threadIdx.x;
  if (i < n) p[i] = 0.f;
}
__global__ __launch_bounds__(256) void k_zero_int(int* __restrict__ p, int n)
{
  int i = blockIdx.x*256 + threadIdx.x;
  if (i < n) p[i] = 0;
}

// CSR build: histogram of dst, block-scan to rowptr (+fill copy), scatter.
__global__ __launch_bounds__(256) void k_hist(
    const int* __restrict__ ei, int* __restrict__ counts, int E)
{
  int e = blockIdx.x*256 + threadIdx.x;
  if (e < E) atomicAdd(&counts[ei[e]], 1);
}
// single-block parallel scan: thread t owns a contiguous chunk of ~N/256
// counts; serial chunk sum -> one 256-wide Hillis-Steele (16 barriers total)
// -> serial chunk prefix write. Replaces the 79-pass version (89 us -> ~5 us).
__global__ __launch_bounds__(256) void k_scan(
    const int* __restrict__ counts, int* __restrict__ rowptr,
    int* __restrict__ fill, int N)
{
  __shared__ int sm[256];
  int tid = threadIdx.x;
  int per = (N + 255) >> 8;
  int lo = tid*per; if (lo > N) lo = N;
  int hi = lo + per; if (hi > N) hi = N;
  int s = 0;
  for (int i = lo; i < hi; i++) s += counts[i];
  sm[tid] = s;
  __syncthreads();
  for (int off=1; off<256; off<<=1){
    int t = (tid >= off) ? sm[tid-off] : 0;
    __syncthreads();
    sm[tid] += t;
    __syncthreads();
  }
  int run = sm[tid] - s;            // exclusive prefix of this thread's chunk
  for (int i = lo; i < hi; i++){
    int v = counts[i];
    rowptr[i] = run; fill[i] = run;
    run += v;
  }
  if (tid == 0) rowptr[N] = sm[255];
}
__global__ __launch_bounds__(256) void k_scatter(
    const int* __restrict__ ei, int* __restrict__ fill,
    int* __restrict__ eorder, int E)
{
  int e = blockIdx.x*256 + threadIdx.x;
  if (e >= E) return;
  int d = ei[e];
  int pos = atomicAdd(&fill[d], 1);
  eorder[pos] = e;
}

// one-time weight conversion to bf16 workspace copies.
// layout in out: [0,49152) W1 | [49152,98304) W3 | [98304,106496) W2a |
// [106496,139264) W2b | [139264,237568) W2c with row permute r->(r&127)*3+(r>>7)
__global__ __launch_bounds__(256) void k_cvt_weights(
    const void* __restrict__ W1, const void* __restrict__ W3,
    const void* __restrict__ W2a, const void* __restrict__ W2b,
    const void* __restrict__ W2c, u16* __restrict__ out,
    const int* __restrict__ dflag)
{
  int isb = *dflag;
  int i = blockIdx.x*256 + threadIdx.x;
  if (i >= 237568) return;
  float v;
  if (i < 49152)        v = ldx(W1, i, isb);
  else if (i < 98304)   v = ldx(W3, i-49152, isb);
  else if (i < 106496)  v = ldx(W2a, i-98304, isb);
  else if (i < 139264)  v = ldx(W2b, i-106496, isb);
  else {
    int j = i - 139264;
    int r = j >> 8, c = j & 255;
    v = ldx(W2c, (size_t)((r & 127)*3 + (r >> 7))*256 + c, isb);
  }
  out[i] = f2b(v);
}
// biases -> f32: [0,128) b2a | [128,384) b2b | [384,768) b2c (col-permuted)
__global__ __launch_bounds__(256) void k_cvt_biases(
    const void* __restrict__ b2a, const void* __restrict__ b2b,
    const void* __restrict__ b2c, float* __restrict__ out,
    const int* __restrict__ dflag)
{
  int isb = *dflag;
  int i = blockIdx.x*256 + threadIdx.x;
  if (i < 128) out[i] = ldx(b2a, i, isb);
  else if (i < 384) out[i] = ldx(b2b, i-128, isb);
  else if (i < 768){ int c = i-384; out[i] = ldx(b2c, (c&127)*3 + (c>>7), isb); }
}
// eatt (E x 64) -> bf16 rows permuted into dst-sorted edge order (eorder).
// Removes the row-gather from gemm1 entirely.
__global__ __launch_bounds__(256) void k_perm_eatt(
    const void* __restrict__ eatt, const int* __restrict__ eorder,
    u16* __restrict__ dst, int E, const int* __restrict__ dflag)
{
  int isb = *dflag;
  int row = blockIdx.x*4 + (threadIdx.x >> 6);
  int c = threadIdx.x & 63;
  if (row >= E) return;
  int e = eorder[row];
  dst[(size_t)row*64 + c] = f2b(ldx(eatt, (size_t)e*64 + c, isb));
}

// normalize X, decompose into 10 independent components (bf16)
__global__ __launch_bounds__(256) void k_decompose(
    const void* __restrict__ X, u16* __restrict__ Di, u16* __restrict__ Da,
    u16* __restrict__ Ds, int NH, const int* __restrict__ dflag)
{
  int tid = blockIdx.x*256 + threadIdx.x;
  if (tid >= NH) return;
  int isb = *dflag;
  int n = tid >> 7, k = tid & 127;
  float x[9]; float nrm = 0.f;
#pragma unroll
  for (int i=0;i<9;i++){ x[i]=ldx(X,(size_t)tid*9+i,isb); nrm += x[i]*x[i]; }
  float inv = 1.0f/(nrm+1.0f);
#pragma unroll
  for (int i=0;i<9;i++) x[i]*=inv;
  float i0 = (x[0]+x[4]+x[8])*(1.0f/3.0f);
  Di[tid] = f2b(i0);
  size_t ab = ((size_t)n*3)*128 + k;
  Da[ab      ] = f2b(0.5f*(x[1]-x[3]));
  Da[ab + 128] = f2b(0.5f*(x[2]-x[6]));
  Da[ab + 256] = f2b(0.5f*(x[5]-x[7]));
  size_t sb = ((size_t)n*6)*128 + k;
  Ds[sb      ] = f2b(x[0]-i0);
  Ds[sb + 128] = f2b(0.5f*(x[1]+x[3]));
  Ds[sb + 256] = f2b(0.5f*(x[2]+x[6]));
  Ds[sb + 384] = f2b(x[4]-i0);
  Ds[sb + 512] = f2b(0.5f*(x[5]+x[7]));
  Ds[sb + 640] = f2b(x[8]-i0);
}

// ---------------------------------------------------------------------------
// MFMA GEMM (m97 structure): C[M,Ncol](bf16) = A[M,K](bf16) * B[Ncol,K]^T(bf16)
// 128x128 tile, 4 waves (2x2 of 64x64), BK=32, mfma_f32_16x16x32_bf16.
// global_load_lds width-16 staging (linear LDS dest), XOR-swizzled granules:
// LDS(row, g) holds global 16B-granule q = g ^ ((row>>1)&3)  -> conflict-free
// ds_read_b128 on the fragment reads (8 lanes per 4-bank group, uniform).
// bias f32, flags: 1=silu, 2=rowscale.  Requires Ncol%128==0, K%32==0.
// Rows >= M are clamped to M-1 on load (garbage compute, never stored).
// ---------------------------------------------------------------------------
__global__ __launch_bounds__(256) void k_mfma_gemm(
    const u16* __restrict__ A, const u16* __restrict__ B,
    const float* __restrict__ bias, const float* __restrict__ rowscale,
    u16* __restrict__ C, int M, int Ncol, int K, int flags)
{
  __shared__ u16 As[4096];   // 128 rows x 32 u16 (64B/row), linear
  __shared__ u16 Bs[4096];
  const int tid = threadIdx.x;
  const int lane = tid & 63, l15 = lane & 15, q = lane >> 4;
  const int wid = tid >> 6, wm = wid & 1, wn = wid >> 1;
  const int n0 = blockIdx.x * 128, m0 = blockIdx.y * 128;

  // staging geometry: wave wid stages rows [wid*32, wid*32+32), 2 instrs (j=0,1)
  // lane -> row = wid*32 + j*16 + (lane>>2), LDS granule g = lane&3,
  // global granule q = g ^ ((row>>1)&3) = (lane&3) ^ ((lane>>3)&3)
  const int srow = wid*32 + (lane >> 2);
  const int qsrc = (lane & 3) ^ ((lane >> 3) & 3);
  int ar0 = m0 + srow;      if (ar0 >= M) ar0 = M-1;
  int ar1 = m0 + srow + 16; if (ar1 >= M) ar1 = M-1;
  const u16* aSrc0 = A + (size_t)ar0*K + qsrc*8;
  const u16* aSrc1 = A + (size_t)ar1*K + qsrc*8;
  const u16* bSrc0 = B + (size_t)(n0 + srow)*K + qsrc*8;
  const u16* bSrc1 = B + (size_t)(n0 + srow + 16)*K + qsrc*8;
  u16* aDst0 = &As[wid*1024];  u16* aDst1 = &As[wid*1024 + 512];
  u16* bDst0 = &Bs[wid*1024];  u16* bDst1 = &Bs[wid*1024 + 512];

  floatx4 acc[4][4];
#pragma unroll
  for (int i=0;i<4;i++)
#pragma unroll
    for (int j=0;j<4;j++) acc[i][j] = (floatx4)0.f;

  // fragment read swizzle: row = {wm,wn}*64 + t*16 + l15 -> (row>>1)&3 == (l15>>1)&3
  const int qsw  = ((q ^ ((l15 >> 1) & 3)) << 3);
  const int aBase = (wm*64 + l15)*32 + qsw;
  const int bBase = (wn*64 + l15)*32 + qsw;

  for (int k0 = 0; k0 < K; k0 += 32){
    gll16(aSrc0 + k0, aDst0);
    gll16(aSrc1 + k0, aDst1);
    gll16(bSrc0 + k0, bDst0);
    gll16(bSrc1 + k0, bDst1);
    __syncthreads();   // compiler drains vmcnt before s_barrier -> LDS ready
    short8 av[4], bv[4];
#pragma unroll
    for (int mt=0; mt<4; mt++)
      av[mt] = *reinterpret_cast<const short8*>(&As[aBase + mt*512]);
#pragma unroll
    for (int nt=0; nt<4; nt++)
      bv[nt] = *reinterpret_cast<const short8*>(&Bs[bBase + nt*512]);
#pragma unroll
    for (int mt=0; mt<4; mt++)
#pragma unroll
      for (int nt=0; nt<4; nt++)
        acc[mt][nt] = __builtin_amdgcn_mfma_f32_16x16x32_bf16(av[mt], bv[nt], acc[mt][nt], 0, 0, 0);
    __syncthreads();   // protect LDS before next iteration's overwrite
  }

  float biasv[4];
#pragma unroll
  for (int nt=0; nt<4; nt++)
    biasv[nt] = bias ? bias[n0 + wn*64 + nt*16 + l15] : 0.f;
#pragma unroll
  for (int mt=0; mt<4; mt++){
#pragma unroll
    for (int reg=0; reg<4; reg++){
      int row = m0 + wm*64 + mt*16 + q*4 + reg;
      if (row >= M) continue;
      float rs = (flags & 2) ? rowscale[row] : 1.0f;
#pragma unroll
      for (int nt=0; nt<4; nt++){
        int col = n0 + wn*64 + nt*16 + l15;
        float t = acc[mt][nt][reg] + biasv[nt];
        if (flags & 1) t = t / (1.0f + expf(-t));
        C[(size_t)row*Ncol + col] = f2b(t*rs);
      }
    }
  }
}

// cutoff factor per sorted edge (row i of chunk = edge eorder[c0+i])
__global__ __launch_bounds__(256) void k_cutoff(
    const void* __restrict__ ew, const int* __restrict__ eorder, int c0,
    float* __restrict__ Cc, int ec, const int* __restrict__ dflag)
{
  int i = blockIdx.x*256 + threadIdx.x;
  if (i >= ec) return;
  int e = eorder[c0 + i];
  float w = ldx(ew, e, *dflag);
  float c = 0.0f;
  if (w < 4.5f) c = 0.5f*(cosf(w*0.6981317007977318f) + 1.0f);
  Cc[i] = c;
}

// ---------------------------------------------------------------------------
// Gather message passing: block per dst node, 128 threads = channels.
// Edges sorted by dst; chunk [c0,c1). ea chunk layout [ec][3][128] (permB).
// Non-atomic msg += (one block per node; chunks sequential on stream).
// msg layout [9][NH] f32 (coalesced).
// ---------------------------------------------------------------------------
__global__ __launch_bounds__(128) void k_gather(
    const int* __restrict__ rowptr, const int* __restrict__ eorder,
    const int* __restrict__ ei, int E, int c0, int c1,
    const u16* __restrict__ ea,
    const u16* __restrict__ Pi, const u16* __restrict__ Pa,
    const u16* __restrict__ Ps, const void* __restrict__ b1,
    float* __restrict__ msg, int NH, const int* __restrict__ dflag)
{
  int n = blockIdx.x;
  int lo = rowptr[n], hi = rowptr[n+1];
  if (lo < c0) lo = c0;
  if (hi > c1) hi = c1;
  if (lo >= hi) return;
  int isb = *dflag;
  int c = threadIdx.x;
  float b0 = ldx(b1,c,isb), b1f = ldx(b1,128+c,isb), b2v = ldx(b1,256+c,isb);
  float m[9];
#pragma unroll
  for (int i=0;i<9;i++) m[i]=0.f;
  for (int idx = lo; idx < hi; idx++){
    int e = eorder[idx];
    int src = ei[E + e];
    const u16* er = ea + (size_t)(idx - c0)*384;
    float e0f = b2f(er[c]), e1f = b2f(er[128+c]), e2f = b2f(er[256+c]);
    float i1 = b2f(Pi[(size_t)src*128 + c]);
    size_t ab = (size_t)src*384 + c;
    float a0 = b2f(Pa[ab]), a1 = b2f(Pa[ab+128]), a2 = b2f(Pa[ab+256]);
    size_t sb = (size_t)src*768 + c;
    float s0 = b2f(Ps[sb]),     s1 = b2f(Ps[sb+128]), s2 = b2f(Ps[sb+256]);
    float s3 = b2f(Ps[sb+384]), s4 = b2f(Ps[sb+512]), s5 = b2f(Ps[sb+640]);
    float bb = e0f*b0 + e1f*b1f + e2f*b2v;
    float t0 = e0f*i1;
    m[0] += t0 + e2f*s0 + bb;
    m[1] += e1f*a0 + e2f*s1 + bb;
    m[2] += e1f*a1 + e2f*s2 + bb;
    m[3] += -e1f*a0 + e2f*s1 + bb;
    m[4] += t0 + e2f*s3 + bb;
    m[5] += e1f*a2 + e2f*s4 + bb;
    m[6] += -e1f*a1 + e2f*s2 + bb;
    m[7] += -e1f*a2 + e2f*s4 + bb;
    m[8] += t0 + e2f*s5 + bb;
  }
  size_t o = (size_t)n*128 + c;
#pragma unroll
  for (int i=0;i<9;i++) msg[(size_t)i*NH + o] += m[i];
}

// Update: F = msg*Y + Y*msg, renormalize, decompose -> D2 (bf16)
__global__ __launch_bounds__(256) void k_update(
    const float* __restrict__ msg, const u16* __restrict__ Pi,
    const u16* __restrict__ Pa, const u16* __restrict__ Ps,
    const void* __restrict__ b1,
    u16* __restrict__ D2i, u16* __restrict__ D2a, u16* __restrict__ D2s,
    int NH, const int* __restrict__ dflag)
{
  int tid = blockIdx.x*256 + threadIdx.x;
  if (tid >= NH) return;
  int isb = *dflag;
  int n = tid >> 7, c = tid & 127;
  float Mx[9];
#pragma unroll
  for (int i=0;i<9;i++) Mx[i] = msg[(size_t)i*NH + tid];
  float i1 = b2f(Pi[tid]);
  size_t ab = ((size_t)n*3)*128 + c;
  float a0 = b2f(Pa[ab]), a1 = b2f(Pa[ab+128]), a2 = b2f(Pa[ab+256]);
  size_t sb = ((size_t)n*6)*128 + c;
  float s0 = b2f(Ps[sb]),     s1 = b2f(Ps[sb+128]), s2 = b2f(Ps[sb+256]);
  float s3 = b2f(Ps[sb+384]), s4 = b2f(Ps[sb+512]), s5 = b2f(Ps[sb+640]);
  float B = ldx(b1,c,isb) + ldx(b1,128+c,isb) + ldx(b1,256+c,isb);
  float Y[9];
  Y[0]= i1+s0+B; Y[1]= a0+s1+B; Y[2]= a1+s2+B;
  Y[3]=-a0+s1+B; Y[4]= i1+s3+B; Y[5]= a2+s4+B;
  Y[6]=-a1+s2+B; Y[7]=-a2+s4+B; Y[8]= i1+s5+B;
  float F[9];
#pragma unroll
  for (int i=0;i<3;i++)
#pragma unroll
    for (int j=0;j<3;j++){
      float acc = 0.f;
#pragma unroll
      for (int t=0;t<3;t++)
        acc += Mx[i*3+t]*Y[t*3+j] + Y[i*3+t]*Mx[t*3+j];
      F[i*3+j] = acc;
    }
  float nrm = 0.f;
#pragma unroll
  for (int i=0;i<9;i++) nrm += F[i]*F[i];
  float inv = 1.0f/(nrm+1.0f);
  float i2 = (F[0]+F[4]+F[8])*(1.0f/3.0f);
  D2i[tid] = f2b(i2*inv);
  D2a[ab      ] = f2b(0.5f*(F[1]-F[3])*inv);
  D2a[ab + 128] = f2b(0.5f*(F[2]-F[6])*inv);
  D2a[ab + 256] = f2b(0.5f*(F[5]-F[7])*inv);
  D2s[sb      ] = f2b((F[0]-i2)*inv);
  D2s[sb + 128] = f2b(0.5f*(F[1]+F[3])*inv);
  D2s[sb + 256] = f2b(0.5f*(F[2]+F[6])*inv);
  D2s[sb + 384] = f2b((F[4]-i2)*inv);
  D2s[sb + 512] = f2b(0.5f*(F[5]+F[7])*inv);
  D2s[sb + 640] = f2b((F[8]-i2)*inv);
}

// Final: dX from P2 + b3; out = Xn + dX + dX*dX (dual-dtype out)
__global__ __launch_bounds__(256) void k_final(
    const void* __restrict__ X, const u16* __restrict__ P2i,
    const u16* __restrict__ P2a, const u16* __restrict__ P2s,
    const void* __restrict__ b3, void* __restrict__ out, int NH,
    const int* __restrict__ dflag)
{
  int tid = blockIdx.x*256 + threadIdx.x;
  if (tid >= NH) return;
  int isb = *dflag;
  int n = tid >> 7, c = tid & 127;
  float i1 = b2f(P2i[tid]);
  size_t ab = ((size_t)n*3)*128 + c;
  float a0 = b2f(P2a[ab]), a1 = b2f(P2a[ab+128]), a2 = b2f(P2a[ab+256]);
  size_t sb = ((size_t)n*6)*128 + c;
  float s0 = b2f(P2s[sb]),     s1 = b2f(P2s[sb+128]), s2 = b2f(P2s[sb+256]);
  float s3 = b2f(P2s[sb+384]), s4 = b2f(P2s[sb+512]), s5 = b2f(P2s[sb+640]);
  float B = ldx(b3,c,isb) + ldx(b3,128+c,isb) + ldx(b3,256+c,isb);
  float dX[9];
  dX[0]= i1+s0+B; dX[1]= a0+s1+B; dX[2]= a1+s2+B;
  dX[3]=-a0+s1+B; dX[4]= i1+s3+B; dX[5]= a2+s4+B;
  dX[6]=-a1+s2+B; dX[7]=-a2+s4+B; dX[8]= i1+s5+B;

  float x[9]; float nrm = 0.f;
#pragma unroll
  for (int i=0;i<9;i++){ x[i]=ldx(X,(size_t)tid*9+i,isb); nrm += x[i]*x[i]; }
  float inv = 1.0f/(nrm+1.0f);

#pragma unroll
  for (int i=0;i<3;i++)
#pragma unroll
    for (int j=0;j<3;j++){
      float acc = 0.f;
#pragma unroll
      for (int t=0;t<3;t++) acc += dX[i*3+t]*dX[t*3+j];
      float v = x[i*3+j]*inv + dX[i*3+j] + acc;
      size_t oi = (size_t)tid*9 + i*3 + j;
      if (isb) ((u16*)out)[oi] = f2b(v);
      else     ((float*)out)[oi] = v;
    }
}

extern "C" void kernel_launch(void* const* d_in, const int* in_sizes, int n_in,
                              void* d_out, int out_size, void* d_ws, size_t ws_size,
                              hipStream_t stream)
{
  const void* X    = d_in[0];
  const int*  ei   = (const int*)d_in[1];
  const void* ew   = d_in[2];
  const void* eatt = d_in[3];
  const void* W1   = d_in[4];
  const void* b1   = d_in[5];
  const void* W2a  = d_in[6];
  const void* b2a  = d_in[7];
  const void* W2b  = d_in[8];
  const void* b2b  = d_in[9];
  const void* W2c  = d_in[10];
  const void* b2c  = d_in[11];
  const void* W3   = d_in[12];
  const void* b3   = d_in[13];

  const int NH = in_sizes[0]/9;   // 20001*128
  const int E  = in_sizes[2];     // 200000
  const int N  = NH/128;

  auto aln = [](size_t x){ return (x + 255) & ~(size_t)255; };
  char* ws = (char*)d_ws;
  size_t off = 0;
  size_t o_flag = off; off += 256;
  size_t o_msg  = off; off += aln((size_t)NH*9*4);
  size_t o_Di   = off; off += aln((size_t)NH*2);
  size_t o_Da   = off; off += aln((size_t)NH*6);
  size_t o_Ds   = off; off += aln((size_t)NH*12);
  size_t o_Pi   = off; off += aln((size_t)NH*2);
  size_t o_Pa   = off; off += aln((size_t)NH*6);
  size_t o_Ps   = off; off += aln((size_t)NH*12);
  size_t o_cnt  = off; off += aln((size_t)N*4);
  size_t o_rp   = off; off += aln((size_t)(N+1)*4);
  size_t o_fill = off; off += aln((size_t)N*4);
  size_t o_eord = off; off += aln((size_t)E*4);
  size_t o_eattb= off; off += aln((size_t)E*64*2);   // eorder-permuted bf16 eatt
  size_t o_wb   = off; off += aln((size_t)237568*2); // bf16 weight copies
  size_t o_bf   = off; off += aln((size_t)768*4);    // f32 bias copies
  size_t persistent = off;

  // Per-edge chunk footprint: h1(256B)+h2(512B)+ea(768B)+Cc(4B) = 1540B
  int EC;
  {
    size_t avail = (ws_size > persistent + 4096) ? (ws_size - persistent - 4096) : 0;
    size_t ecmax = avail / 1540;
    if (ecmax > (size_t)E) ecmax = (size_t)E;
    EC = (int)(ecmax & ~(size_t)1023);
    if (EC < 1024) EC = 1024;
  }
  size_t o_h1 = persistent;
  size_t o_h2 = o_h1 + aln((size_t)EC*256);
  size_t o_ea = o_h2 + aln((size_t)EC*512);
  size_t o_Cc = o_ea + aln((size_t)EC*768);
  (void)n_in; (void)out_size;

  int* dflag = (int*)(ws + o_flag);
  u16* Di = (u16*)(ws + o_Di);
  u16* Da = (u16*)(ws + o_Da);
  u16* Ds = (u16*)(ws + o_Ds);
  u16* Pi = (u16*)(ws + o_Pi);
  u16* Pa = (u16*)(ws + o_Pa);
  u16* Ps = (u16*)(ws + o_Ps);
  float* msg = (float*)(ws + o_msg);
  int* counts = (int*)(ws + o_cnt);
  int* rowptr = (int*)(ws + o_rp);
  int* fill   = (int*)(ws + o_fill);
  int* eorder = (int*)(ws + o_eord);
  u16* eattb  = (u16*)(ws + o_eattb);
  u16* wb     = (u16*)(ws + o_wb);
  float* bf   = (float*)(ws + o_bf);
  u16* h1 = (u16*)(ws + o_h1);
  u16* h2 = (u16*)(ws + o_h2);
  u16* ea = (u16*)(ws + o_ea);
  float* Cc = (float*)(ws + o_Cc);

  dim3 blk(256);
  auto gemm = [&](const u16* A, const u16* Bw, const float* bias, const float* rs,
                  u16* C, int M, int Ncol, int K, int flags){
    dim3 grid(Ncol/128, (M+127)/128);
    k_mfma_gemm<<<grid, blk, 0, stream>>>(A, Bw, bias, rs, C, M, Ncol, K, flags);
  };

  // 0. sniff dtype; one-time bf16/f32 conversions of weights+biases
  k_sniff<<<1, blk, 0, stream>>>(X, dflag);
  k_cvt_weights<<<(237568+255)/256, blk, 0, stream>>>(W1, W3, W2a, W2b, W2c, wb, dflag);
  k_cvt_biases<<<3, blk, 0, stream>>>(b2a, b2b, b2c, bf, dflag);
  // 1. decompose
  k_decompose<<<(NH+255)/256, blk, 0, stream>>>(X, Di, Da, Ds, NH, dflag);
  // 2. node linears (W1) -> P components
  gemm(Di, wb,       nullptr, nullptr, Pi, N,   128, 128, 0);
  gemm(Da, wb+16384, nullptr, nullptr, Pa, 3*N, 128, 128, 0);
  gemm(Ds, wb+32768, nullptr, nullptr, Ps, 6*N, 128, 128, 0);
  // 3. zero msg accumulator; build CSR (sort edges by dst); permute eatt
  k_zero<<<((NH*9)+255)/256, blk, 0, stream>>>(msg, NH*9);
  k_zero_int<<<(N+255)/256, blk, 0, stream>>>(counts, N);
  k_hist<<<(E+255)/256, blk, 0, stream>>>(ei, counts, E);
  k_scan<<<1, blk, 0, stream>>>(counts, rowptr, fill, N);
  k_scatter<<<(E+255)/256, blk, 0, stream>>>(ei, fill, eorder, E);
  k_perm_eatt<<<(E+3)/4, blk, 0, stream>>>(eatt, eorder, eattb, E, dflag);
  // 4. edge MLP (dst-sorted order) + gather message passing, chunked
  for (int c0 = 0; c0 < E; c0 += EC){
    int ec = E - c0; if (ec > EC) ec = EC;
    k_cutoff<<<(ec+255)/256, blk, 0, stream>>>(ew, eorder, c0, Cc, ec, dflag);
    gemm(eattb + (size_t)c0*64, wb+98304,  bf,     nullptr, h1, ec, 128, 64,  1);
    gemm(h1,                    wb+106496, bf+128, nullptr, h2, ec, 256, 128, 1);
    gemm(h2,                    wb+139264, bf+384, Cc,      ea, ec, 384, 256, 1|2);
    k_gather<<<N, dim3(128), 0, stream>>>(rowptr, eorder, ei, E, c0, c0+ec,
                                          ea, Pi, Pa, Ps, b1, msg, NH, dflag);
  }
  // 5. update (writes D2 into D buffers; D dead)
  k_update<<<(NH+255)/256, blk, 0, stream>>>(msg, Pi, Pa, Ps, b1, Di, Da, Ds, NH, dflag);
  // 6. node linears (W3) -> P2 (reuses P buffers)
  gemm(Di, wb+49152, nullptr, nullptr, Pi, N,   128, 128, 0);
  gemm(Da, wb+65536, nullptr, nullptr, Pa, 3*N, 128, 128, 0);
  gemm(Ds, wb+81920, nullptr, nullptr, Ps, 6*N, 128, 128, 0);
  // 7. final output
  k_final<<<(NH+255)/256, blk, 0, stream>>>(X, Pi, Pa, Ps, b3, d_out, NH, dflag);
}

// Round 3
// 911.870 us; speedup vs baseline: 1.1218x; 1.0734x over previous
//
#include <hip/hip_runtime.h>
#include <math.h>
#include <stdint.h>

typedef unsigned short u16;
typedef __attribute__((ext_vector_type(8))) short short8;   // 8 bf16 (4 VGPRs)
typedef __attribute__((ext_vector_type(4))) float floatx4;  // MFMA acc

__device__ __forceinline__ float b2f(u16 u){
  union{unsigned int i; float f;} v; v.i = ((unsigned int)u)<<16; return v.f;
}
__device__ __forceinline__ u16 f2b(float f){
  union{unsigned int i; float f;} v; v.f = f;
  unsigned int r = (v.i + 0x7FFFu + ((v.i>>16)&1u))>>16;
  return (u16)r;
}
__device__ __forceinline__ unsigned int pu(u16 lo, u16 hi){
  return (unsigned int)lo | ((unsigned int)hi<<16);
}
__device__ __forceinline__ float gsel(unsigned int u, int s){
  return b2f((u16)(s ? (u>>16) : (u & 0xffffu)));
}
// dual-dtype external loads: isb=1 -> bf16(u16), isb=0 -> float32
__device__ __forceinline__ float ldx(const void* p, size_t i, int isb){
  return isb ? b2f(((const u16*)p)[i]) : ((const float*)p)[i];
}
// async global->LDS, 16B per lane; LDS dest = wave-uniform base + lane*16
__device__ __forceinline__ void gll16(const u16* g, u16* l){
  __builtin_amdgcn_global_load_lds(
      (const __attribute__((address_space(1))) unsigned int*)(g),
      (__attribute__((address_space(3))) unsigned int*)(l), 16, 0, 0);
}

// dtype sniffer: bf16 N(0,1) data has exponent field in [110,139] for ~all
// even-indexed u16s; f32 low-mantissa halves are uniform (~12% in window).
__global__ void k_sniff(const void* __restrict__ X, int* __restrict__ flag)
{
  __shared__ int cnt;
  if (threadIdx.x==0) cnt = 0;
  __syncthreads();
  int c = 0;
  for (int t = threadIdx.x; t < 512; t += 256){
    unsigned int u = ((const u16*)X)[2*t];
    int e = (u >> 7) & 0xFF;
    if (e >= 110 && e <= 139) c++;
  }
  atomicAdd(&cnt, c);
  __syncthreads();
  if (threadIdx.x==0) *flag = (cnt > 300) ? 1 : 0;
}

__global__ __launch_bounds__(256) void k_zero_int(int* __restrict__ p, int n)
{
  int i = blockIdx.x*256 + threadIdx.x;
  if (i < n) p[i] = 0;
}

// CSR build: histogram of dst, block-scan to rowptr (+fill copy), scatter.
__global__ __launch_bounds__(256) void k_hist(
    const int* __restrict__ ei, int* __restrict__ counts, int E)
{
  int e = blockIdx.x*256 + threadIdx.x;
  if (e < E) atomicAdd(&counts[ei[e]], 1);
}
// single-block parallel scan: thread t owns a contiguous chunk of ~N/256
// counts; serial chunk sum -> one 256-wide Hillis-Steele -> serial prefix.
__global__ __launch_bounds__(256) void k_scan(
    const int* __restrict__ counts, int* __restrict__ rowptr,
    int* __restrict__ fill, int N)
{
  __shared__ int sm[256];
  int tid = threadIdx.x;
  int per = (N + 255) >> 8;
  int lo = tid*per; if (lo > N) lo = N;
  int hi = lo + per; if (hi > N) hi = N;
  int s = 0;
  for (int i = lo; i < hi; i++) s += counts[i];
  sm[tid] = s;
  __syncthreads();
  for (int off=1; off<256; off<<=1){
    int t = (tid >= off) ? sm[tid-off] : 0;
    __syncthreads();
    sm[tid] += t;
    __syncthreads();
  }
  int run = sm[tid] - s;            // exclusive prefix of this thread's chunk
  for (int i = lo; i < hi; i++){
    int v = counts[i];
    rowptr[i] = run; fill[i] = run;
    run += v;
  }
  if (tid == 0) rowptr[N] = sm[255];
}
__global__ __launch_bounds__(256) void k_scatter(
    const int* __restrict__ ei, int* __restrict__ fill,
    int* __restrict__ eorder, int E)
{
  int e = blockIdx.x*256 + threadIdx.x;
  if (e >= E) return;
  int d = ei[e];
  int pos = atomicAdd(&fill[d], 1);
  eorder[pos] = e;
}

// one-time weight conversion to bf16 workspace copies.
// layout in out: [0,49152) W1 | [49152,98304) W3 | [98304,106496) W2a |
// [106496,139264) W2b | [139264,237568) W2c with row permute r->(r&127)*3+(r>>7)
__global__ __launch_bounds__(256) void k_cvt_weights(
    const void* __restrict__ W1, const void* __restrict__ W3,
    const void* __restrict__ W2a, const void* __restrict__ W2b,
    const void* __restrict__ W2c, u16* __restrict__ out,
    const int* __restrict__ dflag)
{
  int isb = *dflag;
  int i = blockIdx.x*256 + threadIdx.x;
  if (i >= 237568) return;
  float v;
  if (i < 49152)        v = ldx(W1, i, isb);
  else if (i < 98304)   v = ldx(W3, i-49152, isb);
  else if (i < 106496)  v = ldx(W2a, i-98304, isb);
  else if (i < 139264)  v = ldx(W2b, i-106496, isb);
  else {
    int j = i - 139264;
    int r = j >> 8, c = j & 255;
    v = ldx(W2c, (size_t)((r & 127)*3 + (r >> 7))*256 + c, isb);
  }
  out[i] = f2b(v);
}
// biases -> f32: [0,128) b2a | [128,384) b2b | [384,768) b2c (col-permuted)
__global__ __launch_bounds__(256) void k_cvt_biases(
    const void* __restrict__ b2a, const void* __restrict__ b2b,
    const void* __restrict__ b2c, float* __restrict__ out,
    const int* __restrict__ dflag)
{
  int isb = *dflag;
  int i = blockIdx.x*256 + threadIdx.x;
  if (i < 128) out[i] = ldx(b2a, i, isb);
  else if (i < 384) out[i] = ldx(b2b, i-128, isb);
  else if (i < 768){ int c = i-384; out[i] = ldx(b2c, (c&127)*3 + (c>>7), isb); }
}
// eatt (E x 64) -> bf16 rows permuted into dst-sorted edge order (eorder).
// 2 cols/thread: f32 reads float2 (8B/lane), writes packed u32 (4B/lane);
// bf16 input degenerates to a packed u32 copy.
__global__ __launch_bounds__(256) void k_perm_eatt(
    const void* __restrict__ eatt, const int* __restrict__ eorder,
    u16* __restrict__ dst, int E, const int* __restrict__ dflag)
{
  int isb = *dflag;
  int row = blockIdx.x*8 + (threadIdx.x >> 5);
  int cp = (threadIdx.x & 31)*2;
  if (row >= E) return;
  int e = eorder[row];
  unsigned int w;
  if (isb){
    w = *(const unsigned int*)((const u16*)eatt + (size_t)e*64 + cp);
  } else {
    float2 v = *(const float2*)((const float*)eatt + (size_t)e*64 + cp);
    w = pu(f2b(v.x), f2b(v.y));
  }
  *(unsigned int*)(dst + (size_t)row*64 + cp) = w;
}

// normalize X, decompose into 10 independent components (bf16).
// Block handles 512 tids: X staged via LDS with 16B/lane loads; each thread
// computes a PAIR of adjacent channels -> packed u32 component writes.
__global__ __launch_bounds__(256) void k_decompose(
    const void* __restrict__ X, u16* __restrict__ Di, u16* __restrict__ Da,
    u16* __restrict__ Ds, int NH, const int* __restrict__ dflag)
{
  __shared__ __align__(16) float buf[4608];   // 18 KB
  u16* bufu = (u16*)buf;
  int isb = *dflag;
  int tid = threadIdx.x;
  size_t t0 = (size_t)blockIdx.x*512;
  int validT = (int)((size_t)NH - t0); if (validT > 512) validT = 512;
  int ve = validT*9;
  if (isb){
    const u16* src = (const u16*)X + t0*9;
    for (int idx = tid; idx*8 < ve; idx += 256){
      if (idx*8+7 < ve) ((uint4*)bufu)[idx] = *(const uint4*)(src + idx*8);
      else for (int j=idx*8; j<ve; j++) bufu[j] = src[j];
    }
  } else {
    const float* src = (const float*)X + t0*9;
    for (int idx = tid; idx*4 < ve; idx += 256){
      if (idx*4+3 < ve) ((float4*)buf)[idx] = *(const float4*)(src + idx*4);
      else for (int j=idx*4; j<ve; j++) buf[j] = src[j];
    }
  }
  __syncthreads();
  int pairs = validT >> 1;
  if (tid >= pairs) return;
  int l2 = 2*tid;
  size_t tid2 = t0 + l2;
  int n = (int)(tid2 >> 7), c = (int)(tid2 & 127);
  u16 ri[2], ra[2][3], rs[2][6];
#pragma unroll
  for (int s=0; s<2; s++){
    float x[9]; float nrm = 0.f;
#pragma unroll
    for (int i=0;i<9;i++){
      x[i] = isb ? b2f(bufu[(l2+s)*9+i]) : buf[(l2+s)*9+i];
      nrm += x[i]*x[i];
    }
    float inv = 1.0f/(nrm+1.0f);
#pragma unroll
    for (int i=0;i<9;i++) x[i]*=inv;
    float i0 = (x[0]+x[4]+x[8])*(1.0f/3.0f);
    ri[s] = f2b(i0);
    ra[s][0] = f2b(0.5f*(x[1]-x[3]));
    ra[s][1] = f2b(0.5f*(x[2]-x[6]));
    ra[s][2] = f2b(0.5f*(x[5]-x[7]));
    rs[s][0] = f2b(x[0]-i0);
    rs[s][1] = f2b(0.5f*(x[1]+x[3]));
    rs[s][2] = f2b(0.5f*(x[2]+x[6]));
    rs[s][3] = f2b(x[4]-i0);
    rs[s][4] = f2b(0.5f*(x[5]+x[7]));
    rs[s][5] = f2b(x[8]-i0);
  }
  *(unsigned int*)&Di[tid2] = pu(ri[0], ri[1]);
  size_t ab = ((size_t)n*3)*128 + c;
#pragma unroll
  for (int j=0;j<3;j++)
    *(unsigned int*)&Da[ab + (size_t)j*128] = pu(ra[0][j], ra[1][j]);
  size_t sb = ((size_t)n*6)*128 + c;
#pragma unroll
  for (int j=0;j<6;j++)
    *(unsigned int*)&Ds[sb + (size_t)j*128] = pu(rs[0][j], rs[1][j]);
}

// ---------------------------------------------------------------------------
// MFMA GEMM (m97 structure): C[M,Ncol](bf16) = A[M,K](bf16) * B[Ncol,K]^T(bf16)
// 128x128 tile, 4 waves (2x2 of 64x64), BK=32, mfma_f32_16x16x32_bf16.
// global_load_lds width-16 staging (linear LDS dest), XOR-swizzled granules.
// bias f32, flags: 1=silu, 2=rowscale.  Requires Ncol%128==0, K%32==0.
// ---------------------------------------------------------------------------
__global__ __launch_bounds__(256) void k_mfma_gemm(
    const u16* __restrict__ A, const u16* __restrict__ B,
    const float* __restrict__ bias, const float* __restrict__ rowscale,
    u16* __restrict__ C, int M, int Ncol, int K, int flags)
{
  __shared__ u16 As[4096];   // 128 rows x 32 u16 (64B/row), linear
  __shared__ u16 Bs[4096];
  const int tid = threadIdx.x;
  const int lane = tid & 63, l15 = lane & 15, q = lane >> 4;
  const int wid = tid >> 6, wm = wid & 1, wn = wid >> 1;
  const int n0 = blockIdx.x * 128, m0 = blockIdx.y * 128;

  const int srow = wid*32 + (lane >> 2);
  const int qsrc = (lane & 3) ^ ((lane >> 3) & 3);
  int ar0 = m0 + srow;      if (ar0 >= M) ar0 = M-1;
  int ar1 = m0 + srow + 16; if (ar1 >= M) ar1 = M-1;
  const u16* aSrc0 = A + (size_t)ar0*K + qsrc*8;
  const u16* aSrc1 = A + (size_t)ar1*K + qsrc*8;
  const u16* bSrc0 = B + (size_t)(n0 + srow)*K + qsrc*8;
  const u16* bSrc1 = B + (size_t)(n0 + srow + 16)*K + qsrc*8;
  u16* aDst0 = &As[wid*1024];  u16* aDst1 = &As[wid*1024 + 512];
  u16* bDst0 = &Bs[wid*1024];  u16* bDst1 = &Bs[wid*1024 + 512];

  floatx4 acc[4][4];
#pragma unroll
  for (int i=0;i<4;i++)
#pragma unroll
    for (int j=0;j<4;j++) acc[i][j] = (floatx4)0.f;

  const int qsw  = ((q ^ ((l15 >> 1) & 3)) << 3);
  const int aBase = (wm*64 + l15)*32 + qsw;
  const int bBase = (wn*64 + l15)*32 + qsw;

  for (int k0 = 0; k0 < K; k0 += 32){
    gll16(aSrc0 + k0, aDst0);
    gll16(aSrc1 + k0, aDst1);
    gll16(bSrc0 + k0, bDst0);
    gll16(bSrc1 + k0, bDst1);
    __syncthreads();
    short8 av[4], bv[4];
#pragma unroll
    for (int mt=0; mt<4; mt++)
      av[mt] = *reinterpret_cast<const short8*>(&As[aBase + mt*512]);
#pragma unroll
    for (int nt=0; nt<4; nt++)
      bv[nt] = *reinterpret_cast<const short8*>(&Bs[bBase + nt*512]);
#pragma unroll
    for (int mt=0; mt<4; mt++)
#pragma unroll
      for (int nt=0; nt<4; nt++)
        acc[mt][nt] = __builtin_amdgcn_mfma_f32_16x16x32_bf16(av[mt], bv[nt], acc[mt][nt], 0, 0, 0);
    __syncthreads();
  }

  float biasv[4];
#pragma unroll
  for (int nt=0; nt<4; nt++)
    biasv[nt] = bias ? bias[n0 + wn*64 + nt*16 + l15] : 0.f;
#pragma unroll
  for (int mt=0; mt<4; mt++){
#pragma unroll
    for (int reg=0; reg<4; reg++){
      int row = m0 + wm*64 + mt*16 + q*4 + reg;
      if (row >= M) continue;
      float rs = (flags & 2) ? rowscale[row] : 1.0f;
#pragma unroll
      for (int nt=0; nt<4; nt++){
        int col = n0 + wn*64 + nt*16 + l15;
        float t = acc[mt][nt][reg] + biasv[nt];
        if (flags & 1) t = t / (1.0f + expf(-t));
        C[(size_t)row*Ncol + col] = f2b(t*rs);
      }
    }
  }
}

// cutoff factor per sorted edge (row i of chunk = edge eorder[c0+i])
__global__ __launch_bounds__(256) void k_cutoff(
    const void* __restrict__ ew, const int* __restrict__ eorder, int c0,
    float* __restrict__ Cc, int ec, const int* __restrict__ dflag)
{
  int i = blockIdx.x*256 + threadIdx.x;
  if (i >= ec) return;
  int e = eorder[c0 + i];
  float w = ldx(ew, e, *dflag);
  float c = 0.0f;
  if (w < 4.5f) c = 0.5f*(cosf(w*0.6981317007977318f) + 1.0f);
  Cc[i] = c;
}

// ---------------------------------------------------------------------------
// Gather message passing: block per dst node, 128 threads = channels.
// Edges sorted by dst; chunk [c0,c1). ea chunk layout [ec][3][128] (permB).
// first=1 (c0==0): assign msg (incl. zero for edge-less nodes) - replaces
// the separate 92MB k_zero pass. Later chunks accumulate.
// msg layout [9][NH] f32 (coalesced).
// ---------------------------------------------------------------------------
__global__ __launch_bounds__(128) void k_gather(
    const int* __restrict__ rowptr, const int* __restrict__ eorder,
    const int* __restrict__ ei, int E, int c0, int c1, int first,
    const u16* __restrict__ ea,
    const u16* __restrict__ Pi, const u16* __restrict__ Pa,
    const u16* __restrict__ Ps, const void* __restrict__ b1,
    float* __restrict__ msg, int NH, const int* __restrict__ dflag)
{
  int n = blockIdx.x;
  int lo = rowptr[n], hi = rowptr[n+1];
  if (lo < c0) lo = c0;
  if (hi > c1) hi = c1;
  if (!first && lo >= hi) return;
  int isb = *dflag;
  int c = threadIdx.x;
  float m[9];
#pragma unroll
  for (int i=0;i<9;i++) m[i]=0.f;
  if (lo < hi){
    float b0 = ldx(b1,c,isb), b1f = ldx(b1,128+c,isb), b2v = ldx(b1,256+c,isb);
    for (int idx = lo; idx < hi; idx++){
      int e = eorder[idx];
      int src = ei[E + e];
      const u16* er = ea + (size_t)(idx - c0)*384;
      float e0f = b2f(er[c]), e1f = b2f(er[128+c]), e2f = b2f(er[256+c]);
      float i1 = b2f(Pi[(size_t)src*128 + c]);
      size_t ab = (size_t)src*384 + c;
      float a0 = b2f(Pa[ab]), a1 = b2f(Pa[ab+128]), a2 = b2f(Pa[ab+256]);
      size_t sb = (size_t)src*768 + c;
      float s0 = b2f(Ps[sb]),     s1 = b2f(Ps[sb+128]), s2 = b2f(Ps[sb+256]);
      float s3 = b2f(Ps[sb+384]), s4 = b2f(Ps[sb+512]), s5 = b2f(Ps[sb+640]);
      float bb = e0f*b0 + e1f*b1f + e2f*b2v;
      float t0 = e0f*i1;
      m[0] += t0 + e2f*s0 + bb;
      m[1] += e1f*a0 + e2f*s1 + bb;
      m[2] += e1f*a1 + e2f*s2 + bb;
      m[3] += -e1f*a0 + e2f*s1 + bb;
      m[4] += t0 + e2f*s3 + bb;
      m[5] += e1f*a2 + e2f*s4 + bb;
      m[6] += -e1f*a1 + e2f*s2 + bb;
      m[7] += -e1f*a2 + e2f*s4 + bb;
      m[8] += t0 + e2f*s5 + bb;
    }
  }
  size_t o = (size_t)n*128 + c;
  if (first){
#pragma unroll
    for (int i=0;i<9;i++) msg[(size_t)i*NH + o] = m[i];
  } else {
#pragma unroll
    for (int i=0;i<9;i++) msg[(size_t)i*NH + o] += m[i];
  }
}

// Update: F = msg*Y + Y*msg, renormalize, decompose -> D2 (bf16).
// Pair of adjacent channels per thread: msg float2, components packed u32.
__global__ __launch_bounds__(256) void k_update(
    const float* __restrict__ msg, const u16* __restrict__ Pi,
    const u16* __restrict__ Pa, const u16* __restrict__ Ps,
    const void* __restrict__ b1,
    u16* __restrict__ D2i, u16* __restrict__ D2a, u16* __restrict__ D2s,
    int NH, const int* __restrict__ dflag)
{
  size_t tid2 = ((size_t)blockIdx.x*256 + threadIdx.x)*2;
  if (tid2 >= (size_t)NH) return;
  int isb = *dflag;
  int n = (int)(tid2 >> 7), c = (int)(tid2 & 127);
  float Mx[2][9];
#pragma unroll
  for (int i=0;i<9;i++){
    float2 v = *(const float2*)&msg[(size_t)i*NH + tid2];
    Mx[0][i] = v.x; Mx[1][i] = v.y;
  }
  unsigned int ui = *(const unsigned int*)&Pi[tid2];
  size_t ab = ((size_t)n*3)*128 + c;
  unsigned int ua[3];
#pragma unroll
  for (int j=0;j<3;j++) ua[j] = *(const unsigned int*)&Pa[ab + (size_t)j*128];
  size_t sb = ((size_t)n*6)*128 + c;
  unsigned int us[6];
#pragma unroll
  for (int j=0;j<6;j++) us[j] = *(const unsigned int*)&Ps[sb + (size_t)j*128];
  u16 ri[2], ra[2][3], rs[2][6];
#pragma unroll
  for (int s=0; s<2; s++){
    float i1 = gsel(ui,s);
    float a0 = gsel(ua[0],s), a1 = gsel(ua[1],s), a2 = gsel(ua[2],s);
    float s0 = gsel(us[0],s), s1 = gsel(us[1],s), s2 = gsel(us[2],s);
    float s3 = gsel(us[3],s), s4 = gsel(us[4],s), s5 = gsel(us[5],s);
    float B = ldx(b1,c+s,isb) + ldx(b1,128+c+s,isb) + ldx(b1,256+c+s,isb);
    float Y[9];
    Y[0]= i1+s0+B; Y[1]= a0+s1+B; Y[2]= a1+s2+B;
    Y[3]=-a0+s1+B; Y[4]= i1+s3+B; Y[5]= a2+s4+B;
    Y[6]=-a1+s2+B; Y[7]=-a2+s4+B; Y[8]= i1+s5+B;
    float F[9];
#pragma unroll
    for (int i=0;i<3;i++)
#pragma unroll
      for (int j=0;j<3;j++){
        float acc = 0.f;
#pragma unroll
        for (int t=0;t<3;t++)
          acc += Mx[s][i*3+t]*Y[t*3+j] + Y[i*3+t]*Mx[s][t*3+j];
        F[i*3+j] = acc;
      }
    float nrm = 0.f;
#pragma unroll
    for (int i=0;i<9;i++) nrm += F[i]*F[i];
    float inv = 1.0f/(nrm+1.0f);
    float i2 = (F[0]+F[4]+F[8])*(1.0f/3.0f);
    ri[s] = f2b(i2*inv);
    ra[s][0] = f2b(0.5f*(F[1]-F[3])*inv);
    ra[s][1] = f2b(0.5f*(F[2]-F[6])*inv);
    ra[s][2] = f2b(0.5f*(F[5]-F[7])*inv);
    rs[s][0] = f2b((F[0]-i2)*inv);
    rs[s][1] = f2b(0.5f*(F[1]+F[3])*inv);
    rs[s][2] = f2b(0.5f*(F[2]+F[6])*inv);
    rs[s][3] = f2b((F[4]-i2)*inv);
    rs[s][4] = f2b(0.5f*(F[5]+F[7])*inv);
    rs[s][5] = f2b((F[8]-i2)*inv);
  }
  *(unsigned int*)&D2i[tid2] = pu(ri[0], ri[1]);
#pragma unroll
  for (int j=0;j<3;j++)
    *(unsigned int*)&D2a[ab + (size_t)j*128] = pu(ra[0][j], ra[1][j]);
#pragma unroll
  for (int j=0;j<6;j++)
    *(unsigned int*)&D2s[sb + (size_t)j*128] = pu(rs[0][j], rs[1][j]);
}

// Final: dX from P2 + b3; out = Xn + dX + dX*dX (dual-dtype out).
// Block handles 512 tids; X and out staged through LDS (16B/lane global);
// pair of channels per thread -> packed u32 P2 reads.
__global__ __launch_bounds__(256) void k_final(
    const void* __restrict__ X, const u16* __restrict__ P2i,
    const u16* __restrict__ P2a, const u16* __restrict__ P2s,
    const void* __restrict__ b3, void* __restrict__ out, int NH,
    const int* __restrict__ dflag)
{
  __shared__ __align__(16) float buf[4608];   // 18 KB; aliased u16 for bf16
  u16* bufu = (u16*)buf;
  int isb = *dflag;
  int tid = threadIdx.x;
  size_t t0 = (size_t)blockIdx.x*512;
  int validT = (int)((size_t)NH - t0); if (validT > 512) validT = 512;
  int ve = validT*9;
  // stage X
  if (isb){
    const u16* src = (const u16*)X + t0*9;
    for (int idx = tid; idx*8 < ve; idx += 256){
      if (idx*8+7 < ve) ((uint4*)bufu)[idx] = *(const uint4*)(src + idx*8);
      else for (int j=idx*8; j<ve; j++) bufu[j] = src[j];
    }
  } else {
    const float* src = (const float*)X + t0*9;
    for (int idx = tid; idx*4 < ve; idx += 256){
      if (idx*4+3 < ve) ((float4*)buf)[idx] = *(const float4*)(src + idx*4);
      else for (int j=idx*4; j<ve; j++) buf[j] = src[j];
    }
  }
  __syncthreads();
  int pairs = validT >> 1;
  int l2 = 2*tid;
  size_t tid2 = t0 + l2;
  float vout[2][9];
  if (tid < pairs){
    int n = (int)(tid2 >> 7), c = (int)(tid2 & 127);
    unsigned int ui = *(const unsigned int*)&P2i[tid2];
    size_t ab = ((size_t)n*3)*128 + c;
    unsigned int ua[3];
#pragma unroll
    for (int j=0;j<3;j++) ua[j] = *(const unsigned int*)&P2a[ab + (size_t)j*128];
    size_t sb = ((size_t)n*6)*128 + c;
    unsigned int us[6];
#pragma unroll
    for (int j=0;j<6;j++) us[j] = *(const unsigned int*)&P2s[sb + (size_t)j*128];
#pragma unroll
    for (int s=0; s<2; s++){
      float i1 = gsel(ui,s);
      float a0 = gsel(ua[0],s), a1 = gsel(ua[1],s), a2 = gsel(ua[2],s);
      float s0 = gsel(us[0],s), s1 = gsel(us[1],s), s2 = gsel(us[2],s);
      float s3 = gsel(us[3],s), s4 = gsel(us[4],s), s5 = gsel(us[5],s);
      float B = ldx(b3,c+s,isb) + ldx(b3,128+c+s,isb) + ldx(b3,256+c+s,isb);
      float dX[9];
      dX[0]= i1+s0+B; dX[1]= a0+s1+B; dX[2]= a1+s2+B;
      dX[3]=-a0+s1+B; dX[4]= i1+s3+B; dX[5]= a2+s4+B;
      dX[6]=-a1+s2+B; dX[7]=-a2+s4+B; dX[8]= i1+s5+B;
      float x[9]; float nrm = 0.f;
#pragma unroll
      for (int i=0;i<9;i++){
        x[i] = isb ? b2f(bufu[(l2+s)*9+i]) : buf[(l2+s)*9+i];
        nrm += x[i]*x[i];
      }
      float inv = 1.0f/(nrm+1.0f);
#pragma unroll
      for (int i=0;i<3;i++)
#pragma unroll
        for (int j=0;j<3;j++){
          float acc = 0.f;
#pragma unroll
          for (int t=0;t<3;t++) acc += dX[i*3+t]*dX[t*3+j];
          vout[s][i*3+j] = x[i*3+j]*inv + dX[i*3+j] + acc;
        }
    }
  }
  __syncthreads();   // all LDS reads of X done
  // stage outputs
  if (tid < pairs){
    if (isb){
#pragma unroll
      for (int s=0;s<2;s++)
#pragma unroll
        for (int i=0;i<9;i++) bufu[(l2+s)*9+i] = f2b(vout[s][i]);
    } else {
#pragma unroll
      for (int s=0;s<2;s++)
#pragma unroll
        for (int i=0;i<9;i++) buf[(l2+s)*9+i] = vout[s][i];
    }
  }
  __syncthreads();
  if (isb){
    u16* dst = (u16*)out + t0*9;
    for (int idx = tid; idx*8 < ve; idx += 256){
      if (idx*8+7 < ve) *(uint4*)(dst + idx*8) = ((const uint4*)bufu)[idx];
      else for (int j=idx*8; j<ve; j++) dst[j] = bufu[j];
    }
  } else {
    float* dst = (float*)out + t0*9;
    for (int idx = tid; idx*4 < ve; idx += 256){
      if (idx*4+3 < ve) *(float4*)(dst + idx*4) = ((const float4*)buf)[idx];
      else for (int j=idx*4; j<ve; j++) dst[j] = buf[j];
    }
  }
}

extern "C" void kernel_launch(void* const* d_in, const int* in_sizes, int n_in,
                              void* d_out, int out_size, void* d_ws, size_t ws_size,
                              hipStream_t stream)
{
  const void* X    = d_in[0];
  const int*  ei   = (const int*)d_in[1];
  const void* ew   = d_in[2];
  const void* eatt = d_in[3];
  const void* W1   = d_in[4];
  const void* b1   = d_in[5];
  const void* W2a  = d_in[6];
  const void* b2a  = d_in[7];
  const void* W2b  = d_in[8];
  const void* b2b  = d_in[9];
  const void* W2c  = d_in[10];
  const void* b2c  = d_in[11];
  const void* W3   = d_in[12];
  const void* b3   = d_in[13];

  const int NH = in_sizes[0]/9;   // 20001*128
  const int E  = in_sizes[2];     // 200000
  const int N  = NH/128;

  auto aln = [](size_t x){ return (x + 255) & ~(size_t)255; };
  char* ws = (char*)d_ws;
  size_t off = 0;
  size_t o_flag = off; off += 256;
  size_t o_msg  = off; off += aln((size_t)NH*9*4);
  size_t o_Di   = off; off += aln((size_t)NH*2);
  size_t o_Da   = off; off += aln((size_t)NH*6);
  size_t o_Ds   = off; off += aln((size_t)NH*12);
  size_t o_Pi   = off; off += aln((size_t)NH*2);
  size_t o_Pa   = off; off += aln((size_t)NH*6);
  size_t o_Ps   = off; off += aln((size_t)NH*12);
  size_t o_cnt  = off; off += aln((size_t)N*4);
  size_t o_rp   = off; off += aln((size_t)(N+1)*4);
  size_t o_fill = off; off += aln((size_t)N*4);
  size_t o_eord = off; off += aln((size_t)E*4);
  size_t o_eattb= off; off += aln((size_t)E*64*2);   // eorder-permuted bf16 eatt
  size_t o_wb   = off; off += aln((size_t)237568*2); // bf16 weight copies
  size_t o_bf   = off; off += aln((size_t)768*4);    // f32 bias copies
  size_t persistent = off;

  // Per-edge chunk footprint: h1(256B)+h2(512B)+ea(768B)+Cc(4B) = 1540B
  int EC;
  {
    size_t avail = (ws_size > persistent + 4096) ? (ws_size - persistent - 4096) : 0;
    size_t ecmax = avail / 1540;
    if (ecmax > (size_t)E) ecmax = (size_t)E;
    EC = (int)(ecmax & ~(size_t)1023);
    if (EC < 1024) EC = 1024;
  }
  size_t o_h1 = persistent;
  size_t o_h2 = o_h1 + aln((size_t)EC*256);
  size_t o_ea = o_h2 + aln((size_t)EC*512);
  size_t o_Cc = o_ea + aln((size_t)EC*768);
  (void)n_in; (void)out_size;

  int* dflag = (int*)(ws + o_flag);
  u16* Di = (u16*)(ws + o_Di);
  u16* Da = (u16*)(ws + o_Da);
  u16* Ds = (u16*)(ws + o_Ds);
  u16* Pi = (u16*)(ws + o_Pi);
  u16* Pa = (u16*)(ws + o_Pa);
  u16* Ps = (u16*)(ws + o_Ps);
  float* msg = (float*)(ws + o_msg);
  int* counts = (int*)(ws + o_cnt);
  int* rowptr = (int*)(ws + o_rp);
  int* fill   = (int*)(ws + o_fill);
  int* eorder = (int*)(ws + o_eord);
  u16* eattb  = (u16*)(ws + o_eattb);
  u16* wb     = (u16*)(ws + o_wb);
  float* bf   = (float*)(ws + o_bf);
  u16* h1 = (u16*)(ws + o_h1);
  u16* h2 = (u16*)(ws + o_h2);
  u16* ea = (u16*)(ws + o_ea);
  float* Cc = (float*)(ws + o_Cc);

  dim3 blk(256);
  auto gemm = [&](const u16* A, const u16* Bw, const float* bias, const float* rs,
                  u16* C, int M, int Ncol, int K, int flags){
    dim3 grid(Ncol/128, (M+127)/128);
    k_mfma_gemm<<<grid, blk, 0, stream>>>(A, Bw, bias, rs, C, M, Ncol, K, flags);
  };

  // 0. sniff dtype; one-time bf16/f32 conversions of weights+biases
  k_sniff<<<1, blk, 0, stream>>>(X, dflag);
  k_cvt_weights<<<(237568+255)/256, blk, 0, stream>>>(W1, W3, W2a, W2b, W2c, wb, dflag);
  k_cvt_biases<<<3, blk, 0, stream>>>(b2a, b2b, b2c, bf, dflag);
  // 1. decompose (512 tids/block)
  k_decompose<<<(NH+511)/512, blk, 0, stream>>>(X, Di, Da, Ds, NH, dflag);
  // 2. node linears (W1) -> P components
  gemm(Di, wb,       nullptr, nullptr, Pi, N,   128, 128, 0);
  gemm(Da, wb+16384, nullptr, nullptr, Pa, 3*N, 128, 128, 0);
  gemm(Ds, wb+32768, nullptr, nullptr, Ps, 6*N, 128, 128, 0);
  // 3. build CSR (sort edges by dst); permute eatt (msg zeroing folded into
  //    first k_gather chunk)
  k_zero_int<<<(N+255)/256, blk, 0, stream>>>(counts, N);
  k_hist<<<(E+255)/256, blk, 0, stream>>>(ei, counts, E);
  k_scan<<<1, blk, 0, stream>>>(counts, rowptr, fill, N);
  k_scatter<<<(E+255)/256, blk, 0, stream>>>(ei, fill, eorder, E);
  k_perm_eatt<<<(E+7)/8, blk, 0, stream>>>(eatt, eorder, eattb, E, dflag);
  // 4. edge MLP (dst-sorted order) + gather message passing, chunked
  for (int c0 = 0; c0 < E; c0 += EC){
    int ec = E - c0; if (ec > EC) ec = EC;
    k_cutoff<<<(ec+255)/256, blk, 0, stream>>>(ew, eorder, c0, Cc, ec, dflag);
    gemm(eattb + (size_t)c0*64, wb+98304,  bf,     nullptr, h1, ec, 128, 64,  1);
    gemm(h1,                    wb+106496, bf+128, nullptr, h2, ec, 256, 128, 1);
    gemm(h2,                    wb+139264, bf+384, Cc,      ea, ec, 384, 256, 1|2);
    k_gather<<<N, dim3(128), 0, stream>>>(rowptr, eorder, ei, E, c0, c0+ec,
                                          (c0==0)?1:0,
                                          ea, Pi, Pa, Ps, b1, msg, NH, dflag);
  }
  // 5. update (writes D2 into D buffers; D dead)
  k_update<<<(NH/2+255)/256, blk, 0, stream>>>(msg, Pi, Pa, Ps, b1, Di, Da, Ds, NH, dflag);
  // 6. node linears (W3) -> P2 (reuses P buffers)
  gemm(Di, wb+49152, nullptr, nullptr, Pi, N,   128, 128, 0);
  gemm(Da, wb+65536, nullptr, nullptr, Pa, 3*N, 128, 128, 0);
  gemm(Ds, wb+81920, nullptr, nullptr, Ps, 6*N, 128, 128, 0);
  // 7. final output (512 tids/block)
  k_final<<<(NH+511)/512, blk, 0, stream>>>(X, Pi, Pa, Ps, b3, d_out, NH, dflag);
}

// Round 4
// 839.954 us; speedup vs baseline: 1.2178x; 1.0856x over previous
//
#include <hip/hip_runtime.h>
#include <math.h>
#include <stdint.h>

typedef unsigned short u16;
typedef __attribute__((ext_vector_type(8))) short short8;   // 8 bf16 (4 VGPRs)
typedef __attribute__((ext_vector_type(4))) float floatx4;  // MFMA acc

__device__ __forceinline__ float b2f(u16 u){
  union{unsigned int i; float f;} v; v.i = ((unsigned int)u)<<16; return v.f;
}
__device__ __forceinline__ u16 f2b(float f){
  union{unsigned int i; float f;} v; v.f = f;
  unsigned int r = (v.i + 0x7FFFu + ((v.i>>16)&1u))>>16;
  return (u16)r;
}
__device__ __forceinline__ unsigned int pu(u16 lo, u16 hi){
  return (unsigned int)lo | ((unsigned int)hi<<16);
}
__device__ __forceinline__ float gsel(unsigned int u, int s){
  return b2f((u16)(s ? (u>>16) : (u & 0xffffu)));
}
// packed RNE f32->bf16 pair (v_cvt_pk_bf16_f32, same rounding as f2b)
__device__ __forceinline__ unsigned int cvtpk(float a, float b){
  unsigned int r;
  asm("v_cvt_pk_bf16_f32 %0, %1, %2" : "=v"(r) : "v"(a), "v"(b));
  return r;
}
// fast silu: t * rcp(1 + exp2(-t*log2e)); hw exp/rcp ~1ulp, exact at +-inf
__device__ __forceinline__ float fsilu(float t){
  float e = __builtin_amdgcn_exp2f(t * -1.442695040888963f);
  return t * __builtin_amdgcn_rcpf(1.0f + e);
}
// dual-dtype external loads: isb=1 -> bf16(u16), isb=0 -> float32
__device__ __forceinline__ float ldx(const void* p, size_t i, int isb){
  return isb ? b2f(((const u16*)p)[i]) : ((const float*)p)[i];
}
// async global->LDS, 16B per lane; LDS dest = wave-uniform base + lane*16
__device__ __forceinline__ void gll16(const u16* g, u16* l){
  __builtin_amdgcn_global_load_lds(
      (const __attribute__((address_space(1))) unsigned int*)(g),
      (__attribute__((address_space(3))) unsigned int*)(l), 16, 0, 0);
}

// dtype sniffer: bf16 N(0,1) data has exponent field in [110,139] for ~all
// even-indexed u16s; f32 low-mantissa halves are uniform (~12% in window).
__global__ void k_sniff(const void* __restrict__ X, int* __restrict__ flag)
{
  __shared__ int cnt;
  if (threadIdx.x==0) cnt = 0;
  __syncthreads();
  int c = 0;
  for (int t = threadIdx.x; t < 512; t += 256){
    unsigned int u = ((const u16*)X)[2*t];
    int e = (u >> 7) & 0xFF;
    if (e >= 110 && e <= 139) c++;
  }
  atomicAdd(&cnt, c);
  __syncthreads();
  if (threadIdx.x==0) *flag = (cnt > 300) ? 1 : 0;
}

__global__ __launch_bounds__(256) void k_zero_int(int* __restrict__ p, int n)
{
  int i = blockIdx.x*256 + threadIdx.x;
  if (i < n) p[i] = 0;
}

// CSR build: histogram of dst, block-scan to rowptr (+fill copy), scatter.
__global__ __launch_bounds__(256) void k_hist(
    const int* __restrict__ ei, int* __restrict__ counts, int E)
{
  int e = blockIdx.x*256 + threadIdx.x;
  if (e < E) atomicAdd(&counts[ei[e]], 1);
}
// single-block parallel scan: thread t owns a contiguous chunk of ~N/256
// counts; serial chunk sum -> one 256-wide Hillis-Steele -> serial prefix.
__global__ __launch_bounds__(256) void k_scan(
    const int* __restrict__ counts, int* __restrict__ rowptr,
    int* __restrict__ fill, int N)
{
  __shared__ int sm[256];
  int tid = threadIdx.x;
  int per = (N + 255) >> 8;
  int lo = tid*per; if (lo > N) lo = N;
  int hi = lo + per; if (hi > N) hi = N;
  int s = 0;
  for (int i = lo; i < hi; i++) s += counts[i];
  sm[tid] = s;
  __syncthreads();
  for (int off=1; off<256; off<<=1){
    int t = (tid >= off) ? sm[tid-off] : 0;
    __syncthreads();
    sm[tid] += t;
    __syncthreads();
  }
  int run = sm[tid] - s;            // exclusive prefix of this thread's chunk
  for (int i = lo; i < hi; i++){
    int v = counts[i];
    rowptr[i] = run; fill[i] = run;
    run += v;
  }
  if (tid == 0) rowptr[N] = sm[255];
}
__global__ __launch_bounds__(256) void k_scatter(
    const int* __restrict__ ei, int* __restrict__ fill,
    int* __restrict__ eorder, int E)
{
  int e = blockIdx.x*256 + threadIdx.x;
  if (e >= E) return;
  int d = ei[e];
  int pos = atomicAdd(&fill[d], 1);
  eorder[pos] = e;
}

// one-time weight conversion to bf16 workspace copies.
// layout in out: [0,49152) W1 | [49152,98304) W3 | [98304,106496) W2a |
// [106496,139264) W2b | [139264,237568) W2c with row permute r->(r&127)*3+(r>>7)
__global__ __launch_bounds__(256) void k_cvt_weights(
    const void* __restrict__ W1, const void* __restrict__ W3,
    const void* __restrict__ W2a, const void* __restrict__ W2b,
    const void* __restrict__ W2c, u16* __restrict__ out,
    const int* __restrict__ dflag)
{
  int isb = *dflag;
  int i = blockIdx.x*256 + threadIdx.x;
  if (i >= 237568) return;
  float v;
  if (i < 49152)        v = ldx(W1, i, isb);
  else if (i < 98304)   v = ldx(W3, i-49152, isb);
  else if (i < 106496)  v = ldx(W2a, i-98304, isb);
  else if (i < 139264)  v = ldx(W2b, i-106496, isb);
  else {
    int j = i - 139264;
    int r = j >> 8, c = j & 255;
    v = ldx(W2c, (size_t)((r & 127)*3 + (r >> 7))*256 + c, isb);
  }
  out[i] = f2b(v);
}
// biases -> f32: [0,128) b2a | [128,384) b2b | [384,768) b2c (col-permuted)
__global__ __launch_bounds__(256) void k_cvt_biases(
    const void* __restrict__ b2a, const void* __restrict__ b2b,
    const void* __restrict__ b2c, float* __restrict__ out,
    const int* __restrict__ dflag)
{
  int isb = *dflag;
  int i = blockIdx.x*256 + threadIdx.x;
  if (i < 128) out[i] = ldx(b2a, i, isb);
  else if (i < 384) out[i] = ldx(b2b, i-128, isb);
  else if (i < 768){ int c = i-384; out[i] = ldx(b2c, (c&127)*3 + (c>>7), isb); }
}
// eatt (E x 64) -> bf16 rows permuted into dst-sorted edge order (eorder).
// 2 cols/thread: f32 reads float2 (8B/lane), writes packed u32 (4B/lane);
// bf16 input degenerates to a packed u32 copy.
__global__ __launch_bounds__(256) void k_perm_eatt(
    const void* __restrict__ eatt, const int* __restrict__ eorder,
    u16* __restrict__ dst, int E, const int* __restrict__ dflag)
{
  int isb = *dflag;
  int row = blockIdx.x*8 + (threadIdx.x >> 5);
  int cp = (threadIdx.x & 31)*2;
  if (row >= E) return;
  int e = eorder[row];
  unsigned int w;
  if (isb){
    w = *(const unsigned int*)((const u16*)eatt + (size_t)e*64 + cp);
  } else {
    float2 v = *(const float2*)((const float*)eatt + (size_t)e*64 + cp);
    w = pu(f2b(v.x), f2b(v.y));
  }
  *(unsigned int*)(dst + (size_t)row*64 + cp) = w;
}

// normalize X, decompose into 10 independent components (bf16).
// Block handles 512 tids: X staged via LDS with 16B/lane loads; each thread
// computes a PAIR of adjacent channels -> packed u32 component writes.
__global__ __launch_bounds__(256) void k_decompose(
    const void* __restrict__ X, u16* __restrict__ Di, u16* __restrict__ Da,
    u16* __restrict__ Ds, int NH, const int* __restrict__ dflag)
{
  __shared__ __align__(16) float buf[4608];   // 18 KB
  u16* bufu = (u16*)buf;
  int isb = *dflag;
  int tid = threadIdx.x;
  size_t t0 = (size_t)blockIdx.x*512;
  int validT = (int)((size_t)NH - t0); if (validT > 512) validT = 512;
  int ve = validT*9;
  if (isb){
    const u16* src = (const u16*)X + t0*9;
    for (int idx = tid; idx*8 < ve; idx += 256){
      if (idx*8+7 < ve) ((uint4*)bufu)[idx] = *(const uint4*)(src + idx*8);
      else for (int j=idx*8; j<ve; j++) bufu[j] = src[j];
    }
  } else {
    const float* src = (const float*)X + t0*9;
    for (int idx = tid; idx*4 < ve; idx += 256){
      if (idx*4+3 < ve) ((float4*)buf)[idx] = *(const float4*)(src + idx*4);
      else for (int j=idx*4; j<ve; j++) buf[j] = src[j];
    }
  }
  __syncthreads();
  int pairs = validT >> 1;
  if (tid >= pairs) return;
  int l2 = 2*tid;
  size_t tid2 = t0 + l2;
  int n = (int)(tid2 >> 7), c = (int)(tid2 & 127);
  u16 ri[2], ra[2][3], rs[2][6];
#pragma unroll
  for (int s=0; s<2; s++){
    float x[9]; float nrm = 0.f;
#pragma unroll
    for (int i=0;i<9;i++){
      x[i] = isb ? b2f(bufu[(l2+s)*9+i]) : buf[(l2+s)*9+i];
      nrm += x[i]*x[i];
    }
    float inv = 1.0f/(nrm+1.0f);
#pragma unroll
    for (int i=0;i<9;i++) x[i]*=inv;
    float i0 = (x[0]+x[4]+x[8])*(1.0f/3.0f);
    ri[s] = f2b(i0);
    ra[s][0] = f2b(0.5f*(x[1]-x[3]));
    ra[s][1] = f2b(0.5f*(x[2]-x[6]));
    ra[s][2] = f2b(0.5f*(x[5]-x[7]));
    rs[s][0] = f2b(x[0]-i0);
    rs[s][1] = f2b(0.5f*(x[1]+x[3]));
    rs[s][2] = f2b(0.5f*(x[2]+x[6]));
    rs[s][3] = f2b(x[4]-i0);
    rs[s][4] = f2b(0.5f*(x[5]+x[7]));
    rs[s][5] = f2b(x[8]-i0);
  }
  *(unsigned int*)&Di[tid2] = pu(ri[0], ri[1]);
  size_t ab = ((size_t)n*3)*128 + c;
#pragma unroll
  for (int j=0;j<3;j++)
    *(unsigned int*)&Da[ab + (size_t)j*128] = pu(ra[0][j], ra[1][j]);
  size_t sb = ((size_t)n*6)*128 + c;
#pragma unroll
  for (int j=0;j<6;j++)
    *(unsigned int*)&Ds[sb + (size_t)j*128] = pu(rs[0][j], rs[1][j]);
}

// ---------------------------------------------------------------------------
// MFMA GEMM (m97 structure): C[M,Ncol](bf16) = A[M,K](bf16) * B[Ncol,K]^T(bf16)
// 128x128 tile, 4 waves (2x2 of 64x64), BK=32, mfma_f32_16x16x32_bf16.
// global_load_lds width-16 staging (linear LDS dest), XOR-swizzled granules.
// bias f32, flags: 1=silu, 2=rowscale.  Requires Ncol%128==0, K%32==0.
// Epilogue: fast-silu (hw exp2+rcp) + packed v_cvt_pk_bf16_f32 (RNE).
// ---------------------------------------------------------------------------
__global__ __launch_bounds__(256) void k_mfma_gemm(
    const u16* __restrict__ A, const u16* __restrict__ B,
    const float* __restrict__ bias, const float* __restrict__ rowscale,
    u16* __restrict__ C, int M, int Ncol, int K, int flags)
{
  __shared__ u16 As[4096];   // 128 rows x 32 u16 (64B/row), linear
  __shared__ u16 Bs[4096];
  const int tid = threadIdx.x;
  const int lane = tid & 63, l15 = lane & 15, q = lane >> 4;
  const int wid = tid >> 6, wm = wid & 1, wn = wid >> 1;
  const int n0 = blockIdx.x * 128, m0 = blockIdx.y * 128;

  const int srow = wid*32 + (lane >> 2);
  const int qsrc = (lane & 3) ^ ((lane >> 3) & 3);
  int ar0 = m0 + srow;      if (ar0 >= M) ar0 = M-1;
  int ar1 = m0 + srow + 16; if (ar1 >= M) ar1 = M-1;
  const u16* aSrc0 = A + (size_t)ar0*K + qsrc*8;
  const u16* aSrc1 = A + (size_t)ar1*K + qsrc*8;
  const u16* bSrc0 = B + (size_t)(n0 + srow)*K + qsrc*8;
  const u16* bSrc1 = B + (size_t)(n0 + srow + 16)*K + qsrc*8;
  u16* aDst0 = &As[wid*1024];  u16* aDst1 = &As[wid*1024 + 512];
  u16* bDst0 = &Bs[wid*1024];  u16* bDst1 = &Bs[wid*1024 + 512];

  floatx4 acc[4][4];
#pragma unroll
  for (int i=0;i<4;i++)
#pragma unroll
    for (int j=0;j<4;j++) acc[i][j] = (floatx4)0.f;

  const int qsw  = ((q ^ ((l15 >> 1) & 3)) << 3);
  const int aBase = (wm*64 + l15)*32 + qsw;
  const int bBase = (wn*64 + l15)*32 + qsw;

  for (int k0 = 0; k0 < K; k0 += 32){
    gll16(aSrc0 + k0, aDst0);
    gll16(aSrc1 + k0, aDst1);
    gll16(bSrc0 + k0, bDst0);
    gll16(bSrc1 + k0, bDst1);
    __syncthreads();
    short8 av[4], bv[4];
#pragma unroll
    for (int mt=0; mt<4; mt++)
      av[mt] = *reinterpret_cast<const short8*>(&As[aBase + mt*512]);
#pragma unroll
    for (int nt=0; nt<4; nt++)
      bv[nt] = *reinterpret_cast<const short8*>(&Bs[bBase + nt*512]);
#pragma unroll
    for (int mt=0; mt<4; mt++)
#pragma unroll
      for (int nt=0; nt<4; nt++)
        acc[mt][nt] = __builtin_amdgcn_mfma_f32_16x16x32_bf16(av[mt], bv[nt], acc[mt][nt], 0, 0, 0);
    __syncthreads();
  }

  float biasv[4];
#pragma unroll
  for (int nt=0; nt<4; nt++)
    biasv[nt] = bias ? bias[n0 + wn*64 + nt*16 + l15] : 0.f;
#pragma unroll
  for (int mt=0; mt<4; mt++){
#pragma unroll
    for (int reg=0; reg<4; reg++){
      int row = m0 + wm*64 + mt*16 + q*4 + reg;
      if (row >= M) continue;
      float rs = (flags & 2) ? rowscale[row] : 1.0f;
      float t[4];
#pragma unroll
      for (int nt=0; nt<4; nt++){
        float v = acc[mt][nt][reg] + biasv[nt];
        if (flags & 1) v = fsilu(v);
        t[nt] = v * rs;
      }
      unsigned int p0 = cvtpk(t[0], t[1]);
      unsigned int p1 = cvtpk(t[2], t[3]);
      size_t rb = (size_t)row*Ncol + n0 + wn*64 + l15;
      C[rb]      = (u16)(p0 & 0xffffu);
      C[rb + 16] = (u16)(p0 >> 16);
      C[rb + 32] = (u16)(p1 & 0xffffu);
      C[rb + 48] = (u16)(p1 >> 16);
    }
  }
}

// cutoff factor per sorted edge (row i of chunk = edge eorder[c0+i])
__global__ __launch_bounds__(256) void k_cutoff(
    const void* __restrict__ ew, const int* __restrict__ eorder, int c0,
    float* __restrict__ Cc, int ec, const int* __restrict__ dflag)
{
  int i = blockIdx.x*256 + threadIdx.x;
  if (i >= ec) return;
  int e = eorder[c0 + i];
  float w = ldx(ew, e, *dflag);
  float c = 0.0f;
  if (w < 4.5f) c = 0.5f*(cosf(w*0.6981317007977318f) + 1.0f);
  Cc[i] = c;
}

// ---------------------------------------------------------------------------
// Gather message passing: block per dst node, 128 threads = channels.
// Edges sorted by dst; chunk [c0,c1). ea chunk layout [ec][3][128] (permB).
// first=1 (c0==0): assign msg (incl. zero for edge-less nodes) - replaces
// the separate 92MB k_zero pass. Later chunks accumulate.
// msg layout [9][NH] f32 (coalesced).
// ---------------------------------------------------------------------------
__global__ __launch_bounds__(128) void k_gather(
    const int* __restrict__ rowptr, const int* __restrict__ eorder,
    const int* __restrict__ ei, int E, int c0, int c1, int first,
    const u16* __restrict__ ea,
    const u16* __restrict__ Pi, const u16* __restrict__ Pa,
    const u16* __restrict__ Ps, const void* __restrict__ b1,
    float* __restrict__ msg, int NH, const int* __restrict__ dflag)
{
  int n = blockIdx.x;
  int lo = rowptr[n], hi = rowptr[n+1];
  if (lo < c0) lo = c0;
  if (hi > c1) hi = c1;
  if (!first && lo >= hi) return;
  int isb = *dflag;
  int c = threadIdx.x;
  float m[9];
#pragma unroll
  for (int i=0;i<9;i++) m[i]=0.f;
  if (lo < hi){
    float b0 = ldx(b1,c,isb), b1f = ldx(b1,128+c,isb), b2v = ldx(b1,256+c,isb);
    for (int idx = lo; idx < hi; idx++){
      int e = eorder[idx];
      int src = ei[E + e];
      const u16* er = ea + (size_t)(idx - c0)*384;
      float e0f = b2f(er[c]), e1f = b2f(er[128+c]), e2f = b2f(er[256+c]);
      float i1 = b2f(Pi[(size_t)src*128 + c]);
      size_t ab = (size_t)src*384 + c;
      float a0 = b2f(Pa[ab]), a1 = b2f(Pa[ab+128]), a2 = b2f(Pa[ab+256]);
      size_t sb = (size_t)src*768 + c;
      float s0 = b2f(Ps[sb]),     s1 = b2f(Ps[sb+128]), s2 = b2f(Ps[sb+256]);
      float s3 = b2f(Ps[sb+384]), s4 = b2f(Ps[sb+512]), s5 = b2f(Ps[sb+640]);
      float bb = e0f*b0 + e1f*b1f + e2f*b2v;
      float t0 = e0f*i1;
      m[0] += t0 + e2f*s0 + bb;
      m[1] += e1f*a0 + e2f*s1 + bb;
      m[2] += e1f*a1 + e2f*s2 + bb;
      m[3] += -e1f*a0 + e2f*s1 + bb;
      m[4] += t0 + e2f*s3 + bb;
      m[5] += e1f*a2 + e2f*s4 + bb;
      m[6] += -e1f*a1 + e2f*s2 + bb;
      m[7] += -e1f*a2 + e2f*s4 + bb;
      m[8] += t0 + e2f*s5 + bb;
    }
  }
  size_t o = (size_t)n*128 + c;
  if (first){
#pragma unroll
    for (int i=0;i<9;i++) msg[(size_t)i*NH + o] = m[i];
  } else {
#pragma unroll
    for (int i=0;i<9;i++) msg[(size_t)i*NH + o] += m[i];
  }
}

// Update: F = msg*Y + Y*msg, renormalize, decompose -> D2 (bf16).
// Pair of adjacent channels per thread: msg float2, components packed u32.
__global__ __launch_bounds__(256) void k_update(
    const float* __restrict__ msg, const u16* __restrict__ Pi,
    const u16* __restrict__ Pa, const u16* __restrict__ Ps,
    const void* __restrict__ b1,
    u16* __restrict__ D2i, u16* __restrict__ D2a, u16* __restrict__ D2s,
    int NH, const int* __restrict__ dflag)
{
  size_t tid2 = ((size_t)blockIdx.x*256 + threadIdx.x)*2;
  if (tid2 >= (size_t)NH) return;
  int isb = *dflag;
  int n = (int)(tid2 >> 7), c = (int)(tid2 & 127);
  float Mx[2][9];
#pragma unroll
  for (int i=0;i<9;i++){
    float2 v = *(const float2*)&msg[(size_t)i*NH + tid2];
    Mx[0][i] = v.x; Mx[1][i] = v.y;
  }
  unsigned int ui = *(const unsigned int*)&Pi[tid2];
  size_t ab = ((size_t)n*3)*128 + c;
  unsigned int ua[3];
#pragma unroll
  for (int j=0;j<3;j++) ua[j] = *(const unsigned int*)&Pa[ab + (size_t)j*128];
  size_t sb = ((size_t)n*6)*128 + c;
  unsigned int us[6];
#pragma unroll
  for (int j=0;j<6;j++) us[j] = *(const unsigned int*)&Ps[sb + (size_t)j*128];
  u16 ri[2], ra[2][3], rs[2][6];
#pragma unroll
  for (int s=0; s<2; s++){
    float i1 = gsel(ui,s);
    float a0 = gsel(ua[0],s), a1 = gsel(ua[1],s), a2 = gsel(ua[2],s);
    float s0 = gsel(us[0],s), s1 = gsel(us[1],s), s2 = gsel(us[2],s);
    float s3 = gsel(us[3],s), s4 = gsel(us[4],s), s5 = gsel(us[5],s);
    float B = ldx(b1,c+s,isb) + ldx(b1,128+c+s,isb) + ldx(b1,256+c+s,isb);
    float Y[9];
    Y[0]= i1+s0+B; Y[1]= a0+s1+B; Y[2]= a1+s2+B;
    Y[3]=-a0+s1+B; Y[4]= i1+s3+B; Y[5]= a2+s4+B;
    Y[6]=-a1+s2+B; Y[7]=-a2+s4+B; Y[8]= i1+s5+B;
    float F[9];
#pragma unroll
    for (int i=0;i<3;i++)
#pragma unroll
      for (int j=0;j<3;j++){
        float acc = 0.f;
#pragma unroll
        for (int t=0;t<3;t++)
          acc += Mx[s][i*3+t]*Y[t*3+j] + Y[i*3+t]*Mx[s][t*3+j];
        F[i*3+j] = acc;
      }
    float nrm = 0.f;
#pragma unroll
    for (int i=0;i<9;i++) nrm += F[i]*F[i];
    float inv = 1.0f/(nrm+1.0f);
    float i2 = (F[0]+F[4]+F[8])*(1.0f/3.0f);
    ri[s] = f2b(i2*inv);
    ra[s][0] = f2b(0.5f*(F[1]-F[3])*inv);
    ra[s][1] = f2b(0.5f*(F[2]-F[6])*inv);
    ra[s][2] = f2b(0.5f*(F[5]-F[7])*inv);
    rs[s][0] = f2b((F[0]-i2)*inv);
    rs[s][1] = f2b(0.5f*(F[1]+F[3])*inv);
    rs[s][2] = f2b(0.5f*(F[2]+F[6])*inv);
    rs[s][3] = f2b((F[4]-i2)*inv);
    rs[s][4] = f2b(0.5f*(F[5]+F[7])*inv);
    rs[s][5] = f2b((F[8]-i2)*inv);
  }
  *(unsigned int*)&D2i[tid2] = pu(ri[0], ri[1]);
#pragma unroll
  for (int j=0;j<3;j++)
    *(unsigned int*)&D2a[ab + (size_t)j*128] = pu(ra[0][j], ra[1][j]);
#pragma unroll
  for (int j=0;j<6;j++)
    *(unsigned int*)&D2s[sb + (size_t)j*128] = pu(rs[0][j], rs[1][j]);
}

// Final: dX from P2 + b3; out = Xn + dX + dX*dX (dual-dtype out).
// Block handles 512 tids; X and out staged through LDS (16B/lane global);
// pair of channels per thread -> packed u32 P2 reads.
__global__ __launch_bounds__(256) void k_final(
    const void* __restrict__ X, const u16* __restrict__ P2i,
    const u16* __restrict__ P2a, const u16* __restrict__ P2s,
    const void* __restrict__ b3, void* __restrict__ out, int NH,
    const int* __restrict__ dflag)
{
  __shared__ __align__(16) float buf[4608];   // 18 KB; aliased u16 for bf16
  u16* bufu = (u16*)buf;
  int isb = *dflag;
  int tid = threadIdx.x;
  size_t t0 = (size_t)blockIdx.x*512;
  int validT = (int)((size_t)NH - t0); if (validT > 512) validT = 512;
  int ve = validT*9;
  // stage X
  if (isb){
    const u16* src = (const u16*)X + t0*9;
    for (int idx = tid; idx*8 < ve; idx += 256){
      if (idx*8+7 < ve) ((uint4*)bufu)[idx] = *(const uint4*)(src + idx*8);
      else for (int j=idx*8; j<ve; j++) bufu[j] = src[j];
    }
  } else {
    const float* src = (const float*)X + t0*9;
    for (int idx = tid; idx*4 < ve; idx += 256){
      if (idx*4+3 < ve) ((float4*)buf)[idx] = *(const float4*)(src + idx*4);
      else for (int j=idx*4; j<ve; j++) buf[j] = src[j];
    }
  }
  __syncthreads();
  int pairs = validT >> 1;
  int l2 = 2*tid;
  size_t tid2 = t0 + l2;
  float vout[2][9];
  if (tid < pairs){
    int n = (int)(tid2 >> 7), c = (int)(tid2 & 127);
    unsigned int ui = *(const unsigned int*)&P2i[tid2];
    size_t ab = ((size_t)n*3)*128 + c;
    unsigned int ua[3];
#pragma unroll
    for (int j=0;j<3;j++) ua[j] = *(const unsigned int*)&P2a[ab + (size_t)j*128];
    size_t sb = ((size_t)n*6)*128 + c;
    unsigned int us[6];
#pragma unroll
    for (int j=0;j<6;j++) us[j] = *(const unsigned int*)&P2s[sb + (size_t)j*128];
#pragma unroll
    for (int s=0; s<2; s++){
      float i1 = gsel(ui,s);
      float a0 = gsel(ua[0],s), a1 = gsel(ua[1],s), a2 = gsel(ua[2],s);
      float s0 = gsel(us[0],s), s1 = gsel(us[1],s), s2 = gsel(us[2],s);
      float s3 = gsel(us[3],s), s4 = gsel(us[4],s), s5 = gsel(us[5],s);
      float B = ldx(b3,c+s,isb) + ldx(b3,128+c+s,isb) + ldx(b3,256+c+s,isb);
      float dX[9];
      dX[0]= i1+s0+B; dX[1]= a0+s1+B; dX[2]= a1+s2+B;
      dX[3]=-a0+s1+B; dX[4]= i1+s3+B; dX[5]= a2+s4+B;
      dX[6]=-a1+s2+B; dX[7]=-a2+s4+B; dX[8]= i1+s5+B;
      float x[9]; float nrm = 0.f;
#pragma unroll
      for (int i=0;i<9;i++){
        x[i] = isb ? b2f(bufu[(l2+s)*9+i]) : buf[(l2+s)*9+i];
        nrm += x[i]*x[i];
      }
      float inv = 1.0f/(nrm+1.0f);
#pragma unroll
      for (int i=0;i<3;i++)
#pragma unroll
        for (int j=0;j<3;j++){
          float acc = 0.f;
#pragma unroll
          for (int t=0;t<3;t++) acc += dX[i*3+t]*dX[t*3+j];
          vout[s][i*3+j] = x[i*3+j]*inv + dX[i*3+j] + acc;
        }
    }
  }
  __syncthreads();   // all LDS reads of X done
  // stage outputs
  if (tid < pairs){
    if (isb){
#pragma unroll
      for (int s=0;s<2;s++)
#pragma unroll
        for (int i=0;i<9;i++) bufu[(l2+s)*9+i] = f2b(vout[s][i]);
    } else {
#pragma unroll
      for (int s=0;s<2;s++)
#pragma unroll
        for (int i=0;i<9;i++) buf[(l2+s)*9+i] = vout[s][i];
    }
  }
  __syncthreads();
  if (isb){
    u16* dst = (u16*)out + t0*9;
    for (int idx = tid; idx*8 < ve; idx += 256){
      if (idx*8+7 < ve) *(uint4*)(dst + idx*8) = ((const uint4*)bufu)[idx];
      else for (int j=idx*8; j<ve; j++) dst[j] = bufu[j];
    }
  } else {
    float* dst = (float*)out + t0*9;
    for (int idx = tid; idx*4 < ve; idx += 256){
      if (idx*4+3 < ve) *(float4*)(dst + idx*4) = ((const float4*)buf)[idx];
      else for (int j=idx*4; j<ve; j++) dst[j] = buf[j];
    }
  }
}

extern "C" void kernel_launch(void* const* d_in, const int* in_sizes, int n_in,
                              void* d_out, int out_size, void* d_ws, size_t ws_size,
                              hipStream_t stream)
{
  const void* X    = d_in[0];
  const int*  ei   = (const int*)d_in[1];
  const void* ew   = d_in[2];
  const void* eatt = d_in[3];
  const void* W1   = d_in[4];
  const void* b1   = d_in[5];
  const void* W2a  = d_in[6];
  const void* b2a  = d_in[7];
  const void* W2b  = d_in[8];
  const void* b2b  = d_in[9];
  const void* W2c  = d_in[10];
  const void* b2c  = d_in[11];
  const void* W3   = d_in[12];
  const void* b3   = d_in[13];

  const int NH = in_sizes[0]/9;   // 20001*128
  const int E  = in_sizes[2];     // 200000
  const int N  = NH/128;

  auto aln = [](size_t x){ return (x + 255) & ~(size_t)255; };
  char* ws = (char*)d_ws;
  size_t off = 0;
  size_t o_flag = off; off += 256;
  size_t o_msg  = off; off += aln((size_t)NH*9*4);
  size_t o_Di   = off; off += aln((size_t)NH*2);
  size_t o_Da   = off; off += aln((size_t)NH*6);
  size_t o_Ds   = off; off += aln((size_t)NH*12);
  size_t o_Pi   = off; off += aln((size_t)NH*2);
  size_t o_Pa   = off; off += aln((size_t)NH*6);
  size_t o_Ps   = off; off += aln((size_t)NH*12);
  size_t o_cnt  = off; off += aln((size_t)N*4);
  size_t o_rp   = off; off += aln((size_t)(N+1)*4);
  size_t o_fill = off; off += aln((size_t)N*4);
  size_t o_eord = off; off += aln((size_t)E*4);
  size_t o_eattb= off; off += aln((size_t)E*64*2);   // eorder-permuted bf16 eatt
  size_t o_wb   = off; off += aln((size_t)237568*2); // bf16 weight copies
  size_t o_bf   = off; off += aln((size_t)768*4);    // f32 bias copies
  size_t persistent = off;

  // Per-edge chunk footprint: h1(256B)+h2(512B)+ea(768B)+Cc(4B) = 1540B
  int EC;
  {
    size_t avail = (ws_size > persistent + 4096) ? (ws_size - persistent - 4096) : 0;
    size_t ecmax = avail / 1540;
    if (ecmax > (size_t)E) ecmax = (size_t)E;
    EC = (int)(ecmax & ~(size_t)1023);
    if (EC < 1024) EC = 1024;
  }
  size_t o_h1 = persistent;
  size_t o_h2 = o_h1 + aln((size_t)EC*256);
  size_t o_ea = o_h2 + aln((size_t)EC*512);
  size_t o_Cc = o_ea + aln((size_t)EC*768);
  (void)n_in; (void)out_size;

  int* dflag = (int*)(ws + o_flag);
  u16* Di = (u16*)(ws + o_Di);
  u16* Da = (u16*)(ws + o_Da);
  u16* Ds = (u16*)(ws + o_Ds);
  u16* Pi = (u16*)(ws + o_Pi);
  u16* Pa = (u16*)(ws + o_Pa);
  u16* Ps = (u16*)(ws + o_Ps);
  float* msg = (float*)(ws + o_msg);
  int* counts = (int*)(ws + o_cnt);
  int* rowptr = (int*)(ws + o_rp);
  int* fill   = (int*)(ws + o_fill);
  int* eorder = (int*)(ws + o_eord);
  u16* eattb  = (u16*)(ws + o_eattb);
  u16* wb     = (u16*)(ws + o_wb);
  float* bf   = (float*)(ws + o_bf);
  u16* h1 = (u16*)(ws + o_h1);
  u16* h2 = (u16*)(ws + o_h2);
  u16* ea = (u16*)(ws + o_ea);
  float* Cc = (float*)(ws + o_Cc);

  dim3 blk(256);
  auto gemm = [&](const u16* A, const u16* Bw, const float* bias, const float* rs,
                  u16* C, int M, int Ncol, int K, int flags){
    dim3 grid(Ncol/128, (M+127)/128);
    k_mfma_gemm<<<grid, blk, 0, stream>>>(A, Bw, bias, rs, C, M, Ncol, K, flags);
  };

  // 0. sniff dtype; one-time bf16/f32 conversions of weights+biases
  k_sniff<<<1, blk, 0, stream>>>(X, dflag);
  k_cvt_weights<<<(237568+255)/256, blk, 0, stream>>>(W1, W3, W2a, W2b, W2c, wb, dflag);
  k_cvt_biases<<<3, blk, 0, stream>>>(b2a, b2b, b2c, bf, dflag);
  // 1. decompose (512 tids/block)
  k_decompose<<<(NH+511)/512, blk, 0, stream>>>(X, Di, Da, Ds, NH, dflag);
  // 2. node linears (W1) -> P components
  gemm(Di, wb,       nullptr, nullptr, Pi, N,   128, 128, 0);
  gemm(Da, wb+16384, nullptr, nullptr, Pa, 3*N, 128, 128, 0);
  gemm(Ds, wb+32768, nullptr, nullptr, Ps, 6*N, 128, 128, 0);
  // 3. build CSR (sort edges by dst); permute eatt (msg zeroing folded into
  //    first k_gather chunk)
  k_zero_int<<<(N+255)/256, blk, 0, stream>>>(counts, N);
  k_hist<<<(E+255)/256, blk, 0, stream>>>(ei, counts, E);
  k_scan<<<1, blk, 0, stream>>>(counts, rowptr, fill, N);
  k_scatter<<<(E+255)/256, blk, 0, stream>>>(ei, fill, eorder, E);
  k_perm_eatt<<<(E+7)/8, blk, 0, stream>>>(eatt, eorder, eattb, E, dflag);
  // 4. edge MLP (dst-sorted order) + gather message passing, chunked
  for (int c0 = 0; c0 < E; c0 += EC){
    int ec = E - c0; if (ec > EC) ec = EC;
    k_cutoff<<<(ec+255)/256, blk, 0, stream>>>(ew, eorder, c0, Cc, ec, dflag);
    gemm(eattb + (size_t)c0*64, wb+98304,  bf,     nullptr, h1, ec, 128, 64,  1);
    gemm(h1,                    wb+106496, bf+128, nullptr, h2, ec, 256, 128, 1);
    gemm(h2,                    wb+139264, bf+384, Cc,      ea, ec, 384, 256, 1|2);
    k_gather<<<N, dim3(128), 0, stream>>>(rowptr, eorder, ei, E, c0, c0+ec,
                                          (c0==0)?1:0,
                                          ea, Pi, Pa, Ps, b1, msg, NH, dflag);
  }
  // 5. update (writes D2 into D buffers; D dead)
  k_update<<<(NH/2+255)/256, blk, 0, stream>>>(msg, Pi, Pa, Ps, b1, Di, Da, Ds, NH, dflag);
  // 6. node linears (W3) -> P2 (reuses P buffers)
  gemm(Di, wb+49152, nullptr, nullptr, Pi, N,   128, 128, 0);
  gemm(Da, wb+65536, nullptr, nullptr, Pa, 3*N, 128, 128, 0);
  gemm(Ds, wb+81920, nullptr, nullptr, Ps, 6*N, 128, 128, 0);
  // 7. final output (512 tids/block)
  k_final<<<(NH+511)/512, blk, 0, stream>>>(X, Pi, Pa, Ps, b3, d_out, NH, dflag);
}

// Round 5
// 829.948 us; speedup vs baseline: 1.2325x; 1.0121x over previous
//
#include <hip/hip_runtime.h>
#include <math.h>
#include <stdint.h>

typedef unsigned short u16;
typedef __attribute__((ext_vector_type(8))) short short8;   // 8 bf16 (4 VGPRs)
typedef __attribute__((ext_vector_type(4))) float floatx4;  // MFMA acc

__device__ __forceinline__ float b2f(u16 u){
  union{unsigned int i; float f;} v; v.i = ((unsigned int)u)<<16; return v.f;
}
__device__ __forceinline__ u16 f2b(float f){
  union{unsigned int i; float f;} v; v.f = f;
  unsigned int r = (v.i + 0x7FFFu + ((v.i>>16)&1u))>>16;
  return (u16)r;
}
__device__ __forceinline__ unsigned int pu(u16 lo, u16 hi){
  return (unsigned int)lo | ((unsigned int)hi<<16);
}
__device__ __forceinline__ float gsel(unsigned int u, int s){
  union{unsigned int i; float f;} v;
  v.i = s ? (u & 0xffff0000u) : (u << 16);
  return v.f;
}
// packed RNE f32->bf16 pair (v_cvt_pk_bf16_f32, same rounding as f2b)
__device__ __forceinline__ unsigned int cvtpk(float a, float b){
  unsigned int r;
  asm("v_cvt_pk_bf16_f32 %0, %1, %2" : "=v"(r) : "v"(a), "v"(b));
  return r;
}
// fast silu: t * rcp(1 + exp2(-t*log2e)); hw exp/rcp ~1ulp, exact at +-inf
__device__ __forceinline__ float fsilu(float t){
  float e = __builtin_amdgcn_exp2f(t * -1.442695040888963f);
  return t * __builtin_amdgcn_rcpf(1.0f + e);
}
// dual-dtype external loads: isb=1 -> bf16(u16), isb=0 -> float32
__device__ __forceinline__ float ldx(const void* p, size_t i, int isb){
  return isb ? b2f(((const u16*)p)[i]) : ((const float*)p)[i];
}
// async global->LDS, 16B per lane; LDS dest = wave-uniform base + lane*16
__device__ __forceinline__ void gll16(const u16* g, u16* l){
  __builtin_amdgcn_global_load_lds(
      (const __attribute__((address_space(1))) unsigned int*)(g),
      (__attribute__((address_space(3))) unsigned int*)(l), 16, 0, 0);
}

// dtype sniffer: bf16 N(0,1) data has exponent field in [110,139] for ~all
// even-indexed u16s; f32 low-mantissa halves are uniform (~12% in window).
__global__ void k_sniff(const void* __restrict__ X, int* __restrict__ flag)
{
  __shared__ int cnt;
  if (threadIdx.x==0) cnt = 0;
  __syncthreads();
  int c = 0;
  for (int t = threadIdx.x; t < 512; t += 256){
    unsigned int u = ((const u16*)X)[2*t];
    int e = (u >> 7) & 0xFF;
    if (e >= 110 && e <= 139) c++;
  }
  atomicAdd(&cnt, c);
  __syncthreads();
  if (threadIdx.x==0) *flag = (cnt > 300) ? 1 : 0;
}

__global__ __launch_bounds__(256) void k_zero_int(int* __restrict__ p, int n)
{
  int i = blockIdx.x*256 + threadIdx.x;
  if (i < n) p[i] = 0;
}

// CSR build: histogram of dst, block-scan to rowptr (+fill copy), scatter.
__global__ __launch_bounds__(256) void k_hist(
    const int* __restrict__ ei, int* __restrict__ counts, int E)
{
  int e = blockIdx.x*256 + threadIdx.x;
  if (e < E) atomicAdd(&counts[ei[e]], 1);
}
// single-block parallel scan: thread t owns a contiguous chunk of ~N/256
// counts; serial chunk sum -> one 256-wide Hillis-Steele -> serial prefix.
__global__ __launch_bounds__(256) void k_scan(
    const int* __restrict__ counts, int* __restrict__ rowptr,
    int* __restrict__ fill, int N)
{
  __shared__ int sm[256];
  int tid = threadIdx.x;
  int per = (N + 255) >> 8;
  int lo = tid*per; if (lo > N) lo = N;
  int hi = lo + per; if (hi > N) hi = N;
  int s = 0;
  for (int i = lo; i < hi; i++) s += counts[i];
  sm[tid] = s;
  __syncthreads();
  for (int off=1; off<256; off<<=1){
    int t = (tid >= off) ? sm[tid-off] : 0;
    __syncthreads();
    sm[tid] += t;
    __syncthreads();
  }
  int run = sm[tid] - s;            // exclusive prefix of this thread's chunk
  for (int i = lo; i < hi; i++){
    int v = counts[i];
    rowptr[i] = run; fill[i] = run;
    run += v;
  }
  if (tid == 0) rowptr[N] = sm[255];
}
// scatter also records srcs[pos] = src-node of the edge (dst-sorted order),
// collapsing gather's eorder->ei dependent chain to one load.
__global__ __launch_bounds__(256) void k_scatter(
    const int* __restrict__ ei, int* __restrict__ fill,
    int* __restrict__ eorder, int* __restrict__ srcs, int E)
{
  int e = blockIdx.x*256 + threadIdx.x;
  if (e >= E) return;
  int d = ei[e];
  int pos = atomicAdd(&fill[d], 1);
  eorder[pos] = e;
  srcs[pos] = ei[E + e];
}

// one-time weight conversion to bf16 workspace copies.
// layout in out: [0,49152) W1 | [49152,98304) W3 | [98304,106496) W2a |
// [106496,139264) W2b | [139264,237568) W2c with row permute r->(r&127)*3+(r>>7)
__global__ __launch_bounds__(256) void k_cvt_weights(
    const void* __restrict__ W1, const void* __restrict__ W3,
    const void* __restrict__ W2a, const void* __restrict__ W2b,
    const void* __restrict__ W2c, u16* __restrict__ out,
    const int* __restrict__ dflag)
{
  int isb = *dflag;
  int i = blockIdx.x*256 + threadIdx.x;
  if (i >= 237568) return;
  float v;
  if (i < 49152)        v = ldx(W1, i, isb);
  else if (i < 98304)   v = ldx(W3, i-49152, isb);
  else if (i < 106496)  v = ldx(W2a, i-98304, isb);
  else if (i < 139264)  v = ldx(W2b, i-106496, isb);
  else {
    int j = i - 139264;
    int r = j >> 8, c = j & 255;
    v = ldx(W2c, (size_t)((r & 127)*3 + (r >> 7))*256 + c, isb);
  }
  out[i] = f2b(v);
}
// biases -> f32: [0,128) b2a | [128,384) b2b | [384,768) b2c (col-permuted)
__global__ __launch_bounds__(256) void k_cvt_biases(
    const void* __restrict__ b2a, const void* __restrict__ b2b,
    const void* __restrict__ b2c, float* __restrict__ out,
    const int* __restrict__ dflag)
{
  int isb = *dflag;
  int i = blockIdx.x*256 + threadIdx.x;
  if (i < 128) out[i] = ldx(b2a, i, isb);
  else if (i < 384) out[i] = ldx(b2b, i-128, isb);
  else if (i < 768){ int c = i-384; out[i] = ldx(b2c, (c&127)*3 + (c>>7), isb); }
}
// eatt (E x 64) -> bf16 rows permuted into dst-sorted edge order (eorder).
// 2 cols/thread: f32 reads float2 (8B/lane), writes packed u32 (4B/lane);
// bf16 input degenerates to a packed u32 copy.
__global__ __launch_bounds__(256) void k_perm_eatt(
    const void* __restrict__ eatt, const int* __restrict__ eorder,
    u16* __restrict__ dst, int E, const int* __restrict__ dflag)
{
  int isb = *dflag;
  int row = blockIdx.x*8 + (threadIdx.x >> 5);
  int cp = (threadIdx.x & 31)*2;
  if (row >= E) return;
  int e = eorder[row];
  unsigned int w;
  if (isb){
    w = *(const unsigned int*)((const u16*)eatt + (size_t)e*64 + cp);
  } else {
    float2 v = *(const float2*)((const float*)eatt + (size_t)e*64 + cp);
    w = pu(f2b(v.x), f2b(v.y));
  }
  *(unsigned int*)(dst + (size_t)row*64 + cp) = w;
}

// normalize X, decompose into 10 independent components (bf16).
// Block handles 512 tids: X staged via LDS with 16B/lane loads; each thread
// computes a PAIR of adjacent channels -> packed u32 component writes.
__global__ __launch_bounds__(256) void k_decompose(
    const void* __restrict__ X, u16* __restrict__ Di, u16* __restrict__ Da,
    u16* __restrict__ Ds, int NH, const int* __restrict__ dflag)
{
  __shared__ __align__(16) float buf[4608];   // 18 KB
  u16* bufu = (u16*)buf;
  int isb = *dflag;
  int tid = threadIdx.x;
  size_t t0 = (size_t)blockIdx.x*512;
  int validT = (int)((size_t)NH - t0); if (validT > 512) validT = 512;
  int ve = validT*9;
  if (isb){
    const u16* src = (const u16*)X + t0*9;
    for (int idx = tid; idx*8 < ve; idx += 256){
      if (idx*8+7 < ve) ((uint4*)bufu)[idx] = *(const uint4*)(src + idx*8);
      else for (int j=idx*8; j<ve; j++) bufu[j] = src[j];
    }
  } else {
    const float* src = (const float*)X + t0*9;
    for (int idx = tid; idx*4 < ve; idx += 256){
      if (idx*4+3 < ve) ((float4*)buf)[idx] = *(const float4*)(src + idx*4);
      else for (int j=idx*4; j<ve; j++) buf[j] = src[j];
    }
  }
  __syncthreads();
  int pairs = validT >> 1;
  if (tid >= pairs) return;
  int l2 = 2*tid;
  size_t tid2 = t0 + l2;
  int n = (int)(tid2 >> 7), c = (int)(tid2 & 127);
  u16 ri[2], ra[2][3], rs[2][6];
#pragma unroll
  for (int s=0; s<2; s++){
    float x[9]; float nrm = 0.f;
#pragma unroll
    for (int i=0;i<9;i++){
      x[i] = isb ? b2f(bufu[(l2+s)*9+i]) : buf[(l2+s)*9+i];
      nrm += x[i]*x[i];
    }
    float inv = 1.0f/(nrm+1.0f);
#pragma unroll
    for (int i=0;i<9;i++) x[i]*=inv;
    float i0 = (x[0]+x[4]+x[8])*(1.0f/3.0f);
    ri[s] = f2b(i0);
    ra[s][0] = f2b(0.5f*(x[1]-x[3]));
    ra[s][1] = f2b(0.5f*(x[2]-x[6]));
    ra[s][2] = f2b(0.5f*(x[5]-x[7]));
    rs[s][0] = f2b(x[0]-i0);
    rs[s][1] = f2b(0.5f*(x[1]+x[3]));
    rs[s][2] = f2b(0.5f*(x[2]+x[6]));
    rs[s][3] = f2b(x[4]-i0);
    rs[s][4] = f2b(0.5f*(x[5]+x[7]));
    rs[s][5] = f2b(x[8]-i0);
  }
  *(unsigned int*)&Di[tid2] = pu(ri[0], ri[1]);
  size_t ab = ((size_t)n*3)*128 + c;
#pragma unroll
  for (int j=0;j<3;j++)
    *(unsigned int*)&Da[ab + (size_t)j*128] = pu(ra[0][j], ra[1][j]);
  size_t sb = ((size_t)n*6)*128 + c;
#pragma unroll
  for (int j=0;j<6;j++)
    *(unsigned int*)&Ds[sb + (size_t)j*128] = pu(rs[0][j], rs[1][j]);
}

// ---------------------------------------------------------------------------
// MFMA GEMM (m97 structure): C[M,Ncol](bf16) = A[M,K](bf16) * B[Ncol,K]^T(bf16)
// 128x128 tile, 4 waves (2x2 of 64x64), BK=32, mfma_f32_16x16x32_bf16.
// global_load_lds width-16 staging (linear LDS dest), XOR-swizzled granules.
// bias f32, flags: 1=silu, 2=rowscale.  Requires Ncol%128==0, K%32==0.
// Epilogue: fast-silu (hw exp2+rcp) + packed v_cvt_pk_bf16_f32 (RNE).
// ---------------------------------------------------------------------------
__global__ __launch_bounds__(256) void k_mfma_gemm(
    const u16* __restrict__ A, const u16* __restrict__ B,
    const float* __restrict__ bias, const float* __restrict__ rowscale,
    u16* __restrict__ C, int M, int Ncol, int K, int flags)
{
  __shared__ u16 As[4096];   // 128 rows x 32 u16 (64B/row), linear
  __shared__ u16 Bs[4096];
  const int tid = threadIdx.x;
  const int lane = tid & 63, l15 = lane & 15, q = lane >> 4;
  const int wid = tid >> 6, wm = wid & 1, wn = wid >> 1;
  const int n0 = blockIdx.x * 128, m0 = blockIdx.y * 128;

  const int srow = wid*32 + (lane >> 2);
  const int qsrc = (lane & 3) ^ ((lane >> 3) & 3);
  int ar0 = m0 + srow;      if (ar0 >= M) ar0 = M-1;
  int ar1 = m0 + srow + 16; if (ar1 >= M) ar1 = M-1;
  const u16* aSrc0 = A + (size_t)ar0*K + qsrc*8;
  const u16* aSrc1 = A + (size_t)ar1*K + qsrc*8;
  const u16* bSrc0 = B + (size_t)(n0 + srow)*K + qsrc*8;
  const u16* bSrc1 = B + (size_t)(n0 + srow + 16)*K + qsrc*8;
  u16* aDst0 = &As[wid*1024];  u16* aDst1 = &As[wid*1024 + 512];
  u16* bDst0 = &Bs[wid*1024];  u16* bDst1 = &Bs[wid*1024 + 512];

  floatx4 acc[4][4];
#pragma unroll
  for (int i=0;i<4;i++)
#pragma unroll
    for (int j=0;j<4;j++) acc[i][j] = (floatx4)0.f;

  const int qsw  = ((q ^ ((l15 >> 1) & 3)) << 3);
  const int aBase = (wm*64 + l15)*32 + qsw;
  const int bBase = (wn*64 + l15)*32 + qsw;

  for (int k0 = 0; k0 < K; k0 += 32){
    gll16(aSrc0 + k0, aDst0);
    gll16(aSrc1 + k0, aDst1);
    gll16(bSrc0 + k0, bDst0);
    gll16(bSrc1 + k0, bDst1);
    __syncthreads();
    short8 av[4], bv[4];
#pragma unroll
    for (int mt=0; mt<4; mt++)
      av[mt] = *reinterpret_cast<const short8*>(&As[aBase + mt*512]);
#pragma unroll
    for (int nt=0; nt<4; nt++)
      bv[nt] = *reinterpret_cast<const short8*>(&Bs[bBase + nt*512]);
#pragma unroll
    for (int mt=0; mt<4; mt++)
#pragma unroll
      for (int nt=0; nt<4; nt++)
        acc[mt][nt] = __builtin_amdgcn_mfma_f32_16x16x32_bf16(av[mt], bv[nt], acc[mt][nt], 0, 0, 0);
    __syncthreads();
  }

  float biasv[4];
#pragma unroll
  for (int nt=0; nt<4; nt++)
    biasv[nt] = bias ? bias[n0 + wn*64 + nt*16 + l15] : 0.f;
#pragma unroll
  for (int mt=0; mt<4; mt++){
#pragma unroll
    for (int reg=0; reg<4; reg++){
      int row = m0 + wm*64 + mt*16 + q*4 + reg;
      if (row >= M) continue;
      float rs = (flags & 2) ? rowscale[row] : 1.0f;
      float t[4];
#pragma unroll
      for (int nt=0; nt<4; nt++){
        float v = acc[mt][nt][reg] + biasv[nt];
        if (flags & 1) v = fsilu(v);
        t[nt] = v * rs;
      }
      unsigned int p0 = cvtpk(t[0], t[1]);
      unsigned int p1 = cvtpk(t[2], t[3]);
      size_t rb = (size_t)row*Ncol + n0 + wn*64 + l15;
      C[rb]      = (u16)(p0 & 0xffffu);
      C[rb + 16] = (u16)(p0 >> 16);
      C[rb + 32] = (u16)(p1 & 0xffffu);
      C[rb + 48] = (u16)(p1 >> 16);
    }
  }
}

// cutoff factor per sorted edge (row i of chunk = edge eorder[c0+i])
__global__ __launch_bounds__(256) void k_cutoff(
    const void* __restrict__ ew, const int* __restrict__ eorder, int c0,
    float* __restrict__ Cc, int ec, const int* __restrict__ dflag)
{
  int i = blockIdx.x*256 + threadIdx.x;
  if (i >= ec) return;
  int e = eorder[c0 + i];
  float w = ldx(ew, e, *dflag);
  float c = 0.0f;
  if (w < 4.5f) c = 0.5f*(cosf(w*0.6981317007977318f) + 1.0f);
  Cc[i] = c;
}

// ---------------------------------------------------------------------------
// Gather message passing: block per dst node. 128 threads = 2 edge slots x
// 64 channel-pairs: all ea/P loads are u32 (256B/wave-instr), slots walk
// alternating edges (2x MLP), combined via small LDS reduce. srcs[] gives
// the src node directly (no eorder/ei chain). msg RMW as float2.
// first=1 (c0==0): assign msg (incl. zero for edge-less nodes).
// ---------------------------------------------------------------------------
__global__ __launch_bounds__(128) void k_gather(
    const int* __restrict__ rowptr, const int* __restrict__ srcs,
    int c0, int c1, int first,
    const u16* __restrict__ ea,
    const u16* __restrict__ Pi, const u16* __restrict__ Pa,
    const u16* __restrict__ Ps, const void* __restrict__ b1,
    float* __restrict__ msg, int NH, const int* __restrict__ dflag)
{
  int n = blockIdx.x;
  int lo = rowptr[n], hi = rowptr[n+1];
  if (lo < c0) lo = c0;
  if (hi > c1) hi = c1;
  if (!first && lo >= hi) return;
  int tid = threadIdx.x;
  int slot = tid >> 6;          // 0/1 (wave-uniform)
  int cp = (tid & 63) * 2;      // channel pair base
  float m[2][9];
#pragma unroll
  for (int s=0;s<2;s++)
#pragma unroll
    for (int i=0;i<9;i++) m[s][i]=0.f;
  if (lo < hi){
    int isb = *dflag;
    float b0[2], b1v[2], b2v[2];
#pragma unroll
    for (int s=0;s<2;s++){
      b0[s]  = ldx(b1, cp+s,     isb);
      b1v[s] = ldx(b1, 128+cp+s, isb);
      b2v[s] = ldx(b1, 256+cp+s, isb);
    }
    for (int idx = lo + slot; idx < hi; idx += 2){
      int src = srcs[idx];
      const u16* er = ea + (size_t)(idx - c0)*384;
      unsigned int ue0 = *(const unsigned int*)(er + cp);
      unsigned int ue1 = *(const unsigned int*)(er + 128 + cp);
      unsigned int ue2 = *(const unsigned int*)(er + 256 + cp);
      unsigned int upi = *(const unsigned int*)(Pi + (size_t)src*128 + cp);
      size_t ab = (size_t)src*384 + cp;
      unsigned int ua0 = *(const unsigned int*)(Pa + ab);
      unsigned int ua1 = *(const unsigned int*)(Pa + ab + 128);
      unsigned int ua2 = *(const unsigned int*)(Pa + ab + 256);
      size_t sbb = (size_t)src*768 + cp;
      unsigned int us0 = *(const unsigned int*)(Ps + sbb);
      unsigned int us1 = *(const unsigned int*)(Ps + sbb + 128);
      unsigned int us2 = *(const unsigned int*)(Ps + sbb + 256);
      unsigned int us3 = *(const unsigned int*)(Ps + sbb + 384);
      unsigned int us4 = *(const unsigned int*)(Ps + sbb + 512);
      unsigned int us5 = *(const unsigned int*)(Ps + sbb + 640);
#pragma unroll
      for (int s=0;s<2;s++){
        float e0f = gsel(ue0,s), e1f = gsel(ue1,s), e2f = gsel(ue2,s);
        float i1 = gsel(upi,s);
        float a0 = gsel(ua0,s), a1 = gsel(ua1,s), a2 = gsel(ua2,s);
        float s0 = gsel(us0,s), s1 = gsel(us1,s), s2 = gsel(us2,s);
        float s3 = gsel(us3,s), s4 = gsel(us4,s), s5 = gsel(us5,s);
        float bb = e0f*b0[s] + e1f*b1v[s] + e2f*b2v[s];
        float t0 = e0f*i1;
        m[s][0] += t0 + e2f*s0 + bb;
        m[s][1] += e1f*a0 + e2f*s1 + bb;
        m[s][2] += e1f*a1 + e2f*s2 + bb;
        m[s][3] += -e1f*a0 + e2f*s1 + bb;
        m[s][4] += t0 + e2f*s3 + bb;
        m[s][5] += e1f*a2 + e2f*s4 + bb;
        m[s][6] += -e1f*a1 + e2f*s2 + bb;
        m[s][7] += -e1f*a2 + e2f*s4 + bb;
        m[s][8] += t0 + e2f*s5 + bb;
      }
    }
  }
  // combine slot1 into slot0 via LDS
  __shared__ float red[64][18];
  if (slot == 1){
#pragma unroll
    for (int s=0;s<2;s++)
#pragma unroll
      for (int i=0;i<9;i++) red[tid & 63][s*9+i] = m[s][i];
  }
  __syncthreads();
  if (slot == 0){
    int cl = tid & 63;
#pragma unroll
    for (int s=0;s<2;s++)
#pragma unroll
      for (int i=0;i<9;i++) m[s][i] += red[cl][s*9+i];
    size_t o = (size_t)n*128 + cp;
    if (first){
#pragma unroll
      for (int i=0;i<9;i++){
        float2 v = {m[0][i], m[1][i]};
        *(float2*)&msg[(size_t)i*NH + o] = v;
      }
    } else {
#pragma unroll
      for (int i=0;i<9;i++){
        float2* p = (float2*)&msg[(size_t)i*NH + o];
        float2 v = *p;
        v.x += m[0][i]; v.y += m[1][i];
        *p = v;
      }
    }
  }
}

// Update: F = msg*Y + Y*msg, renormalize, decompose -> D2 (bf16).
// Pair of adjacent channels per thread: msg float2, components packed u32.
__global__ __launch_bounds__(256) void k_update(
    const float* __restrict__ msg, const u16* __restrict__ Pi,
    const u16* __restrict__ Pa, const u16* __restrict__ Ps,
    const void* __restrict__ b1,
    u16* __restrict__ D2i, u16* __restrict__ D2a, u16* __restrict__ D2s,
    int NH, const int* __restrict__ dflag)
{
  size_t tid2 = ((size_t)blockIdx.x*256 + threadIdx.x)*2;
  if (tid2 >= (size_t)NH) return;
  int isb = *dflag;
  int n = (int)(tid2 >> 7), c = (int)(tid2 & 127);
  float Mx[2][9];
#pragma unroll
  for (int i=0;i<9;i++){
    float2 v = *(const float2*)&msg[(size_t)i*NH + tid2];
    Mx[0][i] = v.x; Mx[1][i] = v.y;
  }
  unsigned int ui = *(const unsigned int*)&Pi[tid2];
  size_t ab = ((size_t)n*3)*128 + c;
  unsigned int ua[3];
#pragma unroll
  for (int j=0;j<3;j++) ua[j] = *(const unsigned int*)&Pa[ab + (size_t)j*128];
  size_t sb = ((size_t)n*6)*128 + c;
  unsigned int us[6];
#pragma unroll
  for (int j=0;j<6;j++) us[j] = *(const unsigned int*)&Ps[sb + (size_t)j*128];
  u16 ri[2], ra[2][3], rs[2][6];
#pragma unroll
  for (int s=0; s<2; s++){
    float i1 = gsel(ui,s);
    float a0 = gsel(ua[0],s), a1 = gsel(ua[1],s), a2 = gsel(ua[2],s);
    float s0 = gsel(us[0],s), s1 = gsel(us[1],s), s2 = gsel(us[2],s);
    float s3 = gsel(us[3],s), s4 = gsel(us[4],s), s5 = gsel(us[5],s);
    float B = ldx(b1,c+s,isb) + ldx(b1,128+c+s,isb) + ldx(b1,256+c+s,isb);
    float Y[9];
    Y[0]= i1+s0+B; Y[1]= a0+s1+B; Y[2]= a1+s2+B;
    Y[3]=-a0+s1+B; Y[4]= i1+s3+B; Y[5]= a2+s4+B;
    Y[6]=-a1+s2+B; Y[7]=-a2+s4+B; Y[8]= i1+s5+B;
    float F[9];
#pragma unroll
    for (int i=0;i<3;i++)
#pragma unroll
      for (int j=0;j<3;j++){
        float acc = 0.f;
#pragma unroll
        for (int t=0;t<3;t++)
          acc += Mx[s][i*3+t]*Y[t*3+j] + Y[i*3+t]*Mx[s][t*3+j];
        F[i*3+j] = acc;
      }
    float nrm = 0.f;
#pragma unroll
    for (int i=0;i<9;i++) nrm += F[i]*F[i];
    float inv = 1.0f/(nrm+1.0f);
    float i2 = (F[0]+F[4]+F[8])*(1.0f/3.0f);
    ri[s] = f2b(i2*inv);
    ra[s][0] = f2b(0.5f*(F[1]-F[3])*inv);
    ra[s][1] = f2b(0.5f*(F[2]-F[6])*inv);
    ra[s][2] = f2b(0.5f*(F[5]-F[7])*inv);
    rs[s][0] = f2b((F[0]-i2)*inv);
    rs[s][1] = f2b(0.5f*(F[1]+F[3])*inv);
    rs[s][2] = f2b(0.5f*(F[2]+F[6])*inv);
    rs[s][3] = f2b((F[4]-i2)*inv);
    rs[s][4] = f2b(0.5f*(F[5]+F[7])*inv);
    rs[s][5] = f2b((F[8]-i2)*inv);
  }
  *(unsigned int*)&D2i[tid2] = pu(ri[0], ri[1]);
#pragma unroll
  for (int j=0;j<3;j++)
    *(unsigned int*)&D2a[ab + (size_t)j*128] = pu(ra[0][j], ra[1][j]);
#pragma unroll
  for (int j=0;j<6;j++)
    *(unsigned int*)&D2s[sb + (size_t)j*128] = pu(rs[0][j], rs[1][j]);
}

// Final: dX from P2 + b3; out = Xn + dX + dX*dX (dual-dtype out).
// Block handles 512 tids; X and out staged through LDS (16B/lane global);
// pair of channels per thread -> packed u32 P2 reads.
__global__ __launch_bounds__(256) void k_final(
    const void* __restrict__ X, const u16* __restrict__ P2i,
    const u16* __restrict__ P2a, const u16* __restrict__ P2s,
    const void* __restrict__ b3, void* __restrict__ out, int NH,
    const int* __restrict__ dflag)
{
  __shared__ __align__(16) float buf[4608];   // 18 KB; aliased u16 for bf16
  u16* bufu = (u16*)buf;
  int isb = *dflag;
  int tid = threadIdx.x;
  size_t t0 = (size_t)blockIdx.x*512;
  int validT = (int)((size_t)NH - t0); if (validT > 512) validT = 512;
  int ve = validT*9;
  // stage X
  if (isb){
    const u16* src = (const u16*)X + t0*9;
    for (int idx = tid; idx*8 < ve; idx += 256){
      if (idx*8+7 < ve) ((uint4*)bufu)[idx] = *(const uint4*)(src + idx*8);
      else for (int j=idx*8; j<ve; j++) bufu[j] = src[j];
    }
  } else {
    const float* src = (const float*)X + t0*9;
    for (int idx = tid; idx*4 < ve; idx += 256){
      if (idx*4+3 < ve) ((float4*)buf)[idx] = *(const float4*)(src + idx*4);
      else for (int j=idx*4; j<ve; j++) buf[j] = src[j];
    }
  }
  __syncthreads();
  int pairs = validT >> 1;
  int l2 = 2*tid;
  size_t tid2 = t0 + l2;
  float vout[2][9];
  if (tid < pairs){
    int n = (int)(tid2 >> 7), c = (int)(tid2 & 127);
    unsigned int ui = *(const unsigned int*)&P2i[tid2];
    size_t ab = ((size_t)n*3)*128 + c;
    unsigned int ua[3];
#pragma unroll
    for (int j=0;j<3;j++) ua[j] = *(const unsigned int*)&P2a[ab + (size_t)j*128];
    size_t sb = ((size_t)n*6)*128 + c;
    unsigned int us[6];
#pragma unroll
    for (int j=0;j<6;j++) us[j] = *(const unsigned int*)&P2s[sb + (size_t)j*128];
#pragma unroll
    for (int s=0; s<2; s++){
      float i1 = gsel(ui,s);
      float a0 = gsel(ua[0],s), a1 = gsel(ua[1],s), a2 = gsel(ua[2],s);
      float s0 = gsel(us[0],s), s1 = gsel(us[1],s), s2 = gsel(us[2],s);
      float s3 = gsel(us[3],s), s4 = gsel(us[4],s), s5 = gsel(us[5],s);
      float B = ldx(b3,c+s,isb) + ldx(b3,128+c+s,isb) + ldx(b3,256+c+s,isb);
      float dX[9];
      dX[0]= i1+s0+B; dX[1]= a0+s1+B; dX[2]= a1+s2+B;
      dX[3]=-a0+s1+B; dX[4]= i1+s3+B; dX[5]= a2+s4+B;
      dX[6]=-a1+s2+B; dX[7]=-a2+s4+B; dX[8]= i1+s5+B;
      float x[9]; float nrm = 0.f;
#pragma unroll
      for (int i=0;i<9;i++){
        x[i] = isb ? b2f(bufu[(l2+s)*9+i]) : buf[(l2+s)*9+i];
        nrm += x[i]*x[i];
      }
      float inv = 1.0f/(nrm+1.0f);
#pragma unroll
      for (int i=0;i<3;i++)
#pragma unroll
        for (int j=0;j<3;j++){
          float acc = 0.f;
#pragma unroll
          for (int t=0;t<3;t++) acc += dX[i*3+t]*dX[t*3+j];
          vout[s][i*3+j] = x[i*3+j]*inv + dX[i*3+j] + acc;
        }
    }
  }
  __syncthreads();   // all LDS reads of X done
  // stage outputs
  if (tid < pairs){
    if (isb){
#pragma unroll
      for (int s=0;s<2;s++)
#pragma unroll
        for (int i=0;i<9;i++) bufu[(l2+s)*9+i] = f2b(vout[s][i]);
    } else {
#pragma unroll
      for (int s=0;s<2;s++)
#pragma unroll
        for (int i=0;i<9;i++) buf[(l2+s)*9+i] = vout[s][i];
    }
  }
  __syncthreads();
  if (isb){
    u16* dst = (u16*)out + t0*9;
    for (int idx = tid; idx*8 < ve; idx += 256){
      if (idx*8+7 < ve) *(uint4*)(dst + idx*8) = ((const uint4*)bufu)[idx];
      else for (int j=idx*8; j<ve; j++) dst[j] = bufu[j];
    }
  } else {
    float* dst = (float*)out + t0*9;
    for (int idx = tid; idx*4 < ve; idx += 256){
      if (idx*4+3 < ve) *(float4*)(dst + idx*4) = ((const float4*)buf)[idx];
      else for (int j=idx*4; j<ve; j++) dst[j] = buf[j];
    }
  }
}

extern "C" void kernel_launch(void* const* d_in, const int* in_sizes, int n_in,
                              void* d_out, int out_size, void* d_ws, size_t ws_size,
                              hipStream_t stream)
{
  const void* X    = d_in[0];
  const int*  ei   = (const int*)d_in[1];
  const void* ew   = d_in[2];
  const void* eatt = d_in[3];
  const void* W1   = d_in[4];
  const void* b1   = d_in[5];
  const void* W2a  = d_in[6];
  const void* b2a  = d_in[7];
  const void* W2b  = d_in[8];
  const void* b2b  = d_in[9];
  const void* W2c  = d_in[10];
  const void* b2c  = d_in[11];
  const void* W3   = d_in[12];
  const void* b3   = d_in[13];

  const int NH = in_sizes[0]/9;   // 20001*128
  const int E  = in_sizes[2];     // 200000
  const int N  = NH/128;

  auto aln = [](size_t x){ return (x + 255) & ~(size_t)255; };
  char* ws = (char*)d_ws;
  size_t off = 0;
  size_t o_flag = off; off += 256;
  size_t o_msg  = off; off += aln((size_t)NH*9*4);
  size_t o_Di   = off; off += aln((size_t)NH*2);
  size_t o_Da   = off; off += aln((size_t)NH*6);
  size_t o_Ds   = off; off += aln((size_t)NH*12);
  size_t o_Pi   = off; off += aln((size_t)NH*2);
  size_t o_Pa   = off; off += aln((size_t)NH*6);
  size_t o_Ps   = off; off += aln((size_t)NH*12);
  size_t o_cnt  = off; off += aln((size_t)N*4);
  size_t o_rp   = off; off += aln((size_t)(N+1)*4);
  size_t o_fill = off; off += aln((size_t)N*4);
  size_t o_eord = off; off += aln((size_t)E*4);
  size_t o_srcs = off; off += aln((size_t)E*4);      // src node per sorted edge
  size_t o_eattb= off; off += aln((size_t)E*64*2);   // eorder-permuted bf16 eatt
  size_t o_wb   = off; off += aln((size_t)237568*2); // bf16 weight copies
  size_t o_bf   = off; off += aln((size_t)768*4);    // f32 bias copies
  size_t persistent = off;

  // Per-edge chunk footprint: h1(256B)+h2(512B)+ea(768B)+Cc(4B) = 1540B
  int EC;
  {
    size_t avail = (ws_size > persistent + 4096) ? (ws_size - persistent - 4096) : 0;
    size_t ecmax = avail / 1540;
    if (ecmax > (size_t)E) ecmax = (size_t)E;
    EC = (int)(ecmax & ~(size_t)1023);
    if (EC < 1024) EC = 1024;
  }
  size_t o_h1 = persistent;
  size_t o_h2 = o_h1 + aln((size_t)EC*256);
  size_t o_ea = o_h2 + aln((size_t)EC*512);
  size_t o_Cc = o_ea + aln((size_t)EC*768);
  (void)n_in; (void)out_size;

  int* dflag = (int*)(ws + o_flag);
  u16* Di = (u16*)(ws + o_Di);
  u16* Da = (u16*)(ws + o_Da);
  u16* Ds = (u16*)(ws + o_Ds);
  u16* Pi = (u16*)(ws + o_Pi);
  u16* Pa = (u16*)(ws + o_Pa);
  u16* Ps = (u16*)(ws + o_Ps);
  float* msg = (float*)(ws + o_msg);
  int* counts = (int*)(ws + o_cnt);
  int* rowptr = (int*)(ws + o_rp);
  int* fill   = (int*)(ws + o_fill);
  int* eorder = (int*)(ws + o_eord);
  int* srcs   = (int*)(ws + o_srcs);
  u16* eattb  = (u16*)(ws + o_eattb);
  u16* wb     = (u16*)(ws + o_wb);
  float* bf   = (float*)(ws + o_bf);
  u16* h1 = (u16*)(ws + o_h1);
  u16* h2 = (u16*)(ws + o_h2);
  u16* ea = (u16*)(ws + o_ea);
  float* Cc = (float*)(ws + o_Cc);

  dim3 blk(256);
  auto gemm = [&](const u16* A, const u16* Bw, const float* bias, const float* rs,
                  u16* C, int M, int Ncol, int K, int flags){
    dim3 grid(Ncol/128, (M+127)/128);
    k_mfma_gemm<<<grid, blk, 0, stream>>>(A, Bw, bias, rs, C, M, Ncol, K, flags);
  };

  // 0. sniff dtype; one-time bf16/f32 conversions of weights+biases
  k_sniff<<<1, blk, 0, stream>>>(X, dflag);
  k_cvt_weights<<<(237568+255)/256, blk, 0, stream>>>(W1, W3, W2a, W2b, W2c, wb, dflag);
  k_cvt_biases<<<3, blk, 0, stream>>>(b2a, b2b, b2c, bf, dflag);
  // 1. decompose (512 tids/block)
  k_decompose<<<(NH+511)/512, blk, 0, stream>>>(X, Di, Da, Ds, NH, dflag);
  // 2. node linears (W1) -> P components
  gemm(Di, wb,       nullptr, nullptr, Pi, N,   128, 128, 0);
  gemm(Da, wb+16384, nullptr, nullptr, Pa, 3*N, 128, 128, 0);
  gemm(Ds, wb+32768, nullptr, nullptr, Ps, 6*N, 128, 128, 0);
  // 3. build CSR (sort edges by dst; srcs recorded); permute eatt
  k_zero_int<<<(N+255)/256, blk, 0, stream>>>(counts, N);
  k_hist<<<(E+255)/256, blk, 0, stream>>>(ei, counts, E);
  k_scan<<<1, blk, 0, stream>>>(counts, rowptr, fill, N);
  k_scatter<<<(E+255)/256, blk, 0, stream>>>(ei, fill, eorder, srcs, E);
  k_perm_eatt<<<(E+7)/8, blk, 0, stream>>>(eatt, eorder, eattb, E, dflag);
  // 4. edge MLP (dst-sorted order) + gather message passing, chunked
  for (int c0 = 0; c0 < E; c0 += EC){
    int ec = E - c0; if (ec > EC) ec = EC;
    k_cutoff<<<(ec+255)/256, blk, 0, stream>>>(ew, eorder, c0, Cc, ec, dflag);
    gemm(eattb + (size_t)c0*64, wb+98304,  bf,     nullptr, h1, ec, 128, 64,  1);
    gemm(h1,                    wb+106496, bf+128, nullptr, h2, ec, 256, 128, 1);
    gemm(h2,                    wb+139264, bf+384, Cc,      ea, ec, 384, 256, 1|2);
    k_gather<<<N, dim3(128), 0, stream>>>(rowptr, srcs, c0, c0+ec,
                                          (c0==0)?1:0,
                                          ea, Pi, Pa, Ps, b1, msg, NH, dflag);
  }
  // 5. update (writes D2 into D buffers; D dead)
  k_update<<<(NH/2+255)/256, blk, 0, stream>>>(msg, Pi, Pa, Ps, b1, Di, Da, Ds, NH, dflag);
  // 6. node linears (W3) -> P2 (reuses P buffers)
  gemm(Di, wb+49152, nullptr, nullptr, Pi, N,   128, 128, 0);
  gemm(Da, wb+65536, nullptr, nullptr, Pa, 3*N, 128, 128, 0);
  gemm(Ds, wb+81920, nullptr, nullptr, Ps, 6*N, 128, 128, 0);
  // 7. final output (512 tids/block)
  k_final<<<(NH+511)/512, blk, 0, stream>>>(X, Pi, Pa, Ps, b3, d_out, NH, dflag);
}

// Round 6
// 808.475 us; speedup vs baseline: 1.2653x; 1.0266x over previous
//
#include <hip/hip_runtime.h>
#include <math.h>
#include <stdint.h>

typedef unsigned short u16;
typedef __attribute__((ext_vector_type(8))) short short8;   // 8 bf16 (4 VGPRs)
typedef __attribute__((ext_vector_type(4))) float floatx4;  // MFMA acc

__device__ __forceinline__ float b2f(u16 u){
  union{unsigned int i; float f;} v; v.i = ((unsigned int)u)<<16; return v.f;
}
__device__ __forceinline__ u16 f2b(float f){
  union{unsigned int i; float f;} v; v.f = f;
  unsigned int r = (v.i + 0x7FFFu + ((v.i>>16)&1u))>>16;
  return (u16)r;
}
__device__ __forceinline__ unsigned int pu(u16 lo, u16 hi){
  return (unsigned int)lo | ((unsigned int)hi<<16);
}
__device__ __forceinline__ float gsel(unsigned int u, int s){
  union{unsigned int i; float f;} v;
  v.i = s ? (u & 0xffff0000u) : (u << 16);
  return v.f;
}
// packed RNE f32->bf16 pair (v_cvt_pk_bf16_f32, same rounding as f2b)
__device__ __forceinline__ unsigned int cvtpk(float a, float b){
  unsigned int r;
  asm("v_cvt_pk_bf16_f32 %0, %1, %2" : "=v"(r) : "v"(a), "v"(b));
  return r;
}
// fast silu: t * rcp(1 + exp2(-t*log2e)); hw exp/rcp ~1ulp, exact at +-inf
__device__ __forceinline__ float fsilu(float t){
  float e = __builtin_amdgcn_exp2f(t * -1.442695040888963f);
  return t * __builtin_amdgcn_rcpf(1.0f + e);
}
// dual-dtype external loads: isb=1 -> bf16(u16), isb=0 -> float32
__device__ __forceinline__ float ldx(const void* p, size_t i, int isb){
  return isb ? b2f(((const u16*)p)[i]) : ((const float*)p)[i];
}
// async global->LDS, 16B per lane; LDS dest = wave-uniform base + lane*16
__device__ __forceinline__ void gll16(const u16* g, u16* l){
  __builtin_amdgcn_global_load_lds(
      (const __attribute__((address_space(1))) unsigned int*)(g),
      (__attribute__((address_space(3))) unsigned int*)(l), 16, 0, 0);
}

// dtype sniffer: bf16 N(0,1) data has exponent field in [110,139] for ~all
// even-indexed u16s; f32 low-mantissa halves are uniform (~12% in window).
__global__ void k_sniff(const void* __restrict__ X, int* __restrict__ flag)
{
  __shared__ int cnt;
  if (threadIdx.x==0) cnt = 0;
  __syncthreads();
  int c = 0;
  for (int t = threadIdx.x; t < 512; t += 256){
    unsigned int u = ((const u16*)X)[2*t];
    int e = (u >> 7) & 0xFF;
    if (e >= 110 && e <= 139) c++;
  }
  atomicAdd(&cnt, c);
  __syncthreads();
  if (threadIdx.x==0) *flag = (cnt > 300) ? 1 : 0;
}

__global__ __launch_bounds__(256) void k_zero_int(int* __restrict__ p, int n)
{
  int i = blockIdx.x*256 + threadIdx.x;
  if (i < n) p[i] = 0;
}

// CSR build: histogram of dst, block-scan to rowptr (+fill copy), scatter.
__global__ __launch_bounds__(256) void k_hist(
    const int* __restrict__ ei, int* __restrict__ counts, int E)
{
  int e = blockIdx.x*256 + threadIdx.x;
  if (e < E) atomicAdd(&counts[ei[e]], 1);
}
// single-block parallel scan: thread t owns a contiguous chunk of ~N/256
// counts; serial chunk sum -> one 256-wide Hillis-Steele -> serial prefix.
__global__ __launch_bounds__(256) void k_scan(
    const int* __restrict__ counts, int* __restrict__ rowptr,
    int* __restrict__ fill, int N)
{
  __shared__ int sm[256];
  int tid = threadIdx.x;
  int per = (N + 255) >> 8;
  int lo = tid*per; if (lo > N) lo = N;
  int hi = lo + per; if (hi > N) hi = N;
  int s = 0;
  for (int i = lo; i < hi; i++) s += counts[i];
  sm[tid] = s;
  __syncthreads();
  for (int off=1; off<256; off<<=1){
    int t = (tid >= off) ? sm[tid-off] : 0;
    __syncthreads();
    sm[tid] += t;
    __syncthreads();
  }
  int run = sm[tid] - s;            // exclusive prefix of this thread's chunk
  for (int i = lo; i < hi; i++){
    int v = counts[i];
    rowptr[i] = run; fill[i] = run;
    run += v;
  }
  if (tid == 0) rowptr[N] = sm[255];
}
// scatter also records srcs[pos] = src-node of the edge (dst-sorted order).
__global__ __launch_bounds__(256) void k_scatter(
    const int* __restrict__ ei, int* __restrict__ fill,
    int* __restrict__ eorder, int* __restrict__ srcs, int E)
{
  int e = blockIdx.x*256 + threadIdx.x;
  if (e >= E) return;
  int d = ei[e];
  int pos = atomicAdd(&fill[d], 1);
  eorder[pos] = e;
  srcs[pos] = ei[E + e];
}

// one-time weight conversion to bf16 workspace copies.
// layout in out: [0,49152) W1 | [49152,98304) W3 | [98304,106496) W2a |
// [106496,139264) W2b | [139264,237568) W2c with row permute r->(r&127)*3+(r>>7)
__global__ __launch_bounds__(256) void k_cvt_weights(
    const void* __restrict__ W1, const void* __restrict__ W3,
    const void* __restrict__ W2a, const void* __restrict__ W2b,
    const void* __restrict__ W2c, u16* __restrict__ out,
    const int* __restrict__ dflag)
{
  int isb = *dflag;
  int i = blockIdx.x*256 + threadIdx.x;
  if (i >= 237568) return;
  float v;
  if (i < 49152)        v = ldx(W1, i, isb);
  else if (i < 98304)   v = ldx(W3, i-49152, isb);
  else if (i < 106496)  v = ldx(W2a, i-98304, isb);
  else if (i < 139264)  v = ldx(W2b, i-106496, isb);
  else {
    int j = i - 139264;
    int r = j >> 8, c = j & 255;
    v = ldx(W2c, (size_t)((r & 127)*3 + (r >> 7))*256 + c, isb);
  }
  out[i] = f2b(v);
}
// biases -> f32: [0,128) b2a | [128,384) b2b | [384,768) b2c (col-permuted)
__global__ __launch_bounds__(256) void k_cvt_biases(
    const void* __restrict__ b2a, const void* __restrict__ b2b,
    const void* __restrict__ b2c, float* __restrict__ out,
    const int* __restrict__ dflag)
{
  int isb = *dflag;
  int i = blockIdx.x*256 + threadIdx.x;
  if (i < 128) out[i] = ldx(b2a, i, isb);
  else if (i < 384) out[i] = ldx(b2b, i-128, isb);
  else if (i < 768){ int c = i-384; out[i] = ldx(b2c, (c&127)*3 + (c>>7), isb); }
}
// eatt (E x 64) -> bf16 rows permuted into dst-sorted edge order (eorder).
__global__ __launch_bounds__(256) void k_perm_eatt(
    const void* __restrict__ eatt, const int* __restrict__ eorder,
    u16* __restrict__ dst, int E, const int* __restrict__ dflag)
{
  int isb = *dflag;
  int row = blockIdx.x*8 + (threadIdx.x >> 5);
  int cp = (threadIdx.x & 31)*2;
  if (row >= E) return;
  int e = eorder[row];
  unsigned int w;
  if (isb){
    w = *(const unsigned int*)((const u16*)eatt + (size_t)e*64 + cp);
  } else {
    float2 v = *(const float2*)((const float*)eatt + (size_t)e*64 + cp);
    w = pu(f2b(v.x), f2b(v.y));
  }
  *(unsigned int*)(dst + (size_t)row*64 + cp) = w;
}

// normalize X, decompose into 10 independent components (bf16).
__global__ __launch_bounds__(256) void k_decompose(
    const void* __restrict__ X, u16* __restrict__ Di, u16* __restrict__ Da,
    u16* __restrict__ Ds, int NH, const int* __restrict__ dflag)
{
  __shared__ __align__(16) float buf[4608];   // 18 KB
  u16* bufu = (u16*)buf;
  int isb = *dflag;
  int tid = threadIdx.x;
  size_t t0 = (size_t)blockIdx.x*512;
  int validT = (int)((size_t)NH - t0); if (validT > 512) validT = 512;
  int ve = validT*9;
  if (isb){
    const u16* src = (const u16*)X + t0*9;
    for (int idx = tid; idx*8 < ve; idx += 256){
      if (idx*8+7 < ve) ((uint4*)bufu)[idx] = *(const uint4*)(src + idx*8);
      else for (int j=idx*8; j<ve; j++) bufu[j] = src[j];
    }
  } else {
    const float* src = (const float*)X + t0*9;
    for (int idx = tid; idx*4 < ve; idx += 256){
      if (idx*4+3 < ve) ((float4*)buf)[idx] = *(const float4*)(src + idx*4);
      else for (int j=idx*4; j<ve; j++) buf[j] = src[j];
    }
  }
  __syncthreads();
  int pairs = validT >> 1;
  if (tid >= pairs) return;
  int l2 = 2*tid;
  size_t tid2 = t0 + l2;
  int n = (int)(tid2 >> 7), c = (int)(tid2 & 127);
  u16 ri[2], ra[2][3], rs[2][6];
#pragma unroll
  for (int s=0; s<2; s++){
    float x[9]; float nrm = 0.f;
#pragma unroll
    for (int i=0;i<9;i++){
      x[i] = isb ? b2f(bufu[(l2+s)*9+i]) : buf[(l2+s)*9+i];
      nrm += x[i]*x[i];
    }
    float inv = 1.0f/(nrm+1.0f);
#pragma unroll
    for (int i=0;i<9;i++) x[i]*=inv;
    float i0 = (x[0]+x[4]+x[8])*(1.0f/3.0f);
    ri[s] = f2b(i0);
    ra[s][0] = f2b(0.5f*(x[1]-x[3]));
    ra[s][1] = f2b(0.5f*(x[2]-x[6]));
    ra[s][2] = f2b(0.5f*(x[5]-x[7]));
    rs[s][0] = f2b(x[0]-i0);
    rs[s][1] = f2b(0.5f*(x[1]+x[3]));
    rs[s][2] = f2b(0.5f*(x[2]+x[6]));
    rs[s][3] = f2b(x[4]-i0);
    rs[s][4] = f2b(0.5f*(x[5]+x[7]));
    rs[s][5] = f2b(x[8]-i0);
  }
  *(unsigned int*)&Di[tid2] = pu(ri[0], ri[1]);
  size_t ab = ((size_t)n*3)*128 + c;
#pragma unroll
  for (int j=0;j<3;j++)
    *(unsigned int*)&Da[ab + (size_t)j*128] = pu(ra[0][j], ra[1][j]);
  size_t sb = ((size_t)n*6)*128 + c;
#pragma unroll
  for (int j=0;j<6;j++)
    *(unsigned int*)&Ds[sb + (size_t)j*128] = pu(rs[0][j], rs[1][j]);
}

// ---------------------------------------------------------------------------
// MFMA GEMM (m97 structure) for the node linears.
// ---------------------------------------------------------------------------
__global__ __launch_bounds__(256) void k_mfma_gemm(
    const u16* __restrict__ A, const u16* __restrict__ B,
    const float* __restrict__ bias, const float* __restrict__ rowscale,
    u16* __restrict__ C, int M, int Ncol, int K, int flags)
{
  __shared__ u16 As[4096];   // 128 rows x 32 u16 (64B/row), linear
  __shared__ u16 Bs[4096];
  const int tid = threadIdx.x;
  const int lane = tid & 63, l15 = lane & 15, q = lane >> 4;
  const int wid = tid >> 6, wm = wid & 1, wn = wid >> 1;
  const int n0 = blockIdx.x * 128, m0 = blockIdx.y * 128;

  const int srow = wid*32 + (lane >> 2);
  const int qsrc = (lane & 3) ^ ((lane >> 3) & 3);
  int ar0 = m0 + srow;      if (ar0 >= M) ar0 = M-1;
  int ar1 = m0 + srow + 16; if (ar1 >= M) ar1 = M-1;
  const u16* aSrc0 = A + (size_t)ar0*K + qsrc*8;
  const u16* aSrc1 = A + (size_t)ar1*K + qsrc*8;
  const u16* bSrc0 = B + (size_t)(n0 + srow)*K + qsrc*8;
  const u16* bSrc1 = B + (size_t)(n0 + srow + 16)*K + qsrc*8;
  u16* aDst0 = &As[wid*1024];  u16* aDst1 = &As[wid*1024 + 512];
  u16* bDst0 = &Bs[wid*1024];  u16* bDst1 = &Bs[wid*1024 + 512];

  floatx4 acc[4][4];
#pragma unroll
  for (int i=0;i<4;i++)
#pragma unroll
    for (int j=0;j<4;j++) acc[i][j] = (floatx4)0.f;

  const int qsw  = ((q ^ ((l15 >> 1) & 3)) << 3);
  const int aBase = (wm*64 + l15)*32 + qsw;
  const int bBase = (wn*64 + l15)*32 + qsw;

  for (int k0 = 0; k0 < K; k0 += 32){
    gll16(aSrc0 + k0, aDst0);
    gll16(aSrc1 + k0, aDst1);
    gll16(bSrc0 + k0, bDst0);
    gll16(bSrc1 + k0, bDst1);
    __syncthreads();
    short8 av[4], bv[4];
#pragma unroll
    for (int mt=0; mt<4; mt++)
      av[mt] = *reinterpret_cast<const short8*>(&As[aBase + mt*512]);
#pragma unroll
    for (int nt=0; nt<4; nt++)
      bv[nt] = *reinterpret_cast<const short8*>(&Bs[bBase + nt*512]);
#pragma unroll
    for (int mt=0; mt<4; mt++)
#pragma unroll
      for (int nt=0; nt<4; nt++)
        acc[mt][nt] = __builtin_amdgcn_mfma_f32_16x16x32_bf16(av[mt], bv[nt], acc[mt][nt], 0, 0, 0);
    __syncthreads();
  }

  float biasv[4];
#pragma unroll
  for (int nt=0; nt<4; nt++)
    biasv[nt] = bias ? bias[n0 + wn*64 + nt*16 + l15] : 0.f;
#pragma unroll
  for (int mt=0; mt<4; mt++){
#pragma unroll
    for (int reg=0; reg<4; reg++){
      int row = m0 + wm*64 + mt*16 + q*4 + reg;
      if (row >= M) continue;
      float rs = (flags & 2) ? rowscale[row] : 1.0f;
      float t[4];
#pragma unroll
      for (int nt=0; nt<4; nt++){
        float v = acc[mt][nt][reg] + biasv[nt];
        if (flags & 1) v = fsilu(v);
        t[nt] = v * rs;
      }
      unsigned int p0 = cvtpk(t[0], t[1]);
      unsigned int p1 = cvtpk(t[2], t[3]);
      size_t rb = (size_t)row*Ncol + n0 + wn*64 + l15;
      C[rb]      = (u16)(p0 & 0xffffu);
      C[rb + 16] = (u16)(p0 >> 16);
      C[rb + 32] = (u16)(p1 & 0xffffu);
      C[rb + 48] = (u16)(p1 >> 16);
    }
  }
}

// ---------------------------------------------------------------------------
// Fused edge MLP: one block = 128 edges. eatt(64) ->[Wa]-> h1(128,LDS)
// ->[Wb]-> h2(256,LDS) ->[Wc]-> ea(384,global, silu+rowscale).
// h1/h2 never touch HBM. All tiles stored as [kstep][128][32] u16 with the
// same granule swizzle as k_mfma_gemm (g_lds = g_src ^ ((row>>1)&3)), so
// staging (gll16) and fragment reads reuse the proven address formulas.
// LDS: Ain 16K + H1 32K + H2 64K + Bs 8K = 120 KB -> 1 block/CU.
// ---------------------------------------------------------------------------
__global__ __launch_bounds__(256) void k_edge_mlp(
    const u16* __restrict__ eatt,   // chunk base [ec][64]
    const u16* __restrict__ Wa,     // [128][64]
    const u16* __restrict__ Wb,     // [256][128]
    const u16* __restrict__ Wc,     // [384][256] (row-permuted)
    const float* __restrict__ bias, // [768]: a | b | c(perm)
    const float* __restrict__ Cc,   // [ec] rowscale
    u16* __restrict__ ea, int ec)
{
  __shared__ u16 lds[61440];
  u16* Ain = lds;            // [2][4096]
  u16* H1  = lds + 8192;     // [4][4096]
  u16* H2  = lds + 24576;    // [8][4096]
  u16* Bs  = lds + 57344;    // [4096]
  const int tid = threadIdx.x;
  const int lane = tid & 63, l15 = lane & 15, q = lane >> 4;
  const int wid = tid >> 6, wm = wid & 1, wn = wid >> 1;
  const int r0 = blockIdx.x * 128;

  const int srow = wid*32 + (lane >> 2);
  const int qsrc = (lane & 3) ^ ((lane >> 3) & 3);
  const int qsw  = ((q ^ ((l15 >> 1) & 3)) << 3);
  const int aBase = (wm*64 + l15)*32 + qsw;   // A-frag offset within a tile
  const int bBase = (wn*64 + l15)*32 + qsw;   // B-frag offset within Bs

  // stage eatt tile (2 ksteps) once
  {
    int er0 = r0 + srow;      if (er0 >= ec) er0 = ec-1;
    int er1 = r0 + srow + 16; if (er1 >= ec) er1 = ec-1;
    const u16* s0 = eatt + (size_t)er0*64 + qsrc*8;
    const u16* s1 = eatt + (size_t)er1*64 + qsrc*8;
    gll16(s0,      Ain + wid*1024);
    gll16(s1,      Ain + wid*1024 + 512);
    gll16(s0 + 32, Ain + 4096 + wid*1024);
    gll16(s1 + 32, Ain + 4096 + wid*1024 + 512);
  }

  floatx4 acc[4][4];
  short8 av[4], bv[4];

  // ---- stage 1: h1[128][128] = silu(eatt @ Wa^T + b[0:128]) -> H1 ----
#pragma unroll
  for (int i=0;i<4;i++)
#pragma unroll
    for (int j=0;j<4;j++) acc[i][j] = (floatx4)0.f;
#pragma unroll
  for (int ks=0; ks<2; ks++){
    const u16* w0 = Wa + (size_t)srow*64 + ks*32 + qsrc*8;
    gll16(w0,        Bs + wid*1024);
    gll16(w0 + 16*64, Bs + wid*1024 + 512);
    __syncthreads();
    const u16* At = Ain + ks*4096;
#pragma unroll
    for (int mt=0; mt<4; mt++)
      av[mt] = *reinterpret_cast<const short8*>(&At[aBase + mt*512]);
#pragma unroll
    for (int nt=0; nt<4; nt++)
      bv[nt] = *reinterpret_cast<const short8*>(&Bs[bBase + nt*512]);
#pragma unroll
    for (int mt=0; mt<4; mt++)
#pragma unroll
      for (int nt=0; nt<4; nt++)
        acc[mt][nt] = __builtin_amdgcn_mfma_f32_16x16x32_bf16(av[mt], bv[nt], acc[mt][nt], 0, 0, 0);
    __syncthreads();
  }
  {
    float biasv[4];
#pragma unroll
    for (int nt=0; nt<4; nt++)
      biasv[nt] = bias[wn*64 + nt*16 + l15];
#pragma unroll
    for (int mt=0; mt<4; mt++)
#pragma unroll
      for (int reg=0; reg<4; reg++){
        int row = wm*64 + mt*16 + q*4 + reg;
        int rsw = ((q*4+reg) >> 1) & 3;
#pragma unroll
        for (int nt=0; nt<4; nt++){
          int col = wn*64 + nt*16 + l15;
          float v = fsilu(acc[mt][nt][reg] + biasv[nt]);
          int ks = col >> 5, g = (col>>3)&3, e = col&7;
          H1[ks*4096 + row*32 + ((g ^ rsw)<<3) + e] = f2b(v);
        }
      }
  }

  // ---- stage 2: h2[128][256] = silu(h1 @ Wb^T + b[128:384]) -> H2 ----
#pragma unroll
  for (int cb=0; cb<2; cb++){
#pragma unroll
    for (int i=0;i<4;i++)
#pragma unroll
      for (int j=0;j<4;j++) acc[i][j] = (floatx4)0.f;
#pragma unroll
    for (int ks=0; ks<4; ks++){
      const u16* w0 = Wb + (size_t)(cb*128 + srow)*128 + ks*32 + qsrc*8;
      gll16(w0,         Bs + wid*1024);
      gll16(w0 + 16*128, Bs + wid*1024 + 512);
      __syncthreads();
      const u16* At = H1 + ks*4096;
#pragma unroll
      for (int mt=0; mt<4; mt++)
        av[mt] = *reinterpret_cast<const short8*>(&At[aBase + mt*512]);
#pragma unroll
      for (int nt=0; nt<4; nt++)
        bv[nt] = *reinterpret_cast<const short8*>(&Bs[bBase + nt*512]);
#pragma unroll
      for (int mt=0; mt<4; mt++)
#pragma unroll
        for (int nt=0; nt<4; nt++)
          acc[mt][nt] = __builtin_amdgcn_mfma_f32_16x16x32_bf16(av[mt], bv[nt], acc[mt][nt], 0, 0, 0);
      __syncthreads();
    }
    float biasv[4];
#pragma unroll
    for (int nt=0; nt<4; nt++)
      biasv[nt] = bias[128 + cb*128 + wn*64 + nt*16 + l15];
#pragma unroll
    for (int mt=0; mt<4; mt++)
#pragma unroll
      for (int reg=0; reg<4; reg++){
        int row = wm*64 + mt*16 + q*4 + reg;
        int rsw = ((q*4+reg) >> 1) & 3;
#pragma unroll
        for (int nt=0; nt<4; nt++){
          int col = cb*128 + wn*64 + nt*16 + l15;
          float v = fsilu(acc[mt][nt][reg] + biasv[nt]);
          int ks = col >> 5, g = (col>>3)&3, e = col&7;
          H2[ks*4096 + row*32 + ((g ^ rsw)<<3) + e] = f2b(v);
        }
      }
  }

  // ---- stage 3: ea[128][384] = silu(h2 @ Wc^T + b[384:768]) * Cc -> global ----
#pragma unroll
  for (int cb=0; cb<3; cb++){
#pragma unroll
    for (int i=0;i<4;i++)
#pragma unroll
      for (int j=0;j<4;j++) acc[i][j] = (floatx4)0.f;
#pragma unroll
    for (int ks=0; ks<8; ks++){
      const u16* w0 = Wc + (size_t)(cb*128 + srow)*256 + ks*32 + qsrc*8;
      gll16(w0,         Bs + wid*1024);
      gll16(w0 + 16*256, Bs + wid*1024 + 512);
      __syncthreads();
      const u16* At = H2 + ks*4096;
#pragma unroll
      for (int mt=0; mt<4; mt++)
        av[mt] = *reinterpret_cast<const short8*>(&At[aBase + mt*512]);
#pragma unroll
      for (int nt=0; nt<4; nt++)
        bv[nt] = *reinterpret_cast<const short8*>(&Bs[bBase + nt*512]);
#pragma unroll
      for (int mt=0; mt<4; mt++)
#pragma unroll
        for (int nt=0; nt<4; nt++)
          acc[mt][nt] = __builtin_amdgcn_mfma_f32_16x16x32_bf16(av[mt], bv[nt], acc[mt][nt], 0, 0, 0);
      __syncthreads();
    }
    float biasv[4];
#pragma unroll
    for (int nt=0; nt<4; nt++)
      biasv[nt] = bias[384 + cb*128 + wn*64 + nt*16 + l15];
#pragma unroll
    for (int mt=0; mt<4; mt++)
#pragma unroll
      for (int reg=0; reg<4; reg++){
        int row = r0 + wm*64 + mt*16 + q*4 + reg;
        if (row >= ec) continue;
        float rs = Cc[row];
        float t[4];
#pragma unroll
        for (int nt=0; nt<4; nt++)
          t[nt] = fsilu(acc[mt][nt][reg] + biasv[nt]) * rs;
        unsigned int p0 = cvtpk(t[0], t[1]);
        unsigned int p1 = cvtpk(t[2], t[3]);
        size_t rb = (size_t)row*384 + cb*128 + wn*64 + l15;
        ea[rb]      = (u16)(p0 & 0xffffu);
        ea[rb + 16] = (u16)(p0 >> 16);
        ea[rb + 32] = (u16)(p1 & 0xffffu);
        ea[rb + 48] = (u16)(p1 >> 16);
      }
  }
}

// cutoff factor per sorted edge (row i of chunk = edge eorder[c0+i])
__global__ __launch_bounds__(256) void k_cutoff(
    const void* __restrict__ ew, const int* __restrict__ eorder, int c0,
    float* __restrict__ Cc, int ec, const int* __restrict__ dflag)
{
  int i = blockIdx.x*256 + threadIdx.x;
  if (i >= ec) return;
  int e = eorder[c0 + i];
  float w = ldx(ew, e, *dflag);
  float c = 0.0f;
  if (w < 4.5f) c = 0.5f*(cosf(w*0.6981317007977318f) + 1.0f);
  Cc[i] = c;
}

// ---------------------------------------------------------------------------
// Gather message passing: block per dst node. 128 threads = 2 edge slots x
// 64 channel-pairs (all loads u32), srcs[] direct. msg RMW as float2.
// ---------------------------------------------------------------------------
__global__ __launch_bounds__(128) void k_gather(
    const int* __restrict__ rowptr, const int* __restrict__ srcs,
    int c0, int c1, int first,
    const u16* __restrict__ ea,
    const u16* __restrict__ Pi, const u16* __restrict__ Pa,
    const u16* __restrict__ Ps, const void* __restrict__ b1,
    float* __restrict__ msg, int NH, const int* __restrict__ dflag)
{
  int n = blockIdx.x;
  int lo = rowptr[n], hi = rowptr[n+1];
  if (lo < c0) lo = c0;
  if (hi > c1) hi = c1;
  if (!first && lo >= hi) return;
  int tid = threadIdx.x;
  int slot = tid >> 6;          // 0/1 (wave-uniform)
  int cp = (tid & 63) * 2;      // channel pair base
  float m[2][9];
#pragma unroll
  for (int s=0;s<2;s++)
#pragma unroll
    for (int i=0;i<9;i++) m[s][i]=0.f;
  if (lo < hi){
    int isb = *dflag;
    float b0[2], b1v[2], b2v[2];
#pragma unroll
    for (int s=0;s<2;s++){
      b0[s]  = ldx(b1, cp+s,     isb);
      b1v[s] = ldx(b1, 128+cp+s, isb);
      b2v[s] = ldx(b1, 256+cp+s, isb);
    }
    for (int idx = lo + slot; idx < hi; idx += 2){
      int src = srcs[idx];
      const u16* er = ea + (size_t)(idx - c0)*384;
      unsigned int ue0 = *(const unsigned int*)(er + cp);
      unsigned int ue1 = *(const unsigned int*)(er + 128 + cp);
      unsigned int ue2 = *(const unsigned int*)(er + 256 + cp);
      unsigned int upi = *(const unsigned int*)(Pi + (size_t)src*128 + cp);
      size_t ab = (size_t)src*384 + cp;
      unsigned int ua0 = *(const unsigned int*)(Pa + ab);
      unsigned int ua1 = *(const unsigned int*)(Pa + ab + 128);
      unsigned int ua2 = *(const unsigned int*)(Pa + ab + 256);
      size_t sbb = (size_t)src*768 + cp;
      unsigned int us0 = *(const unsigned int*)(Ps + sbb);
      unsigned int us1 = *(const unsigned int*)(Ps + sbb + 128);
      unsigned int us2 = *(const unsigned int*)(Ps + sbb + 256);
      unsigned int us3 = *(const unsigned int*)(Ps + sbb + 384);
      unsigned int us4 = *(const unsigned int*)(Ps + sbb + 512);
      unsigned int us5 = *(const unsigned int*)(Ps + sbb + 640);
#pragma unroll
      for (int s=0;s<2;s++){
        float e0f = gsel(ue0,s), e1f = gsel(ue1,s), e2f = gsel(ue2,s);
        float i1 = gsel(upi,s);
        float a0 = gsel(ua0,s), a1 = gsel(ua1,s), a2 = gsel(ua2,s);
        float s0 = gsel(us0,s), s1 = gsel(us1,s), s2 = gsel(us2,s);
        float s3 = gsel(us3,s), s4 = gsel(us4,s), s5 = gsel(us5,s);
        float bb = e0f*b0[s] + e1f*b1v[s] + e2f*b2v[s];
        float t0 = e0f*i1;
        m[s][0] += t0 + e2f*s0 + bb;
        m[s][1] += e1f*a0 + e2f*s1 + bb;
        m[s][2] += e1f*a1 + e2f*s2 + bb;
        m[s][3] += -e1f*a0 + e2f*s1 + bb;
        m[s][4] += t0 + e2f*s3 + bb;
        m[s][5] += e1f*a2 + e2f*s4 + bb;
        m[s][6] += -e1f*a1 + e2f*s2 + bb;
        m[s][7] += -e1f*a2 + e2f*s4 + bb;
        m[s][8] += t0 + e2f*s5 + bb;
      }
    }
  }
  // combine slot1 into slot0 via LDS
  __shared__ float red[64][18];
  if (slot == 1){
#pragma unroll
    for (int s=0;s<2;s++)
#pragma unroll
      for (int i=0;i<9;i++) red[tid & 63][s*9+i] = m[s][i];
  }
  __syncthreads();
  if (slot == 0){
    int cl = tid & 63;
#pragma unroll
    for (int s=0;s<2;s++)
#pragma unroll
      for (int i=0;i<9;i++) m[s][i] += red[cl][s*9+i];
    size_t o = (size_t)n*128 + cp;
    if (first){
#pragma unroll
      for (int i=0;i<9;i++){
        float2 v = {m[0][i], m[1][i]};
        *(float2*)&msg[(size_t)i*NH + o] = v;
      }
    } else {
#pragma unroll
      for (int i=0;i<9;i++){
        float2* p = (float2*)&msg[(size_t)i*NH + o];
        float2 v = *p;
        v.x += m[0][i]; v.y += m[1][i];
        *p = v;
      }
    }
  }
}

// Update: F = msg*Y + Y*msg, renormalize, decompose -> D2 (bf16).
__global__ __launch_bounds__(256) void k_update(
    const float* __restrict__ msg, const u16* __restrict__ Pi,
    const u16* __restrict__ Pa, const u16* __restrict__ Ps,
    const void* __restrict__ b1,
    u16* __restrict__ D2i, u16* __restrict__ D2a, u16* __restrict__ D2s,
    int NH, const int* __restrict__ dflag)
{
  size_t tid2 = ((size_t)blockIdx.x*256 + threadIdx.x)*2;
  if (tid2 >= (size_t)NH) return;
  int isb = *dflag;
  int n = (int)(tid2 >> 7), c = (int)(tid2 & 127);
  float Mx[2][9];
#pragma unroll
  for (int i=0;i<9;i++){
    float2 v = *(const float2*)&msg[(size_t)i*NH + tid2];
    Mx[0][i] = v.x; Mx[1][i] = v.y;
  }
  unsigned int ui = *(const unsigned int*)&Pi[tid2];
  size_t ab = ((size_t)n*3)*128 + c;
  unsigned int ua[3];
#pragma unroll
  for (int j=0;j<3;j++) ua[j] = *(const unsigned int*)&Pa[ab + (size_t)j*128];
  size_t sb = ((size_t)n*6)*128 + c;
  unsigned int us[6];
#pragma unroll
  for (int j=0;j<6;j++) us[j] = *(const unsigned int*)&Ps[sb + (size_t)j*128];
  u16 ri[2], ra[2][3], rs[2][6];
#pragma unroll
  for (int s=0; s<2; s++){
    float i1 = gsel(ui,s);
    float a0 = gsel(ua[0],s), a1 = gsel(ua[1],s), a2 = gsel(ua[2],s);
    float s0 = gsel(us[0],s), s1 = gsel(us[1],s), s2 = gsel(us[2],s);
    float s3 = gsel(us[3],s), s4 = gsel(us[4],s), s5 = gsel(us[5],s);
    float B = ldx(b1,c+s,isb) + ldx(b1,128+c+s,isb) + ldx(b1,256+c+s,isb);
    float Y[9];
    Y[0]= i1+s0+B; Y[1]= a0+s1+B; Y[2]= a1+s2+B;
    Y[3]=-a0+s1+B; Y[4]= i1+s3+B; Y[5]= a2+s4+B;
    Y[6]=-a1+s2+B; Y[7]=-a2+s4+B; Y[8]= i1+s5+B;
    float F[9];
#pragma unroll
    for (int i=0;i<3;i++)
#pragma unroll
      for (int j=0;j<3;j++){
        float acc = 0.f;
#pragma unroll
        for (int t=0;t<3;t++)
          acc += Mx[s][i*3+t]*Y[t*3+j] + Y[i*3+t]*Mx[s][t*3+j];
        F[i*3+j] = acc;
      }
    float nrm = 0.f;
#pragma unroll
    for (int i=0;i<9;i++) nrm += F[i]*F[i];
    float inv = 1.0f/(nrm+1.0f);
    float i2 = (F[0]+F[4]+F[8])*(1.0f/3.0f);
    ri[s] = f2b(i2*inv);
    ra[s][0] = f2b(0.5f*(F[1]-F[3])*inv);
    ra[s][1] = f2b(0.5f*(F[2]-F[6])*inv);
    ra[s][2] = f2b(0.5f*(F[5]-F[7])*inv);
    rs[s][0] = f2b((F[0]-i2)*inv);
    rs[s][1] = f2b(0.5f*(F[1]+F[3])*inv);
    rs[s][2] = f2b(0.5f*(F[2]+F[6])*inv);
    rs[s][3] = f2b((F[4]-i2)*inv);
    rs[s][4] = f2b(0.5f*(F[5]+F[7])*inv);
    rs[s][5] = f2b((F[8]-i2)*inv);
  }
  *(unsigned int*)&D2i[tid2] = pu(ri[0], ri[1]);
#pragma unroll
  for (int j=0;j<3;j++)
    *(unsigned int*)&D2a[ab + (size_t)j*128] = pu(ra[0][j], ra[1][j]);
#pragma unroll
  for (int j=0;j<6;j++)
    *(unsigned int*)&D2s[sb + (size_t)j*128] = pu(rs[0][j], rs[1][j]);
}

// Final: dX from P2 + b3; out = Xn + dX + dX*dX (dual-dtype out).
__global__ __launch_bounds__(256) void k_final(
    const void* __restrict__ X, const u16* __restrict__ P2i,
    const u16* __restrict__ P2a, const u16* __restrict__ P2s,
    const void* __restrict__ b3, void* __restrict__ out, int NH,
    const int* __restrict__ dflag)
{
  __shared__ __align__(16) float buf[4608];   // 18 KB; aliased u16 for bf16
  u16* bufu = (u16*)buf;
  int isb = *dflag;
  int tid = threadIdx.x;
  size_t t0 = (size_t)blockIdx.x*512;
  int validT = (int)((size_t)NH - t0); if (validT > 512) validT = 512;
  int ve = validT*9;
  // stage X
  if (isb){
    const u16* src = (const u16*)X + t0*9;
    for (int idx = tid; idx*8 < ve; idx += 256){
      if (idx*8+7 < ve) ((uint4*)bufu)[idx] = *(const uint4*)(src + idx*8);
      else for (int j=idx*8; j<ve; j++) bufu[j] = src[j];
    }
  } else {
    const float* src = (const float*)X + t0*9;
    for (int idx = tid; idx*4 < ve; idx += 256){
      if (idx*4+3 < ve) ((float4*)buf)[idx] = *(const float4*)(src + idx*4);
      else for (int j=idx*4; j<ve; j++) buf[j] = src[j];
    }
  }
  __syncthreads();
  int pairs = validT >> 1;
  int l2 = 2*tid;
  size_t tid2 = t0 + l2;
  float vout[2][9];
  if (tid < pairs){
    int n = (int)(tid2 >> 7), c = (int)(tid2 & 127);
    unsigned int ui = *(const unsigned int*)&P2i[tid2];
    size_t ab = ((size_t)n*3)*128 + c;
    unsigned int ua[3];
#pragma unroll
    for (int j=0;j<3;j++) ua[j] = *(const unsigned int*)&P2a[ab + (size_t)j*128];
    size_t sb = ((size_t)n*6)*128 + c;
    unsigned int us[6];
#pragma unroll
    for (int j=0;j<6;j++) us[j] = *(const unsigned int*)&P2s[sb + (size_t)j*128];
#pragma unroll
    for (int s=0; s<2; s++){
      float i1 = gsel(ui,s);
      float a0 = gsel(ua[0],s), a1 = gsel(ua[1],s), a2 = gsel(ua[2],s);
      float s0 = gsel(us[0],s), s1 = gsel(us[1],s), s2 = gsel(us[2],s);
      float s3 = gsel(us[3],s), s4 = gsel(us[4],s), s5 = gsel(us[5],s);
      float B = ldx(b3,c+s,isb) + ldx(b3,128+c+s,isb) + ldx(b3,256+c+s,isb);
      float dX[9];
      dX[0]= i1+s0+B; dX[1]= a0+s1+B; dX[2]= a1+s2+B;
      dX[3]=-a0+s1+B; dX[4]= i1+s3+B; dX[5]= a2+s4+B;
      dX[6]=-a1+s2+B; dX[7]=-a2+s4+B; dX[8]= i1+s5+B;
      float x[9]; float nrm = 0.f;
#pragma unroll
      for (int i=0;i<9;i++){
        x[i] = isb ? b2f(bufu[(l2+s)*9+i]) : buf[(l2+s)*9+i];
        nrm += x[i]*x[i];
      }
      float inv = 1.0f/(nrm+1.0f);
#pragma unroll
      for (int i=0;i<3;i++)
#pragma unroll
        for (int j=0;j<3;j++){
          float acc = 0.f;
#pragma unroll
          for (int t=0;t<3;t++) acc += dX[i*3+t]*dX[t*3+j];
          vout[s][i*3+j] = x[i*3+j]*inv + dX[i*3+j] + acc;
        }
    }
  }
  __syncthreads();   // all LDS reads of X done
  // stage outputs
  if (tid < pairs){
    if (isb){
#pragma unroll
      for (int s=0;s<2;s++)
#pragma unroll
        for (int i=0;i<9;i++) bufu[(l2+s)*9+i] = f2b(vout[s][i]);
    } else {
#pragma unroll
      for (int s=0;s<2;s++)
#pragma unroll
        for (int i=0;i<9;i++) buf[(l2+s)*9+i] = vout[s][i];
    }
  }
  __syncthreads();
  if (isb){
    u16* dst = (u16*)out + t0*9;
    for (int idx = tid; idx*8 < ve; idx += 256){
      if (idx*8+7 < ve) *(uint4*)(dst + idx*8) = ((const uint4*)bufu)[idx];
      else for (int j=idx*8; j<ve; j++) dst[j] = bufu[j];
    }
  } else {
    float* dst = (float*)out + t0*9;
    for (int idx = tid; idx*4 < ve; idx += 256){
      if (idx*4+3 < ve) *(float4*)(dst + idx*4) = ((const float4*)buf)[idx];
      else for (int j=idx*4; j<ve; j++) dst[j] = buf[j];
    }
  }
}

extern "C" void kernel_launch(void* const* d_in, const int* in_sizes, int n_in,
                              void* d_out, int out_size, void* d_ws, size_t ws_size,
                              hipStream_t stream)
{
  const void* X    = d_in[0];
  const int*  ei   = (const int*)d_in[1];
  const void* ew   = d_in[2];
  const void* eatt = d_in[3];
  const void* W1   = d_in[4];
  const void* b1   = d_in[5];
  const void* W2a  = d_in[6];
  const void* b2a  = d_in[7];
  const void* W2b  = d_in[8];
  const void* b2b  = d_in[9];
  const void* W2c  = d_in[10];
  const void* b2c  = d_in[11];
  const void* W3   = d_in[12];
  const void* b3   = d_in[13];

  const int NH = in_sizes[0]/9;   // 20001*128
  const int E  = in_sizes[2];     // 200000
  const int N  = NH/128;

  auto aln = [](size_t x){ return (x + 255) & ~(size_t)255; };
  char* ws = (char*)d_ws;
  size_t off = 0;
  size_t o_flag = off; off += 256;
  size_t o_msg  = off; off += aln((size_t)NH*9*4);
  size_t o_Di   = off; off += aln((size_t)NH*2);
  size_t o_Da   = off; off += aln((size_t)NH*6);
  size_t o_Ds   = off; off += aln((size_t)NH*12);
  size_t o_Pi   = off; off += aln((size_t)NH*2);
  size_t o_Pa   = off; off += aln((size_t)NH*6);
  size_t o_Ps   = off; off += aln((size_t)NH*12);
  size_t o_cnt  = off; off += aln((size_t)N*4);
  size_t o_rp   = off; off += aln((size_t)(N+1)*4);
  size_t o_fill = off; off += aln((size_t)N*4);
  size_t o_eord = off; off += aln((size_t)E*4);
  size_t o_srcs = off; off += aln((size_t)E*4);      // src node per sorted edge
  size_t o_eattb= off; off += aln((size_t)E*64*2);   // eorder-permuted bf16 eatt
  size_t o_wb   = off; off += aln((size_t)237568*2); // bf16 weight copies
  size_t o_bf   = off; off += aln((size_t)768*4);    // f32 bias copies
  size_t persistent = off;

  // Per-edge chunk footprint (fused MLP: no h1/h2): ea 768B + Cc 4B = 772B
  int EC;
  {
    size_t avail = (ws_size > persistent + 4096) ? (ws_size - persistent - 4096) : 0;
    size_t ecmax = avail / 772;
    if (ecmax > (size_t)E) ecmax = (size_t)E;
    EC = (int)(ecmax & ~(size_t)1023);
    if (EC < 1024) EC = 1024;
  }
  size_t o_ea = persistent;
  size_t o_Cc = o_ea + aln((size_t)EC*768);
  (void)n_in; (void)out_size;

  int* dflag = (int*)(ws + o_flag);
  u16* Di = (u16*)(ws + o_Di);
  u16* Da = (u16*)(ws + o_Da);
  u16* Ds = (u16*)(ws + o_Ds);
  u16* Pi = (u16*)(ws + o_Pi);
  u16* Pa = (u16*)(ws + o_Pa);
  u16* Ps = (u16*)(ws + o_Ps);
  float* msg = (float*)(ws + o_msg);
  int* counts = (int*)(ws + o_cnt);
  int* rowptr = (int*)(ws + o_rp);
  int* fill   = (int*)(ws + o_fill);
  int* eorder = (int*)(ws + o_eord);
  int* srcs   = (int*)(ws + o_srcs);
  u16* eattb  = (u16*)(ws + o_eattb);
  u16* wb     = (u16*)(ws + o_wb);
  float* bf   = (float*)(ws + o_bf);
  u16* ea = (u16*)(ws + o_ea);
  float* Cc = (float*)(ws + o_Cc);

  dim3 blk(256);
  auto gemm = [&](const u16* A, const u16* Bw, const float* bias, const float* rs,
                  u16* C, int M, int Ncol, int K, int flags){
    dim3 grid(Ncol/128, (M+127)/128);
    k_mfma_gemm<<<grid, blk, 0, stream>>>(A, Bw, bias, rs, C, M, Ncol, K, flags);
  };

  // 0. sniff dtype; one-time bf16/f32 conversions of weights+biases
  k_sniff<<<1, blk, 0, stream>>>(X, dflag);
  k_cvt_weights<<<(237568+255)/256, blk, 0, stream>>>(W1, W3, W2a, W2b, W2c, wb, dflag);
  k_cvt_biases<<<3, blk, 0, stream>>>(b2a, b2b, b2c, bf, dflag);
  // 1. decompose (512 tids/block)
  k_decompose<<<(NH+511)/512, blk, 0, stream>>>(X, Di, Da, Ds, NH, dflag);
  // 2. node linears (W1) -> P components
  gemm(Di, wb,       nullptr, nullptr, Pi, N,   128, 128, 0);
  gemm(Da, wb+16384, nullptr, nullptr, Pa, 3*N, 128, 128, 0);
  gemm(Ds, wb+32768, nullptr, nullptr, Ps, 6*N, 128, 128, 0);
  // 3. build CSR (sort edges by dst; srcs recorded); permute eatt
  k_zero_int<<<(N+255)/256, blk, 0, stream>>>(counts, N);
  k_hist<<<(E+255)/256, blk, 0, stream>>>(ei, counts, E);
  k_scan<<<1, blk, 0, stream>>>(counts, rowptr, fill, N);
  k_scatter<<<(E+255)/256, blk, 0, stream>>>(ei, fill, eorder, srcs, E);
  k_perm_eatt<<<(E+7)/8, blk, 0, stream>>>(eatt, eorder, eattb, E, dflag);
  // 4. fused edge MLP (h1/h2 in LDS) + gather message passing, chunked
  for (int c0 = 0; c0 < E; c0 += EC){
    int ec = E - c0; if (ec > EC) ec = EC;
    k_cutoff<<<(ec+255)/256, blk, 0, stream>>>(ew, eorder, c0, Cc, ec, dflag);
    k_edge_mlp<<<(ec+127)/128, blk, 0, stream>>>(
        eattb + (size_t)c0*64, wb+98304, wb+106496, wb+139264, bf, Cc, ea, ec);
    k_gather<<<N, dim3(128), 0, stream>>>(rowptr, srcs, c0, c0+ec,
                                          (c0==0)?1:0,
                                          ea, Pi, Pa, Ps, b1, msg, NH, dflag);
  }
  // 5. update (writes D2 into D buffers; D dead)
  k_update<<<(NH/2+255)/256, blk, 0, stream>>>(msg, Pi, Pa, Ps, b1, Di, Da, Ds, NH, dflag);
  // 6. node linears (W3) -> P2 (reuses P buffers)
  gemm(Di, wb+49152, nullptr, nullptr, Pi, N,   128, 128, 0);
  gemm(Da, wb+65536, nullptr, nullptr, Pa, 3*N, 128, 128, 0);
  gemm(Ds, wb+81920, nullptr, nullptr, Ps, 6*N, 128, 128, 0);
  // 7. final output (512 tids/block)
  k_final<<<(NH+511)/512, blk, 0, stream>>>(X, Pi, Pa, Ps, b3, d_out, NH, dflag);
}